// Round 5
// baseline (1022.930 us; speedup 1.0000x reference)
//
#include <hip/hip_runtime.h>
#include <math.h>

// HGSA: 3x (mask-guided channel-attention MSA + LN + convFFN) on [2,64,256,256].
// External I/O fp32. Internal activations FP16, residual stream X fp32 (+f16
// mirror Xb), weights f16 in LDS.
// R5: MFMA gemms. R6: staged attn, un-chunked FFN, fused QKV. R7: attn atomic
// 32-way split. R8: weights pre-transposed W^T. R9: dwconv4 (4 px/thread +
// conflict-free weight LDS). R10: bf16 -> fp16 (HW pack/pk_fma).
// R11: attn folded into Wp; mask m1+m2 fused; LN fused into ffn_gemm1.
// R12: attention partials fused INTO qkv_gemm; attn_softmax+fold merged.
// R13: qkv attention tail reworked — R12 was latency-bound (52us, 21% occ,
// 1.05M bank-conflict cycles): (a) Qs/Ks padded to stride 72 (staging writes
// 2-way max, was 16-way); (b) lane=(h,dg,eg) holds 4x4 accS tile, wave covers
// only its OWN 16 rows (16 iters x 2 b64 reads x 16 FMA, was 64 iters of
// scalar reads); wave partials reduced in LDS (aliasing dead Cs), same 1024
// atomics/block as before.

typedef unsigned short bhalf;            // fp16 bits
typedef unsigned int u32;
typedef _Float16 h2 __attribute__((ext_vector_type(2)));
typedef _Float16 f16x8 __attribute__((ext_vector_type(8)));
typedef __attribute__((ext_vector_type(4))) float f32x4;

#define GEMM_GRID 2048      // 131072 rows / 64 rows per block
#define NSPLIT 32           // attn accumulator copies
#define SCOPY 2304          // floats per copy: 2048 S + 128 nq + 128 nk
#define WBLK 57344          // f16 per transformer-block weight blob

__device__ __forceinline__ float h2f(bhalf b) {
  union { bhalf u; _Float16 h; } c; c.u = b; return (float)c.h;
}
__device__ __forceinline__ bhalf f2h(float f) {
  union { _Float16 h; bhalf u; } c; c.h = (_Float16)f; return c.u;
}
__device__ __forceinline__ u32 pack2h(float a, float b) {
  auto r = __builtin_amdgcn_cvt_pkrtz(a, b);     // v_cvt_pkrtz_f16_f32, 1 op
  union { decltype(r) h; u32 u; } c; c.h = r; return c.u;
}
__device__ __forceinline__ void unpack2h(u32 p, float& a, float& b) {
  union { u32 u; h2 h; } c; c.u = p;
  a = (float)c.h[0]; b = (float)c.h[1];
}
__device__ __forceinline__ void unpack8h(uint4 u, float* f) {
  unpack2h(u.x, f[0], f[1]); unpack2h(u.y, f[2], f[3]);
  unpack2h(u.z, f[4], f[5]); unpack2h(u.w, f[6], f[7]);
}
__device__ __forceinline__ float gelu_f(float v) {   // exact gelu
  return 0.5f * v * (1.0f + erff(v * 0.70710678118654752440f));
}
__device__ __forceinline__ uint4 pack16(const float* v) {  // 8 floats -> 8 f16
  uint4 s;
  s.x = pack2h(v[0], v[1]); s.y = pack2h(v[2], v[3]);
  s.z = pack2h(v[4], v[5]); s.w = pack2h(v[6], v[7]);
  return s;
}

// ---------------- weight pre-transpose (once per launch, ~2us) ----------------
// For each GEMM weight W[K][N]: WTg[n*K + k] = f16(W[k][n]).
// Per block i: mm1@0, mm2@4096, Q@8192, K@12288, V@16384, P@20480,
//              ff1@24576 ([256][64]), ff2@40960 ([64][256]).
__global__ __launch_bounds__(256) void prep_weights(
    const float* __restrict__ mm_w1, const float* __restrict__ mm_w2,
    const float* __restrict__ Wq, const float* __restrict__ Wk,
    const float* __restrict__ Wv, const float* __restrict__ Wp,
    const float* __restrict__ ff_w1, const float* __restrict__ ff_w2,
    bhalf* __restrict__ out)
{
  int i = blockIdx.x >> 3, slot = blockIdx.x & 7;
  int t = threadIdx.x;
  const float* src; int ksh, N; size_t off;
  switch (slot) {
    case 0:  src = mm_w1 + i*4096;  ksh=6; N=64;  off = 0;     break;
    case 1:  src = mm_w2 + i*4096;  ksh=6; N=64;  off = 4096;  break;
    case 2:  src = Wq + i*4096;     ksh=6; N=64;  off = 8192;  break;
    case 3:  src = Wk + i*4096;     ksh=6; N=64;  off = 12288; break;
    case 4:  src = Wv + i*4096;     ksh=6; N=64;  off = 16384; break;
    case 5:  src = Wp + i*4096;     ksh=6; N=64;  off = 20480; break;
    case 6:  src = ff_w1 + i*16384; ksh=6; N=256; off = 24576; break;
    default: src = ff_w2 + i*16384; ksh=8; N=64;  off = 40960; break;
  }
  bhalf* dst = out + (size_t)i * WBLK + off;
  int sz = N << ksh;
  int kmask = (1 << ksh) - 1;
  for (int idx = t; idx < sz; idx += 256) {
    int n = idx >> ksh, k = idx & kmask;
    dst[idx] = f2h(src[k * N + n]);
  }
}

// ---------------- transposes ----------------
template<int MODE>   // 0: x -> fp32 X AND f16 Xb.  1: mask -> f16 only.
__global__ __launch_bounds__(256) void nchw2nhwc(const float* __restrict__ in,
                                                 void* __restrict__ out,
                                                 bhalf* __restrict__ out2) {
  __shared__ float tile[64][65];
  int t = threadIdx.x;
  int b = blockIdx.x >> 10;
  int n0 = (blockIdx.x & 1023) << 6;
  #pragma unroll
  for (int j = 0; j < 16; ++j) {
    int idx = j * 256 + t;
    int c = idx >> 6, nn = idx & 63;
    tile[c][nn] = in[(((size_t)(b * 64 + c)) << 16) + n0 + nn];
  }
  __syncthreads();
  #pragma unroll
  for (int j = 0; j < 16; ++j) {
    int idx = j * 256 + t;
    int nn = idx >> 6, c = idx & 63;
    size_t o = ((((size_t)b << 16) + n0 + nn) << 6) + c;
    float v = tile[c][nn];
    if (MODE == 0) { ((float*)out)[o] = v; out2[o] = f2h(v); }
    else           { ((bhalf*)out)[o] = f2h(v); }
  }
}

__global__ __launch_bounds__(256) void nhwc2nchw(const float* __restrict__ in,
                                                 float* __restrict__ out) {
  __shared__ float tile[64][65];
  int t = threadIdx.x;
  int b = blockIdx.x >> 10;
  int n0 = (blockIdx.x & 1023) << 6;
  #pragma unroll
  for (int j = 0; j < 16; ++j) {
    int idx = j * 256 + t;
    int nn = idx >> 6, c = idx & 63;
    tile[c][nn] = in[((((size_t)b << 16) + n0 + nn) << 6) + c];
  }
  __syncthreads();
  #pragma unroll
  for (int j = 0; j < 16; ++j) {
    int idx = j * 256 + t;
    int c = idx >> 6, nn = idx & 63;
    out[(((size_t)(b * 64 + c)) << 16) + n0 + nn] = tile[c][nn];
  }
}

// ---------------- fused mask GEMMs: m1 = M@W1+b1 ; m2 = m1@W2+b2 ----------------
__global__ __launch_bounds__(256) void gemm_mask2(
    const bhalf* __restrict__ M, const bhalf* __restrict__ wt,  // W1T@0, W2T@4096
    const float* __restrict__ b1, const float* __restrict__ b2,
    bhalf* __restrict__ T1o, bhalf* __restrict__ T2o)
{
  __shared__ __align__(16) char smem[9216 * 2 + 17408];
  bhalf* WT1 = (bhalf*)smem;               // [64][72]
  bhalf* WT2 = (bhalf*)(smem + 9216);      // [64][72]
  float* Cs  = (float*)(smem + 18432);     // [64][68] transpose buffer
  bhalf* Ab  = (bhalf*)(smem + 18432);     // [64][72] f16 A relayout (aliases Cs)
  __shared__ float b1s[64], b2s[64];
  int t = threadIdx.x;
  {
    const uint4* ws = (const uint4*)wt;    // 1024 uint4: W1 then W2
    #pragma unroll
    for (int i = 0; i < 4; ++i) {
      int idx4 = i * 256 + t;
      int n = (idx4 >> 3) & 63, q4 = idx4 & 7;
      uint4* wd = (idx4 < 512) ? (uint4*)WT1 : (uint4*)WT2;
      wd[n * 9 + q4] = ws[idx4];
    }
    if (t < 64) { b1s[t] = b1[t]; b2s[t] = b2[t]; }
  }
  __syncthreads();

  int wv = t >> 6, lane = t & 63;
  int lm = lane & 15, q = lane >> 4;
  size_t row0 = ((size_t)blockIdx.x << 6) + (wv << 4);
  int rr = t >> 2, c0 = (t & 3) << 4;
  size_t grow = ((size_t)blockIdx.x << 6) + rr;

  // pass 1: m1 = M @ W1
  const bhalf* arow = M + ((row0 + lm) << 6) + (q << 3);
  f16x8 a0 = *(const f16x8*)(arow);
  f16x8 a1 = *(const f16x8*)(arow + 32);
  f32x4 acc[4];
  #pragma unroll
  for (int nt = 0; nt < 4; ++nt) {
    const bhalf* bp_ = &WT1[(nt * 16 + lm) * 72 + (q << 3)];
    f16x8 bv0 = *(const f16x8*)(bp_);
    f16x8 bv1 = *(const f16x8*)(bp_ + 32);
    f32x4 c = {0.f, 0.f, 0.f, 0.f};
    c = __builtin_amdgcn_mfma_f32_16x16x32_f16(a0, bv0, c, 0, 0, 0);
    c = __builtin_amdgcn_mfma_f32_16x16x32_f16(a1, bv1, c, 0, 0, 0);
    acc[nt] = c;
  }
  #pragma unroll
  for (int nt = 0; nt < 4; ++nt)
    #pragma unroll
    for (int r = 0; r < 4; ++r)
      Cs[((wv << 4) + (q << 2) + r) * 68 + (nt << 4) + lm] = acc[nt][r];
  __syncthreads();
  float v[16];
  #pragma unroll
  for (int j = 0; j < 4; ++j) {
    float4 u = *(const float4*)&Cs[rr * 68 + c0 + 4 * j];
    v[4*j] = u.x; v[4*j+1] = u.y; v[4*j+2] = u.z; v[4*j+3] = u.w;
  }
  #pragma unroll
  for (int j = 0; j < 16; ++j) v[j] += b1s[c0 + j];
  uint4 p0 = pack16(v), p1 = pack16(v + 8);
  bhalf* ob1 = T1o + (grow << 6) + c0;
  ((uint4*)ob1)[0] = p0; ((uint4*)ob1)[1] = p1;
  __syncthreads();                       // all Cs reads done before Ab overwrite
  *(uint4*)&Ab[rr * 72 + c0]     = p0;   // 144B row stride: 16B-aligned
  *(uint4*)&Ab[rr * 72 + c0 + 8] = p1;
  __syncthreads();

  // pass 2: m2 = m1(f16) @ W2
  const bhalf* ar2 = &Ab[((wv << 4) + lm) * 72 + (q << 3)];
  f16x8 c0v = *(const f16x8*)(ar2);
  f16x8 c1v = *(const f16x8*)(ar2 + 32);
  #pragma unroll
  for (int nt = 0; nt < 4; ++nt) {
    const bhalf* bp_ = &WT2[(nt * 16 + lm) * 72 + (q << 3)];
    f16x8 bv0 = *(const f16x8*)(bp_);
    f16x8 bv1 = *(const f16x8*)(bp_ + 32);
    f32x4 c = {0.f, 0.f, 0.f, 0.f};
    c = __builtin_amdgcn_mfma_f32_16x16x32_f16(c0v, bv0, c, 0, 0, 0);
    c = __builtin_amdgcn_mfma_f32_16x16x32_f16(c1v, bv1, c, 0, 0, 0);
    acc[nt] = c;
  }
  __syncthreads();                       // Ab reads done before Cs overwrite
  #pragma unroll
  for (int nt = 0; nt < 4; ++nt)
    #pragma unroll
    for (int r = 0; r < 4; ++r)
      Cs[((wv << 4) + (q << 2) + r) * 68 + (nt << 4) + lm] = acc[nt][r];
  __syncthreads();
  #pragma unroll
  for (int j = 0; j < 4; ++j) {
    float4 u = *(const float4*)&Cs[rr * 68 + c0 + 4 * j];
    v[4*j] = u.x; v[4*j+1] = u.y; v[4*j+2] = u.z; v[4*j+3] = u.w;
  }
  #pragma unroll
  for (int j = 0; j < 16; ++j) v[j] += b2s[c0 + j];
  bhalf* ob2 = T2o + (grow << 6) + c0;
  ((uint4*)ob2)[0] = pack16(v);
  ((uint4*)ob2)[1] = pack16(v + 8);
}

// ---------------- MFMA GEMM 64x64, residual epilogue ----------------
// BW=1: weight blob is per-batch (4096 f16 each), selected by blockIdx>>10.
#define EP_BIAS 1
#define EP_RESID 5  // fp32 out_(X) += result + bias + aux(P f16); writes xbout

template<int EP, int BW>
__global__ __launch_bounds__(256) void gemm64m(
    const bhalf* __restrict__ in_, const bhalf* __restrict__ wt,
    const float* __restrict__ bias, void* __restrict__ out_,
    const bhalf* __restrict__ aux, bhalf* __restrict__ xbout)
{
  __shared__ __align__(16) char smem[64 * 68 * 4];  // WT (9.2KB) then Cs (17.4KB)
  bhalf* WT = (bhalf*)smem;         // W^T, [n][k] stride 72
  float* Cs = (float*)smem;         // epilogue transpose buffer, stride 68
  __shared__ float bias_s[64];
  int t = threadIdx.x;
  if (BW) wt += (size_t)(blockIdx.x >> 10) << 12;
  {
    const uint4* ws = (const uint4*)wt;
    uint4* wd = (uint4*)WT;
    #pragma unroll
    for (int i = 0; i < 2; ++i) {
      int idx4 = i * 256 + t;               // 512 uint4 total; row = 8 uint4
      int n = idx4 >> 3, q4 = idx4 & 7;
      wd[n * 9 + q4] = ws[idx4];            // LDS row stride 72 f16 = 9 uint4
    }
    if (t < 64) bias_s[t] = bias[t];
  }
  __syncthreads();

  int wv = t >> 6, lane = t & 63;
  int lm = lane & 15, q = lane >> 4;
  size_t row0 = ((size_t)blockIdx.x << 6) + (wv << 4);

  const bhalf* arow = in_ + ((row0 + lm) << 6) + (q << 3);
  f16x8 a0 = *(const f16x8*)(arow);
  f16x8 a1 = *(const f16x8*)(arow + 32);

  f32x4 acc[4];
  #pragma unroll
  for (int nt = 0; nt < 4; ++nt) {
    const bhalf* bp_ = &WT[(nt * 16 + lm) * 72 + (q << 3)];
    f16x8 b0 = *(const f16x8*)(bp_);
    f16x8 b1 = *(const f16x8*)(bp_ + 32);
    f32x4 c = {0.f, 0.f, 0.f, 0.f};
    c = __builtin_amdgcn_mfma_f32_16x16x32_f16(a0, b0, c, 0, 0, 0);
    c = __builtin_amdgcn_mfma_f32_16x16x32_f16(a1, b1, c, 0, 0, 0);
    acc[nt] = c;
  }
  __syncthreads();   // all waves done with WT before Cs overwrites it
  #pragma unroll
  for (int nt = 0; nt < 4; ++nt)
    #pragma unroll
    for (int r = 0; r < 4; ++r)
      Cs[((wv << 4) + (q << 2) + r) * 68 + (nt << 4) + lm] = acc[nt][r];
  __syncthreads();

  int rr = t >> 2, c0 = (t & 3) << 4;
  size_t grow = ((size_t)blockIdx.x << 6) + rr;
  float v[16];
  #pragma unroll
  for (int j = 0; j < 4; ++j) {
    float4 u = *(const float4*)&Cs[rr * 68 + c0 + 4 * j];
    v[4*j] = u.x; v[4*j+1] = u.y; v[4*j+2] = u.z; v[4*j+3] = u.w;
  }

  if (EP == EP_RESID) {
    float* xr = (float*)out_ + (grow << 6) + c0;
    const bhalf* pr = aux + (grow << 6) + c0;
    uint4 p0 = ((const uint4*)pr)[0], p1 = ((const uint4*)pr)[1];
    float pf[16];
    unpack8h(p0, pf); unpack8h(p1, pf + 8);
    #pragma unroll
    for (int j = 0; j < 4; ++j) {
      float4* x4 = (float4*)(xr + 4 * j);
      float4 u = *x4;
      u.x += v[4*j]   + bias_s[c0 + 4*j]     + pf[4*j];
      u.y += v[4*j+1] + bias_s[c0 + 4*j + 1] + pf[4*j+1];
      u.z += v[4*j+2] + bias_s[c0 + 4*j + 2] + pf[4*j+2];
      u.w += v[4*j+3] + bias_s[c0 + 4*j + 3] + pf[4*j+3];
      *x4 = u;
      v[4*j] = u.x; v[4*j+1] = u.y; v[4*j+2] = u.z; v[4*j+3] = u.w;
    }
    bhalf* xb = xbout + (grow << 6) + c0;
    ((uint4*)xb)[0] = pack16(v);
    ((uint4*)xb)[1] = pack16(v + 8);
  } else {  // EP_BIAS
    #pragma unroll
    for (int j = 0; j < 16; ++j) v[j] += bias_s[c0 + j];
    bhalf* ob = (bhalf*)out_ + (grow << 6) + c0;
    ((uint4*)ob)[0] = pack16(v);
    ((uint4*)ob)[1] = pack16(v + 8);
  }
}

// ---------------- fused QKV + channel-attention partials ----------------
// [131072x64] @ [64x192]; wt rows 0-63=Q, 64-127=K, 128-191=V.
// Q/K tiles stay in LDS (stride-72 padded: staging writes <=2-way banked).
// S-tail: lane=(h,dg,eg) accumulates a 4x4 accS tile over its wave's OWN 16
// rows; wave partials summed in LDS (aliasing dead Cs); 1024 atomics/block.
__global__ __launch_bounds__(256) void qkv_gemm(
    const bhalf* __restrict__ xb, const bhalf* __restrict__ wt,
    const bhalf* __restrict__ ma, bhalf* __restrict__ Vb,
    bhalf* __restrict__ VG, float* __restrict__ S)
{
  // WT 0..27647 (192x72 f16, dead after MFMA loop); Cs aliases 0..17407;
  // Sw (wave S partials, 16KB) aliases 0..16383; Ks @17408 (WT tail, 9216B);
  // Qs @27648 (9216B). Total 36864.
  __shared__ __align__(16) char smem[36864];
  bhalf* WT = (bhalf*)smem;
  float* Cs = (float*)smem;
  float* Sw = (float*)smem;             // [4 waves][1024] f32
  bhalf* Ks = (bhalf*)(smem + 17408);   // [64][72] f16
  bhalf* Qs = (bhalf*)(smem + 27648);   // [64][72] f16
  int t = threadIdx.x;
  {
    const uint4* ws = (const uint4*)wt;
    uint4* wd = (uint4*)WT;
    #pragma unroll
    for (int i = 0; i < 6; ++i) {
      int idx4 = i * 256 + t;               // 1536 uint4
      int n = idx4 >> 3, q4 = idx4 & 7;
      wd[n * 9 + q4] = ws[idx4];
    }
  }
  __syncthreads();

  int wv_ = t >> 6, lane = t & 63;
  int lm = lane & 15, q = lane >> 4;
  size_t row0 = ((size_t)blockIdx.x << 6) + (wv_ << 4);
  const bhalf* arow = xb + ((row0 + lm) << 6) + (q << 3);
  f16x8 a0 = *(const f16x8*)(arow);
  f16x8 a1 = *(const f16x8*)(arow + 32);

  f32x4 acc[12];
  #pragma unroll
  for (int nt = 0; nt < 12; ++nt) {
    const bhalf* bp_ = &WT[(nt * 16 + lm) * 72 + (q << 3)];
    f16x8 b0 = *(const f16x8*)(bp_);
    f16x8 b1 = *(const f16x8*)(bp_ + 32);
    f32x4 c = {0.f, 0.f, 0.f, 0.f};
    c = __builtin_amdgcn_mfma_f32_16x16x32_f16(a0, b0, c, 0, 0, 0);
    c = __builtin_amdgcn_mfma_f32_16x16x32_f16(a1, b1, c, 0, 0, 0);
    acc[nt] = c;
  }

  int rr = t >> 2, c0 = (t & 3) << 4;
  size_t grow = ((size_t)blockIdx.x << 6) + rr;
  #pragma unroll
  for (int g = 0; g < 3; ++g) {
    __syncthreads();
    #pragma unroll
    for (int nt = 0; nt < 4; ++nt)
      #pragma unroll
      for (int r = 0; r < 4; ++r)
        Cs[((wv_ << 4) + (q << 2) + r) * 68 + (nt << 4) + lm] = acc[g * 4 + nt][r];
    __syncthreads();
    float v[16];
    #pragma unroll
    for (int j = 0; j < 4; ++j) {
      float4 u = *(const float4*)&Cs[rr * 68 + c0 + 4 * j];
      v[4*j] = u.x; v[4*j+1] = u.y; v[4*j+2] = u.z; v[4*j+3] = u.w;
    }
    uint4 o0 = pack16(v), o1 = pack16(v + 8);
    if (g == 0) {
      *(uint4*)&Qs[rr * 72 + c0] = o0;
      *(uint4*)&Qs[rr * 72 + c0 + 8] = o1;
    } else if (g == 1) {
      *(uint4*)&Ks[rr * 72 + c0] = o0;
      *(uint4*)&Ks[rr * 72 + c0 + 8] = o1;
    } else {
      bhalf* ob = Vb + (grow << 6) + c0;
      ((uint4*)ob)[0] = o0;
      ((uint4*)ob)[1] = o1;
      const bhalf* mr = ma + (grow << 6) + c0;
      uint4 m0 = ((const uint4*)mr)[0], m1q = ((const uint4*)mr)[1];
      float mf[16];
      unpack8h(m0, mf); unpack8h(m1q, mf + 8);
      float gv[16];
      #pragma unroll
      for (int j = 0; j < 16; ++j) gv[j] = v[j] * mf[j];
      bhalf* gb = VG + (grow << 6) + c0;
      ((uint4*)gb)[0] = pack16(gv);
      ((uint4*)gb)[1] = pack16(gv + 8);
    }
  }

  // ---- attention partials: lane = (h, dg, eg); wave covers rows wv*16..+15 ----
  int h = lane >> 4, dg = (lane >> 2) & 3, eg = lane & 3;
  float accS[16];
  float qssv[4] = {0.f, 0.f, 0.f, 0.f};
  float kssv[4] = {0.f, 0.f, 0.f, 0.f};
  #pragma unroll
  for (int k = 0; k < 16; ++k) accS[k] = 0.f;
  {
    int r0 = wv_ << 4;
    #pragma unroll
    for (int rr2 = 0; rr2 < 16; ++rr2) {
      int r = r0 + rr2;
      uint2 ku = *(const uint2*)&Ks[r * 72 + (h << 4) + (dg << 2)];
      uint2 qu = *(const uint2*)&Qs[r * 72 + (h << 4) + (eg << 2)];
      float kf[4], qf[4];
      unpack2h(ku.x, kf[0], kf[1]); unpack2h(ku.y, kf[2], kf[3]);
      unpack2h(qu.x, qf[0], qf[1]); unpack2h(qu.y, qf[2], qf[3]);
      #pragma unroll
      for (int i = 0; i < 4; ++i)
        #pragma unroll
        for (int j = 0; j < 4; ++j)
          accS[i * 4 + j] += kf[i] * qf[j];
      #pragma unroll
      for (int j = 0; j < 4; ++j) qssv[j] += qf[j] * qf[j];
      #pragma unroll
      for (int i = 0; i < 4; ++i) kssv[i] += kf[i] * kf[i];
    }
  }
  __syncthreads();   // all g=2 Cs reads done; Sw may overwrite Cs
  {
    float* swp = Sw + (wv_ << 10) + (h << 8);
    #pragma unroll
    for (int i = 0; i < 4; ++i) {
      float4 sv = { accS[i*4], accS[i*4+1], accS[i*4+2], accS[i*4+3] };
      *(float4*)&swp[((dg << 2) + i) * 16 + (eg << 2)] = sv;
    }
  }
  __syncthreads();
  int b = (int)(blockIdx.x >> 10);
  float* Sc = S + (size_t)(blockIdx.x & (NSPLIT - 1)) * SCOPY;
  {
    int ci = t << 2;
    float4 s = {0.f, 0.f, 0.f, 0.f};
    #pragma unroll
    for (int wv2 = 0; wv2 < 4; ++wv2) {
      float4 u = *(const float4*)&Sw[(wv2 << 10) + ci];
      s.x += u.x; s.y += u.y; s.z += u.z; s.w += u.w;
    }
    float* sp = Sc + b * 1024 + ci;
    atomicAdd(sp + 0, s.x); atomicAdd(sp + 1, s.y);
    atomicAdd(sp + 2, s.z); atomicAdd(sp + 3, s.w);
  }
  if (dg == 0) {
    float* qp = Sc + 2048 + b * 64 + (h << 4) + (eg << 2);
    #pragma unroll
    for (int j = 0; j < 4; ++j) atomicAdd(qp + j, qssv[j]);
  }
  if (eg == 0) {
    float* kp = Sc + 2176 + b * 64 + (h << 4) + (dg << 2);
    #pragma unroll
    for (int i = 0; i < 4; ++i) atomicAdd(kp + i, kssv[i]);
  }
}

// ---------------- FFN gemm1 + fused LayerNorm: ln(X) @ [64x256], GELU ----------------
__global__ __launch_bounds__(256) void ffn_gemm1_ln(
    const float* __restrict__ X, const bhalf* __restrict__ wt,
    const float* __restrict__ g, const float* __restrict__ bb,
    bhalf* __restrict__ out_)
{
  __shared__ __align__(16) char smem[256 * 72 * 2];  // WT 36.9KB; Cs aliased
  bhalf* WT = (bhalf*)smem;
  float* Cs = (float*)smem;
  __shared__ float gs[64], bs[64];
  int t = threadIdx.x;
  {
    const uint4* ws = (const uint4*)wt;
    uint4* wd = (uint4*)WT;
    #pragma unroll
    for (int i = 0; i < 8; ++i) {
      int idx4 = i * 256 + t;               // 2048 uint4
      int n = idx4 >> 3, q4 = idx4 & 7;
      wd[n * 9 + q4] = ws[idx4];
    }
    if (t < 64) { gs[t] = g[t]; bs[t] = bb[t]; }
  }
  __syncthreads();

  int wv_ = t >> 6, lane = t & 63;
  int lm = lane & 15, q = lane >> 4;
  size_t row0 = ((size_t)blockIdx.x << 6) + (wv_ << 4);
  // A-fragment rows from fp32 X, with in-register LayerNorm.
  const float* xr = X + ((row0 + lm) << 6);
  int k0 = q << 3;
  float xa[8], xb2[8];
  {
    float4 u0 = *(const float4*)(xr + k0);
    float4 u1 = *(const float4*)(xr + k0 + 4);
    float4 u2 = *(const float4*)(xr + 32 + k0);
    float4 u3 = *(const float4*)(xr + 32 + k0 + 4);
    xa[0]=u0.x; xa[1]=u0.y; xa[2]=u0.z; xa[3]=u0.w;
    xa[4]=u1.x; xa[5]=u1.y; xa[6]=u1.z; xa[7]=u1.w;
    xb2[0]=u2.x; xb2[1]=u2.y; xb2[2]=u2.z; xb2[3]=u2.w;
    xb2[4]=u3.x; xb2[5]=u3.y; xb2[6]=u3.z; xb2[7]=u3.w;
  }
  float s1 = 0.f, s2 = 0.f;
  #pragma unroll
  for (int j = 0; j < 8; ++j) {
    s1 += xa[j] + xb2[j];
    s2 += xa[j] * xa[j] + xb2[j] * xb2[j];
  }
  s1 += __shfl_xor(s1, 16); s1 += __shfl_xor(s1, 32);
  s2 += __shfl_xor(s2, 16); s2 += __shfl_xor(s2, 32);
  float mu = s1 * 0.015625f;
  float var = s2 * 0.015625f - mu * mu;
  float rstd = rsqrtf(var + 1e-5f);
  f16x8 a0, a1;
  #pragma unroll
  for (int j = 0; j < 8; ++j) {
    a0[j] = (_Float16)((xa[j]  - mu) * rstd * gs[k0 + j]      + bs[k0 + j]);
    a1[j] = (_Float16)((xb2[j] - mu) * rstd * gs[32 + k0 + j] + bs[32 + k0 + j]);
  }

  f32x4 acc[16];
  #pragma unroll
  for (int nt = 0; nt < 16; ++nt) {
    const bhalf* bp_ = &WT[(nt * 16 + lm) * 72 + (q << 3)];
    f16x8 b0 = *(const f16x8*)(bp_);
    f16x8 b1 = *(const f16x8*)(bp_ + 32);
    f32x4 c = {0.f, 0.f, 0.f, 0.f};
    c = __builtin_amdgcn_mfma_f32_16x16x32_f16(a0, b0, c, 0, 0, 0);
    c = __builtin_amdgcn_mfma_f32_16x16x32_f16(a1, b1, c, 0, 0, 0);
    acc[nt] = c;
  }

  int rr = t >> 2, c0 = (t & 3) << 4;
  size_t grow = ((size_t)blockIdx.x << 6) + rr;
  #pragma unroll
  for (int gi = 0; gi < 4; ++gi) {
    __syncthreads();
    #pragma unroll
    for (int nt = 0; nt < 4; ++nt)
      #pragma unroll
      for (int r = 0; r < 4; ++r)
        Cs[((wv_ << 4) + (q << 2) + r) * 68 + (nt << 4) + lm] = acc[gi * 4 + nt][r];
    __syncthreads();
    float v[16];
    #pragma unroll
    for (int j = 0; j < 4; ++j) {
      float4 u = *(const float4*)&Cs[rr * 68 + c0 + 4 * j];
      v[4*j]   = gelu_f(u.x); v[4*j+1] = gelu_f(u.y);
      v[4*j+2] = gelu_f(u.z); v[4*j+3] = gelu_f(u.w);
    }
    bhalf* ob = out_ + (grow << 8) + (gi << 6) + c0;
    ((uint4*)ob)[0] = pack16(v);
    ((uint4*)ob)[1] = pack16(v + 8);
  }
}

// ---------------- FFN gemm2: [131072x256] @ [256x64], X += ; writes Xb ----------------
__global__ __launch_bounds__(256) void ffn_gemm2(
    const bhalf* __restrict__ in_, const bhalf* __restrict__ wt,
    float* __restrict__ X, bhalf* __restrict__ Xb)
{
  __shared__ __align__(16) char smem[64 * 264 * 2];  // WT 33.8KB; Cs aliased
  bhalf* WT = (bhalf*)smem;
  float* Cs = (float*)smem;
  int t = threadIdx.x;
  {
    const uint4* ws = (const uint4*)wt;
    uint4* wd = (uint4*)WT;
    #pragma unroll
    for (int i = 0; i < 8; ++i) {
      int idx4 = i * 256 + t;               // 2048 uint4; row = 32 uint4
      int n = idx4 >> 5, q4 = idx4 & 31;
      wd[n * 33 + q4] = ws[idx4];           // LDS row stride 264 f16 = 33 uint4
    }
  }
  __syncthreads();

  int wv_ = t >> 6, lane = t & 63;
  int lm = lane & 15, q = lane >> 4;
  size_t row0 = ((size_t)blockIdx.x << 6) + (wv_ << 4);
  const bhalf* arow = in_ + ((row0 + lm) << 8) + (q << 3);
  f16x8 a[8];
  #pragma unroll
  for (int ch = 0; ch < 8; ++ch) a[ch] = *(const f16x8*)(arow + 32 * ch);

  f32x4 acc[4];
  #pragma unroll
  for (int nt = 0; nt < 4; ++nt) {
    const bhalf* bp_ = &WT[(nt * 16 + lm) * 264 + (q << 3)];
    f32x4 c = {0.f, 0.f, 0.f, 0.f};
    #pragma unroll
    for (int ch = 0; ch < 8; ++ch) {
      f16x8 b = *(const f16x8*)(bp_ + 32 * ch);
      c = __builtin_amdgcn_mfma_f32_16x16x32_f16(a[ch], b, c, 0, 0, 0);
    }
    acc[nt] = c;
  }
  __syncthreads();
  #pragma unroll
  for (int nt = 0; nt < 4; ++nt)
    #pragma unroll
    for (int r = 0; r < 4; ++r)
      Cs[((wv_ << 4) + (q << 2) + r) * 68 + (nt << 4) + lm] = acc[nt][r];
  __syncthreads();

  int rr = t >> 2, c0 = (t & 3) << 4;
  size_t grow = ((size_t)blockIdx.x << 6) + rr;
  float v[16];
  #pragma unroll
  for (int j = 0; j < 4; ++j) {
    float4 u = *(const float4*)&Cs[rr * 68 + c0 + 4 * j];
    v[4*j] = u.x; v[4*j+1] = u.y; v[4*j+2] = u.z; v[4*j+3] = u.w;
  }
  float* xr = X + (grow << 6) + c0;
  #pragma unroll
  for (int j = 0; j < 4; ++j) {
    float4* x4 = (float4*)(xr + 4 * j);
    float4 u = *x4;
    u.x += v[4*j]; u.y += v[4*j+1]; u.z += v[4*j+2]; u.w += v[4*j+3];
    *x4 = u;
    v[4*j] = u.x; v[4*j+1] = u.y; v[4*j+2] = u.z; v[4*j+3] = u.w;
  }
  bhalf* xb = Xb + (grow << 6) + c0;
  ((uint4*)xb)[0] = pack16(v);
  ((uint4*)xb)[1] = pack16(v + 8);
}

// ---------------- depthwise conv KxK SAME, NHWC — 4 x-pixels per thread ----------------
template<int KS, int EPI, int CH>
__global__ __launch_bounds__(256) void dwconv4(
    const bhalf* __restrict__ in, const float* __restrict__ wt,
    const float* __restrict__ db, const bhalf* __restrict__ m1,
    bhalf* __restrict__ out, int wstride)
{
  const int CB = (CH == 64) ? 6 : 8;    // log2(CH)
  const int G  = CH >> 3;               // channel groups per pixel (8 or 32)
  const int GB = (CH == 64) ? 3 : 5;    // log2(G)
  const int R  = KS >> 1;
  const int NCOL = KS + 3;              // window columns for 4 outputs
  __shared__ u32 Wsu[KS * KS * G * 5];  // packed half2 weights, padded stride 5
  __shared__ float db_s[64];
  int t = threadIdx.x;
  for (int idx = t; idx < KS * KS * (CH >> 1); idx += 256) {
    int tap = idx >> (CB - 1), cp = idx & ((CH >> 1) - 1);
    int cg = cp >> 2, j = cp & 3;
    h2 p;
    p[0] = (_Float16)wt[tap * wstride + 2 * cp];
    p[1] = (_Float16)wt[tap * wstride + 2 * cp + 1];
    union { h2 h; u32 u; } cv; cv.h = p;
    Wsu[tap * (G * 5) + cg * 5 + j] = cv.u;
  }
  if (EPI == 2 && t < 64) db_s[t] = db[t];
  __syncthreads();

  size_t gid = (size_t)blockIdx.x * 256 + t;
  int cg = (int)gid & (G - 1);
  int c0 = cg << 3;
  size_t p4 = gid >> GB;                // 4-pixel unit index
  int x0 = ((int)(p4 & 63)) << 2;
  int hy = (int)((p4 >> 6) & 255);
  size_t bb = p4 >> 14;

  h2 zero = {(_Float16)0.0f, (_Float16)0.0f};
  h2 acc[4][4];
  #pragma unroll
  for (int o = 0; o < 4; ++o)
    #pragma unroll
    for (int j = 0; j < 4; ++j) acc[o][j] = zero;

  #pragma unroll
  for (int kh = 0; kh < KS; ++kh) {
    int y = hy + kh - R;
    if ((unsigned)y >= 256u) continue;
    h2 wr[KS][4];
    #pragma unroll
    for (int kw = 0; kw < KS; ++kw) {
      const u32* wp = &Wsu[(kh * KS + kw) * (G * 5) + cg * 5];
      #pragma unroll
      for (int j = 0; j < 4; ++j) {
        union { u32 u; h2 h; } cv; cv.u = wp[j]; wr[kw][j] = cv.h;
      }
    }
    const bhalf* rowp = in + (((((size_t)bb << 8) + (size_t)y) << 8) << CB) + c0;
    #pragma unroll
    for (int cc = 0; cc < NCOL; ++cc) {
      int xw = x0 + cc - R;
      // only edge columns can be OOB: interior columns fold the test away
      if (cc < R || cc >= NCOL - R) {
        if ((unsigned)xw >= 256u) continue;
      }
      union { uint4 u; h2 h[4]; } dv;
      dv.u = *(const uint4*)(rowp + ((size_t)xw << CB));
      #pragma unroll
      for (int kw = 0; kw < KS; ++kw) {
        int o = cc - kw;
        if (o >= 0 && o < 4) {
          #pragma unroll
          for (int j = 0; j < 4; ++j)
            acc[o][j] += dv.h[j] * wr[kw][j];   // v_pk_fma_f16
        }
      }
    }
  }

  size_t p0 = ((((size_t)bb << 8) + (size_t)hy) << 8) + (size_t)x0;
  #pragma unroll
  for (int o = 0; o < 4; ++o) {
    bhalf* op = out + ((p0 + o) << CB) + c0;
    if (EPI == 0) {
      union { h2 h[4]; uint4 u; } sv;
      #pragma unroll
      for (int j = 0; j < 4; ++j) sv.h[j] = acc[o][j];
      *(uint4*)op = sv.u;
    } else if (EPI == 1) {
      float r[8];
      #pragma unroll
      for (int j = 0; j < 4; ++j) {
        r[2*j]   = gelu_f((float)acc[o][j][0]);
        r[2*j+1] = gelu_f((float)acc[o][j][1]);
      }
      *(uint4*)op = pack16(r);
    } else {
      uint4 mu = *(const uint4*)(m1 + ((p0 + o) << CB) + c0);
      float mf[8];
      unpack8h(mu, mf);
      float r[8];
      #pragma unroll
      for (int j = 0; j < 8; ++j) {
        float av = (float)acc[o][j >> 1][j & 1];
        float am = 1.0f / (1.0f + expf(-(av + db_s[c0 + j])));
        r[j] = mf[j] * (am + 1.0f);
      }
      *(uint4*)op = pack16(r);
    }
  }
}

// ---------------- attn softmax + fold into Wp (merged) ----------------
__global__ __launch_bounds__(256) void attn_fold(
    const float* __restrict__ S, const float* __restrict__ resc,
    const bhalf* __restrict__ wpT, bhalf* __restrict__ weffT)
{
  __shared__ float As[1024];     // [h][e][d]
  __shared__ float nqs_s[64];    // [h][d]
  int b = blockIdx.x;            // 2 blocks (batch)
  int t = threadIdx.x;
  if (t < 64) {
    int h = t >> 4, d = t & 15;
    float nqsum = 0.f;
    for (int c = 0; c < NSPLIT; ++c)
      nqsum += S[c * SCOPY + 2048 + b * 64 + h * 16 + d];
    nqs_s[t] = fmaxf(sqrtf(nqsum), 1e-6f);
  }
  __syncthreads();
  if (t < 64) {
    int h = t >> 4, d = t & 15;
    float nksum = 0.f;
    for (int c = 0; c < NSPLIT; ++c)
      nksum += S[c * SCOPY + 2176 + b * 64 + h * 16 + d];
    float nkd = fmaxf(sqrtf(nksum), 1e-6f);
    float r = resc[h];
    float4 s4[4] = {{0,0,0,0},{0,0,0,0},{0,0,0,0},{0,0,0,0}};
    for (int c = 0; c < NSPLIT; ++c) {
      const float4* sp = (const float4*)&S[c * SCOPY + (((b * 4 + h) * 16 + d) << 4)];
      #pragma unroll
      for (int j = 0; j < 4; ++j) {
        float4 u = sp[j];
        s4[j].x += u.x; s4[j].y += u.y; s4[j].z += u.z; s4[j].w += u.w;
      }
    }
    float a[16];
    #pragma unroll
    for (int j = 0; j < 4; ++j) {
      a[4*j]   = s4[j].x * r / (nkd * nqs_s[h * 16 + 4*j]);
      a[4*j+1] = s4[j].y * r / (nkd * nqs_s[h * 16 + 4*j + 1]);
      a[4*j+2] = s4[j].z * r / (nkd * nqs_s[h * 16 + 4*j + 2]);
      a[4*j+3] = s4[j].w * r / (nkd * nqs_s[h * 16 + 4*j + 3]);
    }
    float m = -1e30f;
    #pragma unroll
    for (int e = 0; e < 16; ++e) m = fmaxf(m, a[e]);
    float sum = 0.f;
    #pragma unroll
    for (int e = 0; e < 16; ++e) { a[e] = expf(a[e] - m); sum += a[e]; }
    float inv = 1.0f / sum;
    #pragma unroll
    for (int e = 0; e < 16; ++e)
      As[((h * 16 + e) << 4) + d] = a[e] * inv;
  }
  __syncthreads();
  int m = t & 63, h = t >> 6;    // each thread: one (m, h) pair -> 16 outputs
  const bhalf* wp = wpT + m * 64 + h * 16;
  float wv_[16];
  uint4 w0 = ((const uint4*)wp)[0], w1 = ((const uint4*)wp)[1];
  unpack8h(w0, wv_); unpack8h(w1, wv_ + 8);
  float r2[16];
  #pragma unroll
  for (int e = 0; e < 16; ++e) {
    const float* ar = &As[(h * 16 + e) << 4];
    float s = 0.f;
    #pragma unroll
    for (int d = 0; d < 16; ++d) s += ar[d] * wv_[d];
    r2[e] = s;
  }
  bhalf* dst = weffT + b * 4096 + m * 64 + h * 16;
  ((uint4*)dst)[0] = pack16(r2);
  ((uint4*)dst)[1] = pack16(r2 + 8);
}

// ---------------- host orchestration ----------------
extern "C" void kernel_launch(void* const* d_in, const int* in_sizes, int n_in,
                              void* d_out, int out_size, void* d_ws, size_t ws_size,
                              hipStream_t stream)
{
  (void)in_sizes; (void)n_in; (void)out_size; (void)ws_size;
  const float* x_in    = (const float*)d_in[0];
  const float* mask_in = (const float*)d_in[1];
  const float* Wq    = (const float*)d_in[2];
  const float* Wk    = (const float*)d_in[3];
  const float* Wv    = (const float*)d_in[4];
  const float* resc  = (const float*)d_in[5];
  const float* Wp    = (const float*)d_in[6];
  const float* bp    = (const float*)d_in[7];
  const float* pe1   = (const float*)d_in[8];
  const float* pe2   = (const float*)d_in[9];
  const float* mm_w1 = (const float*)d_in[10];
  const float* mm_b1 = (const float*)d_in[11];
  const float* mm_w2 = (const float*)d_in[12];
  const float* mm_b2 = (const float*)d_in[13];
  const float* mm_dw = (const float*)d_in[14];
  const float* mm_db = (const float*)d_in[15];
  const float* ln_g  = (const float*)d_in[16];
  const float* ln_b  = (const float*)d_in[17];
  const float* ff_w1 = (const float*)d_in[18];
  const float* ff_dw = (const float*)d_in[19];
  const float* ff_w2 = (const float*)d_in[20];

  const size_t NC = 8388608;  // B*N*C
  char* w = (char*)d_ws;
  float* X  = (float*)w; w += NC * 4;   // residual stream, fp32
  bhalf* Xb = (bhalf*)w; w += NC * 2;   // f16 mirror of X
  bhalf* M  = (bhalf*)w; w += NC * 2;   // mask NHWC
  bhalf* Qb = (bhalf*)w; w += NC * 2;   // (dead; spanned by F1)
  bhalf* Kb = (bhalf*)w; w += NC * 2;   // (dead; spanned by F1)
  bhalf* Vb = (bhalf*)w; w += NC * 2;
  bhalf* VG = (bhalf*)w; w += NC * 2;
  bhalf* T1 = (bhalf*)w; w += NC * 2;
  bhalf* T2 = (bhalf*)w; w += NC * 2;
  bhalf* T3 = (bhalf*)w; w += NC * 2;
  bhalf* Pb = (bhalf*)w; w += NC * 2;
  float* Sb    = (float*)w; w += (size_t)NSPLIT * SCOPY * 4;  // split accumulators
  bhalf* WeffT = (bhalf*)w; w += 8192 * 2;                    // per-batch A_bd@Wp
  bhalf* WTg   = (bhalf*)w; w += (size_t)3 * WBLK * 2;        // pre-transposed weights
  (void)Qb; (void)Kb;
  // FFN 256-ch temps alias dead 64-ch buffers.
  bhalf* F1 = Qb;   // [131072 x 256] ffn hidden (spans Qb,Kb,Vb,VG)
  bhalf* F2 = T1;   // [131072 x 256] post-dwconv (spans T1,T2,T3,Pb)

  prep_weights<<<24, 256, 0, stream>>>(mm_w1, mm_w2, Wq, Wk, Wv, Wp, ff_w1, ff_w2, WTg);
  nchw2nhwc<0><<<2048, 256, 0, stream>>>(x_in, X, Xb);
  nchw2nhwc<1><<<2048, 256, 0, stream>>>(mask_in, M, nullptr);

  for (int i = 0; i < 3; ++i) {
    const bhalf* wb = WTg + (size_t)i * WBLK;
    // mask branch: m1 (T1) + m2 (T2) fused; then MA (T3)
    gemm_mask2<<<GEMM_GRID, 256, 0, stream>>>(M, wb + 0, mm_b1 + i*64, mm_b2 + i*64, T1, T2);
    dwconv4<5, 2, 64><<<1024, 256, 0, stream>>>(T2, mm_dw + i*1600, mm_db + i*64, T1, T3, 64);
    // fused QKV + gate + attention partials
    hipMemsetAsync(Sb, 0, NSPLIT * SCOPY * 4, stream);
    qkv_gemm<<<GEMM_GRID, 256, 0, stream>>>(Xb, wb + 8192, T3, Vb, VG, Sb);
    attn_fold<<<2, 256, 0, stream>>>(Sb, resc + i*4, wb + 20480, WeffT);
    // positional branch on ungated V
    dwconv4<3, 1, 64><<<1024, 256, 0, stream>>>(Vb, pe1 + i*576, nullptr, nullptr, T1, 64);
    dwconv4<3, 0, 64><<<1024, 256, 0, stream>>>(T1, pe2 + i*576, nullptr, nullptr, Pb, 64);
    // X += VG@Weff + bp + P; refresh Xb  (attn folded into weights)
    gemm64m<EP_RESID, 1><<<GEMM_GRID, 256, 0, stream>>>(VG, WeffT, bp + i*64, X, Pb, Xb);
    // FFN (full 256 hidden): fused ln+gemm1(gelu) -> dw3(gelu) -> gemm2(acc)
    ffn_gemm1_ln<<<GEMM_GRID, 256, 0, stream>>>(X, wb + 24576, ln_g + i*64, ln_b + i*64, F1);
    dwconv4<3, 1, 256><<<4096, 256, 0, stream>>>(F1, ff_dw + i*2304, nullptr, nullptr, F2, 256);
    ffn_gemm2<<<GEMM_GRID, 256, 0, stream>>>(F2, wb + 40960, X, Xb);
  }
  nhwc2nchw<<<2048, 256, 0, stream>>>(X, (float*)d_out);
}

// Round 7
// 839.762 us; speedup vs baseline: 1.2181x; 1.2181x over previous
//
#include <hip/hip_runtime.h>
#include <math.h>

// HGSA: 3x (mask-guided channel-attention MSA + LN + convFFN) on [2,64,256,256].
// External I/O fp32. Internal activations FP16, residual stream X fp32 (+f16
// mirror Xb), weights f16 in LDS.
// R5: MFMA gemms. R6: staged attn, un-chunked FFN, fused QKV. R7: attn atomic
// 32-way split. R8: weights pre-transposed W^T. R9: dwconv4 (4 px/thread +
// conflict-free weight LDS). R10: bf16 -> fp16 (HW pack/pk_fma).
// R11: attn folded into Wp; mask m1+m2 fused; LN fused into ffn_gemm1.
// R12: attention partials fused INTO qkv_gemm; attn_softmax+fold merged.
// R13 (reverted): LDS-tile tail blew VGPR to 128 (occupancy crash).
// R14: S computed by IN-REGISTER MFMA — the gemm C-layout (lane=col,
// rows=q*4+r) is exactly the A/B fragment layout of mfma_f32_16x16x16f16
// with k=rows, so S16[h] = mfma(f16(accK[h]), f16(accQ[h]), accS[h]).
// Q/K never touch LDS/HBM (Qs/Ks deleted, LDS 27.6KB). 128 rows/block
// (1024 blocks x 2 groups) halves device-atomic count (2.36M -> 1.18M);
// norms from f32 accs via shfl_xor; cross-wave reduce in LDS aliasing WT.
// (R15 = R14 resubmitted: round-6 bench was an infra/container failure;
// audit found no OOB/barrier/ISA defect.)

typedef unsigned short bhalf;            // fp16 bits
typedef unsigned int u32;
typedef _Float16 h2 __attribute__((ext_vector_type(2)));
typedef _Float16 f16x4 __attribute__((ext_vector_type(4)));
typedef _Float16 f16x8 __attribute__((ext_vector_type(8)));
typedef __attribute__((ext_vector_type(4))) float f32x4;

#define GEMM_GRID 2048      // 131072 rows / 64 rows per block
#define NSPLIT 32           // attn accumulator copies
#define SCOPY 2304          // floats per copy: 2048 S + 128 nq + 128 nk
#define WBLK 57344          // f16 per transformer-block weight blob

__device__ __forceinline__ float h2f(bhalf b) {
  union { bhalf u; _Float16 h; } c; c.u = b; return (float)c.h;
}
__device__ __forceinline__ bhalf f2h(float f) {
  union { _Float16 h; bhalf u; } c; c.h = (_Float16)f; return c.u;
}
__device__ __forceinline__ u32 pack2h(float a, float b) {
  auto r = __builtin_amdgcn_cvt_pkrtz(a, b);     // v_cvt_pkrtz_f16_f32, 1 op
  union { decltype(r) h; u32 u; } c; c.h = r; return c.u;
}
__device__ __forceinline__ void unpack2h(u32 p, float& a, float& b) {
  union { u32 u; h2 h; } c; c.u = p;
  a = (float)c.h[0]; b = (float)c.h[1];
}
__device__ __forceinline__ void unpack8h(uint4 u, float* f) {
  unpack2h(u.x, f[0], f[1]); unpack2h(u.y, f[2], f[3]);
  unpack2h(u.z, f[4], f[5]); unpack2h(u.w, f[6], f[7]);
}
__device__ __forceinline__ float gelu_f(float v) {   // exact gelu
  return 0.5f * v * (1.0f + erff(v * 0.70710678118654752440f));
}
__device__ __forceinline__ uint4 pack16(const float* v) {  // 8 floats -> 8 f16
  uint4 s;
  s.x = pack2h(v[0], v[1]); s.y = pack2h(v[2], v[3]);
  s.z = pack2h(v[4], v[5]); s.w = pack2h(v[6], v[7]);
  return s;
}
__device__ __forceinline__ f16x4 cvt4h(f32x4 v) {    // 4 f32 -> f16x4 frag
  union { u32 u[2]; f16x4 h; } c;
  c.u[0] = pack2h(v[0], v[1]); c.u[1] = pack2h(v[2], v[3]);
  return c.h;
}

// ---------------- weight pre-transpose (once per launch, ~2us) ----------------
// For each GEMM weight W[K][N]: WTg[n*K + k] = f16(W[k][n]).
// Per block i: mm1@0, mm2@4096, Q@8192, K@12288, V@16384, P@20480,
//              ff1@24576 ([256][64]), ff2@40960 ([64][256]).
__global__ __launch_bounds__(256) void prep_weights(
    const float* __restrict__ mm_w1, const float* __restrict__ mm_w2,
    const float* __restrict__ Wq, const float* __restrict__ Wk,
    const float* __restrict__ Wv, const float* __restrict__ Wp,
    const float* __restrict__ ff_w1, const float* __restrict__ ff_w2,
    bhalf* __restrict__ out)
{
  int i = blockIdx.x >> 3, slot = blockIdx.x & 7;
  int t = threadIdx.x;
  const float* src; int ksh, N; size_t off;
  switch (slot) {
    case 0:  src = mm_w1 + i*4096;  ksh=6; N=64;  off = 0;     break;
    case 1:  src = mm_w2 + i*4096;  ksh=6; N=64;  off = 4096;  break;
    case 2:  src = Wq + i*4096;     ksh=6; N=64;  off = 8192;  break;
    case 3:  src = Wk + i*4096;     ksh=6; N=64;  off = 12288; break;
    case 4:  src = Wv + i*4096;     ksh=6; N=64;  off = 16384; break;
    case 5:  src = Wp + i*4096;     ksh=6; N=64;  off = 20480; break;
    case 6:  src = ff_w1 + i*16384; ksh=6; N=256; off = 24576; break;
    default: src = ff_w2 + i*16384; ksh=8; N=64;  off = 40960; break;
  }
  bhalf* dst = out + (size_t)i * WBLK + off;
  int sz = N << ksh;
  int kmask = (1 << ksh) - 1;
  for (int idx = t; idx < sz; idx += 256) {
    int n = idx >> ksh, k = idx & kmask;
    dst[idx] = f2h(src[k * N + n]);
  }
}

// ---------------- transposes ----------------
template<int MODE>   // 0: x -> fp32 X AND f16 Xb.  1: mask -> f16 only.
__global__ __launch_bounds__(256) void nchw2nhwc(const float* __restrict__ in,
                                                 void* __restrict__ out,
                                                 bhalf* __restrict__ out2) {
  __shared__ float tile[64][65];
  int t = threadIdx.x;
  int b = blockIdx.x >> 10;
  int n0 = (blockIdx.x & 1023) << 6;
  #pragma unroll
  for (int j = 0; j < 16; ++j) {
    int idx = j * 256 + t;
    int c = idx >> 6, nn = idx & 63;
    tile[c][nn] = in[(((size_t)(b * 64 + c)) << 16) + n0 + nn];
  }
  __syncthreads();
  #pragma unroll
  for (int j = 0; j < 16; ++j) {
    int idx = j * 256 + t;
    int nn = idx >> 6, c = idx & 63;
    size_t o = ((((size_t)b << 16) + n0 + nn) << 6) + c;
    float v = tile[c][nn];
    if (MODE == 0) { ((float*)out)[o] = v; out2[o] = f2h(v); }
    else           { ((bhalf*)out)[o] = f2h(v); }
  }
}

__global__ __launch_bounds__(256) void nhwc2nchw(const float* __restrict__ in,
                                                 float* __restrict__ out) {
  __shared__ float tile[64][65];
  int t = threadIdx.x;
  int b = blockIdx.x >> 10;
  int n0 = (blockIdx.x & 1023) << 6;
  #pragma unroll
  for (int j = 0; j < 16; ++j) {
    int idx = j * 256 + t;
    int nn = idx >> 6, c = idx & 63;
    tile[c][nn] = in[((((size_t)b << 16) + n0 + nn) << 6) + c];
  }
  __syncthreads();
  #pragma unroll
  for (int j = 0; j < 16; ++j) {
    int idx = j * 256 + t;
    int c = idx >> 6, nn = idx & 63;
    out[(((size_t)(b * 64 + c)) << 16) + n0 + nn] = tile[c][nn];
  }
}

// ---------------- fused mask GEMMs: m1 = M@W1+b1 ; m2 = m1@W2+b2 ----------------
__global__ __launch_bounds__(256) void gemm_mask2(
    const bhalf* __restrict__ M, const bhalf* __restrict__ wt,  // W1T@0, W2T@4096
    const float* __restrict__ b1, const float* __restrict__ b2,
    bhalf* __restrict__ T1o, bhalf* __restrict__ T2o)
{
  __shared__ __align__(16) char smem[9216 * 2 + 17408];
  bhalf* WT1 = (bhalf*)smem;               // [64][72]
  bhalf* WT2 = (bhalf*)(smem + 9216);      // [64][72]
  float* Cs  = (float*)(smem + 18432);     // [64][68] transpose buffer
  bhalf* Ab  = (bhalf*)(smem + 18432);     // [64][72] f16 A relayout (aliases Cs)
  __shared__ float b1s[64], b2s[64];
  int t = threadIdx.x;
  {
    const uint4* ws = (const uint4*)wt;    // 1024 uint4: W1 then W2
    #pragma unroll
    for (int i = 0; i < 4; ++i) {
      int idx4 = i * 256 + t;
      int n = (idx4 >> 3) & 63, q4 = idx4 & 7;
      uint4* wd = (idx4 < 512) ? (uint4*)WT1 : (uint4*)WT2;
      wd[n * 9 + q4] = ws[idx4];
    }
    if (t < 64) { b1s[t] = b1[t]; b2s[t] = b2[t]; }
  }
  __syncthreads();

  int wv = t >> 6, lane = t & 63;
  int lm = lane & 15, q = lane >> 4;
  size_t row0 = ((size_t)blockIdx.x << 6) + (wv << 4);
  int rr = t >> 2, c0 = (t & 3) << 4;
  size_t grow = ((size_t)blockIdx.x << 6) + rr;

  // pass 1: m1 = M @ W1
  const bhalf* arow = M + ((row0 + lm) << 6) + (q << 3);
  f16x8 a0 = *(const f16x8*)(arow);
  f16x8 a1 = *(const f16x8*)(arow + 32);
  f32x4 acc[4];
  #pragma unroll
  for (int nt = 0; nt < 4; ++nt) {
    const bhalf* bp_ = &WT1[(nt * 16 + lm) * 72 + (q << 3)];
    f16x8 bv0 = *(const f16x8*)(bp_);
    f16x8 bv1 = *(const f16x8*)(bp_ + 32);
    f32x4 c = {0.f, 0.f, 0.f, 0.f};
    c = __builtin_amdgcn_mfma_f32_16x16x32_f16(a0, bv0, c, 0, 0, 0);
    c = __builtin_amdgcn_mfma_f32_16x16x32_f16(a1, bv1, c, 0, 0, 0);
    acc[nt] = c;
  }
  #pragma unroll
  for (int nt = 0; nt < 4; ++nt)
    #pragma unroll
    for (int r = 0; r < 4; ++r)
      Cs[((wv << 4) + (q << 2) + r) * 68 + (nt << 4) + lm] = acc[nt][r];
  __syncthreads();
  float v[16];
  #pragma unroll
  for (int j = 0; j < 4; ++j) {
    float4 u = *(const float4*)&Cs[rr * 68 + c0 + 4 * j];
    v[4*j] = u.x; v[4*j+1] = u.y; v[4*j+2] = u.z; v[4*j+3] = u.w;
  }
  #pragma unroll
  for (int j = 0; j < 16; ++j) v[j] += b1s[c0 + j];
  uint4 p0 = pack16(v), p1 = pack16(v + 8);
  bhalf* ob1 = T1o + (grow << 6) + c0;
  ((uint4*)ob1)[0] = p0; ((uint4*)ob1)[1] = p1;
  __syncthreads();                       // all Cs reads done before Ab overwrite
  *(uint4*)&Ab[rr * 72 + c0]     = p0;   // 144B row stride: 16B-aligned
  *(uint4*)&Ab[rr * 72 + c0 + 8] = p1;
  __syncthreads();

  // pass 2: m2 = m1(f16) @ W2
  const bhalf* ar2 = &Ab[((wv << 4) + lm) * 72 + (q << 3)];
  f16x8 c0v = *(const f16x8*)(ar2);
  f16x8 c1v = *(const f16x8*)(ar2 + 32);
  #pragma unroll
  for (int nt = 0; nt < 4; ++nt) {
    const bhalf* bp_ = &WT2[(nt * 16 + lm) * 72 + (q << 3)];
    f16x8 bv0 = *(const f16x8*)(bp_);
    f16x8 bv1 = *(const f16x8*)(bp_ + 32);
    f32x4 c = {0.f, 0.f, 0.f, 0.f};
    c = __builtin_amdgcn_mfma_f32_16x16x32_f16(c0v, bv0, c, 0, 0, 0);
    c = __builtin_amdgcn_mfma_f32_16x16x32_f16(c1v, bv1, c, 0, 0, 0);
    acc[nt] = c;
  }
  __syncthreads();                       // Ab reads done before Cs overwrite
  #pragma unroll
  for (int nt = 0; nt < 4; ++nt)
    #pragma unroll
    for (int r = 0; r < 4; ++r)
      Cs[((wv << 4) + (q << 2) + r) * 68 + (nt << 4) + lm] = acc[nt][r];
  __syncthreads();
  #pragma unroll
  for (int j = 0; j < 4; ++j) {
    float4 u = *(const float4*)&Cs[rr * 68 + c0 + 4 * j];
    v[4*j] = u.x; v[4*j+1] = u.y; v[4*j+2] = u.z; v[4*j+3] = u.w;
  }
  #pragma unroll
  for (int j = 0; j < 16; ++j) v[j] += b2s[c0 + j];
  bhalf* ob2 = T2o + (grow << 6) + c0;
  ((uint4*)ob2)[0] = pack16(v);
  ((uint4*)ob2)[1] = pack16(v + 8);
}

// ---------------- MFMA GEMM 64x64, residual epilogue ----------------
// BW=1: weight blob is per-batch (4096 f16 each), selected by blockIdx>>10.
#define EP_BIAS 1
#define EP_RESID 5  // fp32 out_(X) += result + bias + aux(P f16); writes xbout

template<int EP, int BW>
__global__ __launch_bounds__(256) void gemm64m(
    const bhalf* __restrict__ in_, const bhalf* __restrict__ wt,
    const float* __restrict__ bias, void* __restrict__ out_,
    const bhalf* __restrict__ aux, bhalf* __restrict__ xbout)
{
  __shared__ __align__(16) char smem[64 * 68 * 4];  // WT (9.2KB) then Cs (17.4KB)
  bhalf* WT = (bhalf*)smem;         // W^T, [n][k] stride 72
  float* Cs = (float*)smem;         // epilogue transpose buffer, stride 68
  __shared__ float bias_s[64];
  int t = threadIdx.x;
  if (BW) wt += (size_t)(blockIdx.x >> 10) << 12;
  {
    const uint4* ws = (const uint4*)wt;
    uint4* wd = (uint4*)WT;
    #pragma unroll
    for (int i = 0; i < 2; ++i) {
      int idx4 = i * 256 + t;               // 512 uint4 total; row = 8 uint4
      int n = idx4 >> 3, q4 = idx4 & 7;
      wd[n * 9 + q4] = ws[idx4];            // LDS row stride 72 f16 = 9 uint4
    }
    if (t < 64) bias_s[t] = bias[t];
  }
  __syncthreads();

  int wv = t >> 6, lane = t & 63;
  int lm = lane & 15, q = lane >> 4;
  size_t row0 = ((size_t)blockIdx.x << 6) + (wv << 4);

  const bhalf* arow = in_ + ((row0 + lm) << 6) + (q << 3);
  f16x8 a0 = *(const f16x8*)(arow);
  f16x8 a1 = *(const f16x8*)(arow + 32);

  f32x4 acc[4];
  #pragma unroll
  for (int nt = 0; nt < 4; ++nt) {
    const bhalf* bp_ = &WT[(nt * 16 + lm) * 72 + (q << 3)];
    f16x8 b0 = *(const f16x8*)(bp_);
    f16x8 b1 = *(const f16x8*)(bp_ + 32);
    f32x4 c = {0.f, 0.f, 0.f, 0.f};
    c = __builtin_amdgcn_mfma_f32_16x16x32_f16(a0, b0, c, 0, 0, 0);
    c = __builtin_amdgcn_mfma_f32_16x16x32_f16(a1, b1, c, 0, 0, 0);
    acc[nt] = c;
  }
  __syncthreads();   // all waves done with WT before Cs overwrites it
  #pragma unroll
  for (int nt = 0; nt < 4; ++nt)
    #pragma unroll
    for (int r = 0; r < 4; ++r)
      Cs[((wv << 4) + (q << 2) + r) * 68 + (nt << 4) + lm] = acc[nt][r];
  __syncthreads();

  int rr = t >> 2, c0 = (t & 3) << 4;
  size_t grow = ((size_t)blockIdx.x << 6) + rr;
  float v[16];
  #pragma unroll
  for (int j = 0; j < 4; ++j) {
    float4 u = *(const float4*)&Cs[rr * 68 + c0 + 4 * j];
    v[4*j] = u.x; v[4*j+1] = u.y; v[4*j+2] = u.z; v[4*j+3] = u.w;
  }

  if (EP == EP_RESID) {
    float* xr = (float*)out_ + (grow << 6) + c0;
    const bhalf* pr = aux + (grow << 6) + c0;
    uint4 p0 = ((const uint4*)pr)[0], p1 = ((const uint4*)pr)[1];
    float pf[16];
    unpack8h(p0, pf); unpack8h(p1, pf + 8);
    #pragma unroll
    for (int j = 0; j < 4; ++j) {
      float4* x4 = (float4*)(xr + 4 * j);
      float4 u = *x4;
      u.x += v[4*j]   + bias_s[c0 + 4*j]     + pf[4*j];
      u.y += v[4*j+1] + bias_s[c0 + 4*j + 1] + pf[4*j+1];
      u.z += v[4*j+2] + bias_s[c0 + 4*j + 2] + pf[4*j+2];
      u.w += v[4*j+3] + bias_s[c0 + 4*j + 3] + pf[4*j+3];
      *x4 = u;
      v[4*j] = u.x; v[4*j+1] = u.y; v[4*j+2] = u.z; v[4*j+3] = u.w;
    }
    bhalf* xb = xbout + (grow << 6) + c0;
    ((uint4*)xb)[0] = pack16(v);
    ((uint4*)xb)[1] = pack16(v + 8);
  } else {  // EP_BIAS
    #pragma unroll
    for (int j = 0; j < 16; ++j) v[j] += bias_s[c0 + j];
    bhalf* ob = (bhalf*)out_ + (grow << 6) + c0;
    ((uint4*)ob)[0] = pack16(v);
    ((uint4*)ob)[1] = pack16(v + 8);
  }
}

// ---------------- fused QKV + in-register channel-attention partials ----------------
// 1024 blocks x 128 rows (2 groups of 64). wt rows 0-63=Q, 64-127=K, 128-191=V.
// Q/K live only in accumulators: S16[h] += mfma_16x16x16(f16(accK[h]),
// f16(accQ[h])) — the gemm C-layout (lane=col, rows q*4+r) IS the A/B frag
// layout with k=rows. Norms from f32 accs (shfl_xor over q). V epilogues
// deferred until WT dead (Cs aliases WT). Cross-wave reduce in LDS, then
// 1152 atomics/block (half of R12's total).
__global__ __launch_bounds__(256) void qkv_gemm(
    const bhalf* __restrict__ xb, const bhalf* __restrict__ wt,
    const bhalf* __restrict__ ma, bhalf* __restrict__ Vb,
    bhalf* __restrict__ VG, float* __restrict__ S)
{
  __shared__ __align__(16) char smem[27648];   // WT 192x72 f16
  bhalf* WT = (bhalf*)smem;
  float* Cs = (float*)smem;                    // [64][68] f32 (17408B), post-mfma
  float* Sred = (float*)smem;                  // [4][1024] f32 (16384B), post-Cs
  float* qred = (float*)(smem + 16384);        // [4][64]
  float* kred = (float*)(smem + 17408);        // [4][64] (ends 18432 < 27648)
  int t = threadIdx.x;
  {
    const uint4* ws = (const uint4*)wt;
    uint4* wd = (uint4*)WT;
    #pragma unroll
    for (int i = 0; i < 6; ++i) {
      int idx4 = i * 256 + t;               // 1536 uint4
      int n = idx4 >> 3, q4 = idx4 & 7;
      wd[n * 9 + q4] = ws[idx4];
    }
  }
  __syncthreads();

  int wv_ = t >> 6, lane = t & 63;
  int lm = lane & 15, q = lane >> 4;
  int rr = t >> 2, c0 = (t & 3) << 4;

  f32x4 accS[4];
  f32x4 accV[2][4];
  float qss[4] = {0.f, 0.f, 0.f, 0.f};
  float kss[4] = {0.f, 0.f, 0.f, 0.f};
  #pragma unroll
  for (int h = 0; h < 4; ++h) accS[h] = (f32x4){0.f, 0.f, 0.f, 0.f};

  #pragma unroll
  for (int grp = 0; grp < 2; ++grp) {
    size_t row0 = ((size_t)blockIdx.x << 7) + (grp << 6) + (wv_ << 4);
    const bhalf* arow = xb + ((row0 + lm) << 6) + (q << 3);
    f16x8 a0 = *(const f16x8*)(arow);
    f16x8 a1 = *(const f16x8*)(arow + 32);
    f32x4 accQ[4], accK[4];
    #pragma unroll
    for (int nt = 0; nt < 4; ++nt) {
      const bhalf* bp_ = &WT[(nt * 16 + lm) * 72 + (q << 3)];
      f32x4 c = {0.f, 0.f, 0.f, 0.f};
      c = __builtin_amdgcn_mfma_f32_16x16x32_f16(a0, *(const f16x8*)(bp_), c, 0, 0, 0);
      c = __builtin_amdgcn_mfma_f32_16x16x32_f16(a1, *(const f16x8*)(bp_ + 32), c, 0, 0, 0);
      accQ[nt] = c;
    }
    #pragma unroll
    for (int nt = 0; nt < 4; ++nt) {
      const bhalf* bp_ = &WT[((64 + nt * 16) + lm) * 72 + (q << 3)];
      f32x4 c = {0.f, 0.f, 0.f, 0.f};
      c = __builtin_amdgcn_mfma_f32_16x16x32_f16(a0, *(const f16x8*)(bp_), c, 0, 0, 0);
      c = __builtin_amdgcn_mfma_f32_16x16x32_f16(a1, *(const f16x8*)(bp_ + 32), c, 0, 0, 0);
      accK[nt] = c;
    }
    #pragma unroll
    for (int nt = 0; nt < 4; ++nt) {
      const bhalf* bp_ = &WT[((128 + nt * 16) + lm) * 72 + (q << 3)];
      f32x4 c = {0.f, 0.f, 0.f, 0.f};
      c = __builtin_amdgcn_mfma_f32_16x16x32_f16(a0, *(const f16x8*)(bp_), c, 0, 0, 0);
      c = __builtin_amdgcn_mfma_f32_16x16x32_f16(a1, *(const f16x8*)(bp_ + 32), c, 0, 0, 0);
      accV[grp][nt] = c;
    }
    // S16[h] += K^T Q over this group's rows (in-register MFMA, k=16 rows)
    #pragma unroll
    for (int h = 0; h < 4; ++h) {
      f16x4 kf = cvt4h(accK[h]);
      f16x4 qf = cvt4h(accQ[h]);
      accS[h] = __builtin_amdgcn_mfma_f32_16x16x16f16(kf, qf, accS[h], 0, 0, 0);
      #pragma unroll
      for (int r = 0; r < 4; ++r) {
        qss[h] += accQ[h][r] * accQ[h][r];
        kss[h] += accK[h][r] * accK[h][r];
      }
    }
  }

  // ---- V epilogues (WT dead; Cs aliases it) ----
  #pragma unroll
  for (int grp = 0; grp < 2; ++grp) {
    __syncthreads();
    #pragma unroll
    for (int nt = 0; nt < 4; ++nt)
      #pragma unroll
      for (int r = 0; r < 4; ++r)
        Cs[((wv_ << 4) + (q << 2) + r) * 68 + (nt << 4) + lm] = accV[grp][nt][r];
    __syncthreads();
    float v[16];
    #pragma unroll
    for (int j = 0; j < 4; ++j) {
      float4 u = *(const float4*)&Cs[rr * 68 + c0 + 4 * j];
      v[4*j] = u.x; v[4*j+1] = u.y; v[4*j+2] = u.z; v[4*j+3] = u.w;
    }
    size_t grow = ((size_t)blockIdx.x << 7) + (grp << 6) + rr;
    bhalf* ob = Vb + (grow << 6) + c0;
    ((uint4*)ob)[0] = pack16(v);
    ((uint4*)ob)[1] = pack16(v + 8);
    const bhalf* mr = ma + (grow << 6) + c0;
    uint4 m0 = ((const uint4*)mr)[0], m1q = ((const uint4*)mr)[1];
    float mf[16];
    unpack8h(m0, mf); unpack8h(m1q, mf + 8);
    float gv[16];
    #pragma unroll
    for (int j = 0; j < 16; ++j) gv[j] = v[j] * mf[j];
    bhalf* gb = VG + (grow << 6) + c0;
    ((uint4*)gb)[0] = pack16(gv);
    ((uint4*)gb)[1] = pack16(gv + 8);
  }
  __syncthreads();   // last Cs reads done; Sred/qred/kred may write

  // ---- cross-wave reduce + atomics ----
  // accS[h] lane (lm,q) reg r = S[h][d = q*4+r][e = lm]
  #pragma unroll
  for (int h = 0; h < 4; ++h)
    #pragma unroll
    for (int r = 0; r < 4; ++r)
      Sred[(wv_ << 10) + (h << 8) + ((q << 2) + r) * 16 + lm] = accS[h][r];
  #pragma unroll
  for (int nt = 0; nt < 4; ++nt) {
    qss[nt] += __shfl_xor(qss[nt], 16); qss[nt] += __shfl_xor(qss[nt], 32);
    kss[nt] += __shfl_xor(kss[nt], 16); kss[nt] += __shfl_xor(kss[nt], 32);
  }
  if (q == 0) {
    #pragma unroll
    for (int nt = 0; nt < 4; ++nt) {
      qred[(wv_ << 6) + (nt << 4) + lm] = qss[nt];
      kred[(wv_ << 6) + (nt << 4) + lm] = kss[nt];
    }
  }
  __syncthreads();

  int b = (int)(blockIdx.x >> 9);
  float* Sc = S + (size_t)(blockIdx.x & (NSPLIT - 1)) * SCOPY;
  {
    int ci = t << 2;
    float4 s = {0.f, 0.f, 0.f, 0.f};
    #pragma unroll
    for (int wv2 = 0; wv2 < 4; ++wv2) {
      float4 u = *(const float4*)&Sred[(wv2 << 10) + ci];
      s.x += u.x; s.y += u.y; s.z += u.z; s.w += u.w;
    }
    float* sp = Sc + b * 1024 + ci;
    atomicAdd(sp + 0, s.x); atomicAdd(sp + 1, s.y);
    atomicAdd(sp + 2, s.z); atomicAdd(sp + 3, s.w);
  }
  if (t < 64) {
    float qs = qred[t] + qred[64 + t] + qred[128 + t] + qred[192 + t];
    float ks = kred[t] + kred[64 + t] + kred[128 + t] + kred[192 + t];
    atomicAdd(Sc + 2048 + b * 64 + t, qs);
    atomicAdd(Sc + 2176 + b * 64 + t, ks);
  }
}

// ---------------- FFN gemm1 + fused LayerNorm: ln(X) @ [64x256], GELU ----------------
__global__ __launch_bounds__(256) void ffn_gemm1_ln(
    const float* __restrict__ X, const bhalf* __restrict__ wt,
    const float* __restrict__ g, const float* __restrict__ bb,
    bhalf* __restrict__ out_)
{
  __shared__ __align__(16) char smem[256 * 72 * 2];  // WT 36.9KB; Cs aliased
  bhalf* WT = (bhalf*)smem;
  float* Cs = (float*)smem;
  __shared__ float gs[64], bs[64];
  int t = threadIdx.x;
  {
    const uint4* ws = (const uint4*)wt;
    uint4* wd = (uint4*)WT;
    #pragma unroll
    for (int i = 0; i < 8; ++i) {
      int idx4 = i * 256 + t;               // 2048 uint4
      int n = idx4 >> 3, q4 = idx4 & 7;
      wd[n * 9 + q4] = ws[idx4];
    }
    if (t < 64) { gs[t] = g[t]; bs[t] = bb[t]; }
  }
  __syncthreads();

  int wv_ = t >> 6, lane = t & 63;
  int lm = lane & 15, q = lane >> 4;
  size_t row0 = ((size_t)blockIdx.x << 6) + (wv_ << 4);
  // A-fragment rows from fp32 X, with in-register LayerNorm.
  const float* xr = X + ((row0 + lm) << 6);
  int k0 = q << 3;
  float xa[8], xb2[8];
  {
    float4 u0 = *(const float4*)(xr + k0);
    float4 u1 = *(const float4*)(xr + k0 + 4);
    float4 u2 = *(const float4*)(xr + 32 + k0);
    float4 u3 = *(const float4*)(xr + 32 + k0 + 4);
    xa[0]=u0.x; xa[1]=u0.y; xa[2]=u0.z; xa[3]=u0.w;
    xa[4]=u1.x; xa[5]=u1.y; xa[6]=u1.z; xa[7]=u1.w;
    xb2[0]=u2.x; xb2[1]=u2.y; xb2[2]=u2.z; xb2[3]=u2.w;
    xb2[4]=u3.x; xb2[5]=u3.y; xb2[6]=u3.z; xb2[7]=u3.w;
  }
  float s1 = 0.f, s2 = 0.f;
  #pragma unroll
  for (int j = 0; j < 8; ++j) {
    s1 += xa[j] + xb2[j];
    s2 += xa[j] * xa[j] + xb2[j] * xb2[j];
  }
  s1 += __shfl_xor(s1, 16); s1 += __shfl_xor(s1, 32);
  s2 += __shfl_xor(s2, 16); s2 += __shfl_xor(s2, 32);
  float mu = s1 * 0.015625f;
  float var = s2 * 0.015625f - mu * mu;
  float rstd = rsqrtf(var + 1e-5f);
  f16x8 a0, a1;
  #pragma unroll
  for (int j = 0; j < 8; ++j) {
    a0[j] = (_Float16)((xa[j]  - mu) * rstd * gs[k0 + j]      + bs[k0 + j]);
    a1[j] = (_Float16)((xb2[j] - mu) * rstd * gs[32 + k0 + j] + bs[32 + k0 + j]);
  }

  f32x4 acc[16];
  #pragma unroll
  for (int nt = 0; nt < 16; ++nt) {
    const bhalf* bp_ = &WT[(nt * 16 + lm) * 72 + (q << 3)];
    f16x8 b0 = *(const f16x8*)(bp_);
    f16x8 b1 = *(const f16x8*)(bp_ + 32);
    f32x4 c = {0.f, 0.f, 0.f, 0.f};
    c = __builtin_amdgcn_mfma_f32_16x16x32_f16(a0, b0, c, 0, 0, 0);
    c = __builtin_amdgcn_mfma_f32_16x16x32_f16(a1, b1, c, 0, 0, 0);
    acc[nt] = c;
  }

  int rr = t >> 2, c0 = (t & 3) << 4;
  size_t grow = ((size_t)blockIdx.x << 6) + rr;
  #pragma unroll
  for (int gi = 0; gi < 4; ++gi) {
    __syncthreads();
    #pragma unroll
    for (int nt = 0; nt < 4; ++nt)
      #pragma unroll
      for (int r = 0; r < 4; ++r)
        Cs[((wv_ << 4) + (q << 2) + r) * 68 + (nt << 4) + lm] = acc[gi * 4 + nt][r];
    __syncthreads();
    float v[16];
    #pragma unroll
    for (int j = 0; j < 4; ++j) {
      float4 u = *(const float4*)&Cs[rr * 68 + c0 + 4 * j];
      v[4*j]   = gelu_f(u.x); v[4*j+1] = gelu_f(u.y);
      v[4*j+2] = gelu_f(u.z); v[4*j+3] = gelu_f(u.w);
    }
    bhalf* ob = out_ + (grow << 8) + (gi << 6) + c0;
    ((uint4*)ob)[0] = pack16(v);
    ((uint4*)ob)[1] = pack16(v + 8);
  }
}

// ---------------- FFN gemm2: [131072x256] @ [256x64], X += ; writes Xb ----------------
__global__ __launch_bounds__(256) void ffn_gemm2(
    const bhalf* __restrict__ in_, const bhalf* __restrict__ wt,
    float* __restrict__ X, bhalf* __restrict__ Xb)
{
  __shared__ __align__(16) char smem[64 * 264 * 2];  // WT 33.8KB; Cs aliased
  bhalf* WT = (bhalf*)smem;
  float* Cs = (float*)smem;
  int t = threadIdx.x;
  {
    const uint4* ws = (const uint4*)wt;
    uint4* wd = (uint4*)WT;
    #pragma unroll
    for (int i = 0; i < 8; ++i) {
      int idx4 = i * 256 + t;               // 2048 uint4; row = 32 uint4
      int n = idx4 >> 5, q4 = idx4 & 31;
      wd[n * 33 + q4] = ws[idx4];           // LDS row stride 264 f16 = 33 uint4
    }
  }
  __syncthreads();

  int wv_ = t >> 6, lane = t & 63;
  int lm = lane & 15, q = lane >> 4;
  size_t row0 = ((size_t)blockIdx.x << 6) + (wv_ << 4);
  const bhalf* arow = in_ + ((row0 + lm) << 8) + (q << 3);
  f16x8 a[8];
  #pragma unroll
  for (int ch = 0; ch < 8; ++ch) a[ch] = *(const f16x8*)(arow + 32 * ch);

  f32x4 acc[4];
  #pragma unroll
  for (int nt = 0; nt < 4; ++nt) {
    const bhalf* bp_ = &WT[(nt * 16 + lm) * 264 + (q << 3)];
    f32x4 c = {0.f, 0.f, 0.f, 0.f};
    #pragma unroll
    for (int ch = 0; ch < 8; ++ch) {
      f16x8 b = *(const f16x8*)(bp_ + 32 * ch);
      c = __builtin_amdgcn_mfma_f32_16x16x32_f16(a[ch], b, c, 0, 0, 0);
    }
    acc[nt] = c;
  }
  __syncthreads();
  #pragma unroll
  for (int nt = 0; nt < 4; ++nt)
    #pragma unroll
    for (int r = 0; r < 4; ++r)
      Cs[((wv_ << 4) + (q << 2) + r) * 68 + (nt << 4) + lm] = acc[nt][r];
  __syncthreads();

  int rr = t >> 2, c0 = (t & 3) << 4;
  size_t grow = ((size_t)blockIdx.x << 6) + rr;
  float v[16];
  #pragma unroll
  for (int j = 0; j < 4; ++j) {
    float4 u = *(const float4*)&Cs[rr * 68 + c0 + 4 * j];
    v[4*j] = u.x; v[4*j+1] = u.y; v[4*j+2] = u.z; v[4*j+3] = u.w;
  }
  float* xr = X + (grow << 6) + c0;
  #pragma unroll
  for (int j = 0; j < 4; ++j) {
    float4* x4 = (float4*)(xr + 4 * j);
    float4 u = *x4;
    u.x += v[4*j]; u.y += v[4*j+1]; u.z += v[4*j+2]; u.w += v[4*j+3];
    *x4 = u;
    v[4*j] = u.x; v[4*j+1] = u.y; v[4*j+2] = u.z; v[4*j+3] = u.w;
  }
  bhalf* xb = Xb + (grow << 6) + c0;
  ((uint4*)xb)[0] = pack16(v);
  ((uint4*)xb)[1] = pack16(v + 8);
}

// ---------------- depthwise conv KxK SAME, NHWC — 4 x-pixels per thread ----------------
template<int KS, int EPI, int CH>
__global__ __launch_bounds__(256) void dwconv4(
    const bhalf* __restrict__ in, const float* __restrict__ wt,
    const float* __restrict__ db, const bhalf* __restrict__ m1,
    bhalf* __restrict__ out, int wstride)
{
  const int CB = (CH == 64) ? 6 : 8;    // log2(CH)
  const int G  = CH >> 3;               // channel groups per pixel (8 or 32)
  const int GB = (CH == 64) ? 3 : 5;    // log2(G)
  const int R  = KS >> 1;
  const int NCOL = KS + 3;              // window columns for 4 outputs
  __shared__ u32 Wsu[KS * KS * G * 5];  // packed half2 weights, padded stride 5
  __shared__ float db_s[64];
  int t = threadIdx.x;
  for (int idx = t; idx < KS * KS * (CH >> 1); idx += 256) {
    int tap = idx >> (CB - 1), cp = idx & ((CH >> 1) - 1);
    int cg = cp >> 2, j = cp & 3;
    h2 p;
    p[0] = (_Float16)wt[tap * wstride + 2 * cp];
    p[1] = (_Float16)wt[tap * wstride + 2 * cp + 1];
    union { h2 h; u32 u; } cv; cv.h = p;
    Wsu[tap * (G * 5) + cg * 5 + j] = cv.u;
  }
  if (EPI == 2 && t < 64) db_s[t] = db[t];
  __syncthreads();

  size_t gid = (size_t)blockIdx.x * 256 + t;
  int cg = (int)gid & (G - 1);
  int c0 = cg << 3;
  size_t p4 = gid >> GB;                // 4-pixel unit index
  int x0 = ((int)(p4 & 63)) << 2;
  int hy = (int)((p4 >> 6) & 255);
  size_t bb = p4 >> 14;

  h2 zero = {(_Float16)0.0f, (_Float16)0.0f};
  h2 acc[4][4];
  #pragma unroll
  for (int o = 0; o < 4; ++o)
    #pragma unroll
    for (int j = 0; j < 4; ++j) acc[o][j] = zero;

  #pragma unroll
  for (int kh = 0; kh < KS; ++kh) {
    int y = hy + kh - R;
    if ((unsigned)y >= 256u) continue;
    h2 wr[KS][4];
    #pragma unroll
    for (int kw = 0; kw < KS; ++kw) {
      const u32* wp = &Wsu[(kh * KS + kw) * (G * 5) + cg * 5];
      #pragma unroll
      for (int j = 0; j < 4; ++j) {
        union { u32 u; h2 h; } cv; cv.u = wp[j]; wr[kw][j] = cv.h;
      }
    }
    const bhalf* rowp = in + (((((size_t)bb << 8) + (size_t)y) << 8) << CB) + c0;
    #pragma unroll
    for (int cc = 0; cc < NCOL; ++cc) {
      int xw = x0 + cc - R;
      // only edge columns can be OOB: interior columns fold the test away
      if (cc < R || cc >= NCOL - R) {
        if ((unsigned)xw >= 256u) continue;
      }
      union { uint4 u; h2 h[4]; } dv;
      dv.u = *(const uint4*)(rowp + ((size_t)xw << CB));
      #pragma unroll
      for (int kw = 0; kw < KS; ++kw) {
        int o = cc - kw;
        if (o >= 0 && o < 4) {
          #pragma unroll
          for (int j = 0; j < 4; ++j)
            acc[o][j] += dv.h[j] * wr[kw][j];   // v_pk_fma_f16
        }
      }
    }
  }

  size_t p0 = ((((size_t)bb << 8) + (size_t)hy) << 8) + (size_t)x0;
  #pragma unroll
  for (int o = 0; o < 4; ++o) {
    bhalf* op = out + ((p0 + o) << CB) + c0;
    if (EPI == 0) {
      union { h2 h[4]; uint4 u; } sv;
      #pragma unroll
      for (int j = 0; j < 4; ++j) sv.h[j] = acc[o][j];
      *(uint4*)op = sv.u;
    } else if (EPI == 1) {
      float r[8];
      #pragma unroll
      for (int j = 0; j < 4; ++j) {
        r[2*j]   = gelu_f((float)acc[o][j][0]);
        r[2*j+1] = gelu_f((float)acc[o][j][1]);
      }
      *(uint4*)op = pack16(r);
    } else {
      uint4 mu = *(const uint4*)(m1 + ((p0 + o) << CB) + c0);
      float mf[8];
      unpack8h(mu, mf);
      float r[8];
      #pragma unroll
      for (int j = 0; j < 8; ++j) {
        float av = (float)acc[o][j >> 1][j & 1];
        float am = 1.0f / (1.0f + expf(-(av + db_s[c0 + j])));
        r[j] = mf[j] * (am + 1.0f);
      }
      *(uint4*)op = pack16(r);
    }
  }
}

// ---------------- attn softmax + fold into Wp (merged) ----------------
__global__ __launch_bounds__(256) void attn_fold(
    const float* __restrict__ S, const float* __restrict__ resc,
    const bhalf* __restrict__ wpT, bhalf* __restrict__ weffT)
{
  __shared__ float As[1024];     // [h][e][d]
  __shared__ float nqs_s[64];    // [h][d]
  int b = blockIdx.x;            // 2 blocks (batch)
  int t = threadIdx.x;
  if (t < 64) {
    int h = t >> 4, d = t & 15;
    float nqsum = 0.f;
    for (int c = 0; c < NSPLIT; ++c)
      nqsum += S[c * SCOPY + 2048 + b * 64 + h * 16 + d];
    nqs_s[t] = fmaxf(sqrtf(nqsum), 1e-6f);
  }
  __syncthreads();
  if (t < 64) {
    int h = t >> 4, d = t & 15;
    float nksum = 0.f;
    for (int c = 0; c < NSPLIT; ++c)
      nksum += S[c * SCOPY + 2176 + b * 64 + h * 16 + d];
    float nkd = fmaxf(sqrtf(nksum), 1e-6f);
    float r = resc[h];
    float4 s4[4] = {{0,0,0,0},{0,0,0,0},{0,0,0,0},{0,0,0,0}};
    for (int c = 0; c < NSPLIT; ++c) {
      const float4* sp = (const float4*)&S[c * SCOPY + (((b * 4 + h) * 16 + d) << 4)];
      #pragma unroll
      for (int j = 0; j < 4; ++j) {
        float4 u = sp[j];
        s4[j].x += u.x; s4[j].y += u.y; s4[j].z += u.z; s4[j].w += u.w;
      }
    }
    float a[16];
    #pragma unroll
    for (int j = 0; j < 4; ++j) {
      a[4*j]   = s4[j].x * r / (nkd * nqs_s[h * 16 + 4*j]);
      a[4*j+1] = s4[j].y * r / (nkd * nqs_s[h * 16 + 4*j + 1]);
      a[4*j+2] = s4[j].z * r / (nkd * nqs_s[h * 16 + 4*j + 2]);
      a[4*j+3] = s4[j].w * r / (nkd * nqs_s[h * 16 + 4*j + 3]);
    }
    float m = -1e30f;
    #pragma unroll
    for (int e = 0; e < 16; ++e) m = fmaxf(m, a[e]);
    float sum = 0.f;
    #pragma unroll
    for (int e = 0; e < 16; ++e) { a[e] = expf(a[e] - m); sum += a[e]; }
    float inv = 1.0f / sum;
    #pragma unroll
    for (int e = 0; e < 16; ++e)
      As[((h * 16 + e) << 4) + d] = a[e] * inv;
  }
  __syncthreads();
  int m = t & 63, h = t >> 6;    // each thread: one (m, h) pair -> 16 outputs
  const bhalf* wp = wpT + m * 64 + h * 16;
  float wv_[16];
  uint4 w0 = ((const uint4*)wp)[0], w1 = ((const uint4*)wp)[1];
  unpack8h(w0, wv_); unpack8h(w1, wv_ + 8);
  float r2[16];
  #pragma unroll
  for (int e = 0; e < 16; ++e) {
    const float* ar = &As[(h * 16 + e) << 4];
    float s = 0.f;
    #pragma unroll
    for (int d = 0; d < 16; ++d) s += ar[d] * wv_[d];
    r2[e] = s;
  }
  bhalf* dst = weffT + b * 4096 + m * 64 + h * 16;
  ((uint4*)dst)[0] = pack16(r2);
  ((uint4*)dst)[1] = pack16(r2 + 8);
}

// ---------------- host orchestration ----------------
extern "C" void kernel_launch(void* const* d_in, const int* in_sizes, int n_in,
                              void* d_out, int out_size, void* d_ws, size_t ws_size,
                              hipStream_t stream)
{
  (void)in_sizes; (void)n_in; (void)out_size; (void)ws_size;
  const float* x_in    = (const float*)d_in[0];
  const float* mask_in = (const float*)d_in[1];
  const float* Wq    = (const float*)d_in[2];
  const float* Wk    = (const float*)d_in[3];
  const float* Wv    = (const float*)d_in[4];
  const float* resc  = (const float*)d_in[5];
  const float* Wp    = (const float*)d_in[6];
  const float* bp    = (const float*)d_in[7];
  const float* pe1   = (const float*)d_in[8];
  const float* pe2   = (const float*)d_in[9];
  const float* mm_w1 = (const float*)d_in[10];
  const float* mm_b1 = (const float*)d_in[11];
  const float* mm_w2 = (const float*)d_in[12];
  const float* mm_b2 = (const float*)d_in[13];
  const float* mm_dw = (const float*)d_in[14];
  const float* mm_db = (const float*)d_in[15];
  const float* ln_g  = (const float*)d_in[16];
  const float* ln_b  = (const float*)d_in[17];
  const float* ff_w1 = (const float*)d_in[18];
  const float* ff_dw = (const float*)d_in[19];
  const float* ff_w2 = (const float*)d_in[20];

  const size_t NC = 8388608;  // B*N*C
  char* w = (char*)d_ws;
  float* X  = (float*)w; w += NC * 4;   // residual stream, fp32
  bhalf* Xb = (bhalf*)w; w += NC * 2;   // f16 mirror of X
  bhalf* M  = (bhalf*)w; w += NC * 2;   // mask NHWC
  bhalf* Qb = (bhalf*)w; w += NC * 2;   // (dead; spanned by F1)
  bhalf* Kb = (bhalf*)w; w += NC * 2;   // (dead; spanned by F1)
  bhalf* Vb = (bhalf*)w; w += NC * 2;
  bhalf* VG = (bhalf*)w; w += NC * 2;
  bhalf* T1 = (bhalf*)w; w += NC * 2;
  bhalf* T2 = (bhalf*)w; w += NC * 2;
  bhalf* T3 = (bhalf*)w; w += NC * 2;
  bhalf* Pb = (bhalf*)w; w += NC * 2;
  float* Sb    = (float*)w; w += (size_t)NSPLIT * SCOPY * 4;  // split accumulators
  bhalf* WeffT = (bhalf*)w; w += 8192 * 2;                    // per-batch A_bd@Wp
  bhalf* WTg   = (bhalf*)w; w += (size_t)3 * WBLK * 2;        // pre-transposed weights
  (void)Qb; (void)Kb;
  // FFN 256-ch temps alias dead 64-ch buffers.
  bhalf* F1 = Qb;   // [131072 x 256] ffn hidden (spans Qb,Kb,Vb,VG)
  bhalf* F2 = T1;   // [131072 x 256] post-dwconv (spans T1,T2,T3,Pb)

  prep_weights<<<24, 256, 0, stream>>>(mm_w1, mm_w2, Wq, Wk, Wv, Wp, ff_w1, ff_w2, WTg);
  nchw2nhwc<0><<<2048, 256, 0, stream>>>(x_in, X, Xb);
  nchw2nhwc<1><<<2048, 256, 0, stream>>>(mask_in, M, nullptr);

  for (int i = 0; i < 3; ++i) {
    const bhalf* wb = WTg + (size_t)i * WBLK;
    // mask branch: m1 (T1) + m2 (T2) fused; then MA (T3)
    gemm_mask2<<<GEMM_GRID, 256, 0, stream>>>(M, wb + 0, mm_b1 + i*64, mm_b2 + i*64, T1, T2);
    dwconv4<5, 2, 64><<<1024, 256, 0, stream>>>(T2, mm_dw + i*1600, mm_db + i*64, T1, T3, 64);
    // fused QKV + gate + in-register attention partials (128 rows/block)
    hipMemsetAsync(Sb, 0, NSPLIT * SCOPY * 4, stream);
    qkv_gemm<<<1024, 256, 0, stream>>>(Xb, wb + 8192, T3, Vb, VG, Sb);
    attn_fold<<<2, 256, 0, stream>>>(Sb, resc + i*4, wb + 20480, WeffT);
    // positional branch on ungated V
    dwconv4<3, 1, 64><<<1024, 256, 0, stream>>>(Vb, pe1 + i*576, nullptr, nullptr, T1, 64);
    dwconv4<3, 0, 64><<<1024, 256, 0, stream>>>(T1, pe2 + i*576, nullptr, nullptr, Pb, 64);
    // X += VG@Weff + bp + P; refresh Xb  (attn folded into weights)
    gemm64m<EP_RESID, 1><<<GEMM_GRID, 256, 0, stream>>>(VG, WeffT, bp + i*64, X, Pb, Xb);
    // FFN (full 256 hidden): fused ln+gemm1(gelu) -> dw3(gelu) -> gemm2(acc)
    ffn_gemm1_ln<<<GEMM_GRID, 256, 0, stream>>>(X, wb + 24576, ln_g + i*64, ln_b + i*64, F1);
    dwconv4<3, 1, 256><<<4096, 256, 0, stream>>>(F1, ff_dw + i*2304, nullptr, nullptr, F2, 256);
    ffn_gemm2<<<GEMM_GRID, 256, 0, stream>>>(F2, wb + 40960, X, Xb);
  }
  nhwc2nchw<<<2048, 256, 0, stream>>>(X, (float*)d_out);
}

// Round 8
// 799.646 us; speedup vs baseline: 1.2792x; 1.0502x over previous
//
#include <hip/hip_runtime.h>
#include <math.h>

// HGSA: 3x (mask-guided channel-attention MSA + LN + convFFN) on [2,64,256,256].
// External I/O fp32. Internal activations FP16, residual stream X fp32 (+f16
// mirror Xb), weights f16 in LDS.
// R5: MFMA gemms. R6: staged attn, un-chunked FFN, fused QKV. R7: attn atomic
// 32-way split. R8: weights pre-transposed W^T. R9: dwconv4 (4 px/thread +
// conflict-free weight LDS). R10: bf16 -> fp16 (HW pack/pk_fma).
// R11: attn folded into Wp; mask m1+m2 fused; LN fused into ffn_gemm1.
// R12: attention partials fused INTO qkv_gemm; attn_softmax+fold merged.
// R14: S via in-register MFMA (Q/K never touch LDS/HBM); 128 rows/block.
// R16: (a) exact erff-GELU -> tanh-form GELU with native v_exp/v_rcp
// (NaN-safe th = 1-2/(e^{2u}+1); max dev 4e-4 << 0.0156 f16 absmax) — erff
// was ~60% of dwconv256/ffn_gemm1 VALU; (b) EPI=2 sigmoid on native exp/rcp;
// (c) iteration-3 ffn_gemm2<FINAL=1> writes d_out NCHW directly via Cs LDS
// re-transpose — removes nhwc2nchw kernel and the dead X/Xb final writes
// (-118 MB, -1 launch).

typedef unsigned short bhalf;            // fp16 bits
typedef unsigned int u32;
typedef _Float16 h2 __attribute__((ext_vector_type(2)));
typedef _Float16 f16x4 __attribute__((ext_vector_type(4)));
typedef _Float16 f16x8 __attribute__((ext_vector_type(8)));
typedef __attribute__((ext_vector_type(4))) float f32x4;

#define GEMM_GRID 2048      // 131072 rows / 64 rows per block
#define NSPLIT 32           // attn accumulator copies
#define SCOPY 2304          // floats per copy: 2048 S + 128 nq + 128 nk
#define WBLK 57344          // f16 per transformer-block weight blob

__device__ __forceinline__ float h2f(bhalf b) {
  union { bhalf u; _Float16 h; } c; c.u = b; return (float)c.h;
}
__device__ __forceinline__ bhalf f2h(float f) {
  union { _Float16 h; bhalf u; } c; c.h = (_Float16)f; return c.u;
}
__device__ __forceinline__ u32 pack2h(float a, float b) {
  auto r = __builtin_amdgcn_cvt_pkrtz(a, b);     // v_cvt_pkrtz_f16_f32, 1 op
  union { decltype(r) h; u32 u; } c; c.h = r; return c.u;
}
__device__ __forceinline__ void unpack2h(u32 p, float& a, float& b) {
  union { u32 u; h2 h; } c; c.u = p;
  a = (float)c.h[0]; b = (float)c.h[1];
}
__device__ __forceinline__ void unpack8h(uint4 u, float* f) {
  unpack2h(u.x, f[0], f[1]); unpack2h(u.y, f[2], f[3]);
  unpack2h(u.z, f[4], f[5]); unpack2h(u.w, f[6], f[7]);
}
// tanh-form GELU, branch-free, native exp/rcp. th = 1 - 2/(exp(2u)+1) is
// NaN-safe at both infinities (e=inf -> th=1; e=0 -> th=-1).
__device__ __forceinline__ float gelu_f(float v) {
  float u = v * (0.7978845608f + 0.03567740814f * v * v);
  float e = __expf(2.0f * u);
  float th = 1.0f - 2.0f * __builtin_amdgcn_rcpf(e + 1.0f);
  return 0.5f * v * (1.0f + th);
}
__device__ __forceinline__ uint4 pack16(const float* v) {  // 8 floats -> 8 f16
  uint4 s;
  s.x = pack2h(v[0], v[1]); s.y = pack2h(v[2], v[3]);
  s.z = pack2h(v[4], v[5]); s.w = pack2h(v[6], v[7]);
  return s;
}
__device__ __forceinline__ f16x4 cvt4h(f32x4 v) {    // 4 f32 -> f16x4 frag
  union { u32 u[2]; f16x4 h; } c;
  c.u[0] = pack2h(v[0], v[1]); c.u[1] = pack2h(v[2], v[3]);
  return c.h;
}

// ---------------- weight pre-transpose (once per launch, ~2us) ----------------
// For each GEMM weight W[K][N]: WTg[n*K + k] = f16(W[k][n]).
// Per block i: mm1@0, mm2@4096, Q@8192, K@12288, V@16384, P@20480,
//              ff1@24576 ([256][64]), ff2@40960 ([64][256]).
__global__ __launch_bounds__(256) void prep_weights(
    const float* __restrict__ mm_w1, const float* __restrict__ mm_w2,
    const float* __restrict__ Wq, const float* __restrict__ Wk,
    const float* __restrict__ Wv, const float* __restrict__ Wp,
    const float* __restrict__ ff_w1, const float* __restrict__ ff_w2,
    bhalf* __restrict__ out)
{
  int i = blockIdx.x >> 3, slot = blockIdx.x & 7;
  int t = threadIdx.x;
  const float* src; int ksh, N; size_t off;
  switch (slot) {
    case 0:  src = mm_w1 + i*4096;  ksh=6; N=64;  off = 0;     break;
    case 1:  src = mm_w2 + i*4096;  ksh=6; N=64;  off = 4096;  break;
    case 2:  src = Wq + i*4096;     ksh=6; N=64;  off = 8192;  break;
    case 3:  src = Wk + i*4096;     ksh=6; N=64;  off = 12288; break;
    case 4:  src = Wv + i*4096;     ksh=6; N=64;  off = 16384; break;
    case 5:  src = Wp + i*4096;     ksh=6; N=64;  off = 20480; break;
    case 6:  src = ff_w1 + i*16384; ksh=6; N=256; off = 24576; break;
    default: src = ff_w2 + i*16384; ksh=8; N=64;  off = 40960; break;
  }
  bhalf* dst = out + (size_t)i * WBLK + off;
  int sz = N << ksh;
  int kmask = (1 << ksh) - 1;
  for (int idx = t; idx < sz; idx += 256) {
    int n = idx >> ksh, k = idx & kmask;
    dst[idx] = f2h(src[k * N + n]);
  }
}

// ---------------- transposes ----------------
template<int MODE>   // 0: x -> fp32 X AND f16 Xb.  1: mask -> f16 only.
__global__ __launch_bounds__(256) void nchw2nhwc(const float* __restrict__ in,
                                                 void* __restrict__ out,
                                                 bhalf* __restrict__ out2) {
  __shared__ float tile[64][65];
  int t = threadIdx.x;
  int b = blockIdx.x >> 10;
  int n0 = (blockIdx.x & 1023) << 6;
  #pragma unroll
  for (int j = 0; j < 16; ++j) {
    int idx = j * 256 + t;
    int c = idx >> 6, nn = idx & 63;
    tile[c][nn] = in[(((size_t)(b * 64 + c)) << 16) + n0 + nn];
  }
  __syncthreads();
  #pragma unroll
  for (int j = 0; j < 16; ++j) {
    int idx = j * 256 + t;
    int nn = idx >> 6, c = idx & 63;
    size_t o = ((((size_t)b << 16) + n0 + nn) << 6) + c;
    float v = tile[c][nn];
    if (MODE == 0) { ((float*)out)[o] = v; out2[o] = f2h(v); }
    else           { ((bhalf*)out)[o] = f2h(v); }
  }
}

// ---------------- fused mask GEMMs: m1 = M@W1+b1 ; m2 = m1@W2+b2 ----------------
__global__ __launch_bounds__(256) void gemm_mask2(
    const bhalf* __restrict__ M, const bhalf* __restrict__ wt,  // W1T@0, W2T@4096
    const float* __restrict__ b1, const float* __restrict__ b2,
    bhalf* __restrict__ T1o, bhalf* __restrict__ T2o)
{
  __shared__ __align__(16) char smem[9216 * 2 + 17408];
  bhalf* WT1 = (bhalf*)smem;               // [64][72]
  bhalf* WT2 = (bhalf*)(smem + 9216);      // [64][72]
  float* Cs  = (float*)(smem + 18432);     // [64][68] transpose buffer
  bhalf* Ab  = (bhalf*)(smem + 18432);     // [64][72] f16 A relayout (aliases Cs)
  __shared__ float b1s[64], b2s[64];
  int t = threadIdx.x;
  {
    const uint4* ws = (const uint4*)wt;    // 1024 uint4: W1 then W2
    #pragma unroll
    for (int i = 0; i < 4; ++i) {
      int idx4 = i * 256 + t;
      int n = (idx4 >> 3) & 63, q4 = idx4 & 7;
      uint4* wd = (idx4 < 512) ? (uint4*)WT1 : (uint4*)WT2;
      wd[n * 9 + q4] = ws[idx4];
    }
    if (t < 64) { b1s[t] = b1[t]; b2s[t] = b2[t]; }
  }
  __syncthreads();

  int wv = t >> 6, lane = t & 63;
  int lm = lane & 15, q = lane >> 4;
  size_t row0 = ((size_t)blockIdx.x << 6) + (wv << 4);
  int rr = t >> 2, c0 = (t & 3) << 4;
  size_t grow = ((size_t)blockIdx.x << 6) + rr;

  // pass 1: m1 = M @ W1
  const bhalf* arow = M + ((row0 + lm) << 6) + (q << 3);
  f16x8 a0 = *(const f16x8*)(arow);
  f16x8 a1 = *(const f16x8*)(arow + 32);
  f32x4 acc[4];
  #pragma unroll
  for (int nt = 0; nt < 4; ++nt) {
    const bhalf* bp_ = &WT1[(nt * 16 + lm) * 72 + (q << 3)];
    f16x8 bv0 = *(const f16x8*)(bp_);
    f16x8 bv1 = *(const f16x8*)(bp_ + 32);
    f32x4 c = {0.f, 0.f, 0.f, 0.f};
    c = __builtin_amdgcn_mfma_f32_16x16x32_f16(a0, bv0, c, 0, 0, 0);
    c = __builtin_amdgcn_mfma_f32_16x16x32_f16(a1, bv1, c, 0, 0, 0);
    acc[nt] = c;
  }
  #pragma unroll
  for (int nt = 0; nt < 4; ++nt)
    #pragma unroll
    for (int r = 0; r < 4; ++r)
      Cs[((wv << 4) + (q << 2) + r) * 68 + (nt << 4) + lm] = acc[nt][r];
  __syncthreads();
  float v[16];
  #pragma unroll
  for (int j = 0; j < 4; ++j) {
    float4 u = *(const float4*)&Cs[rr * 68 + c0 + 4 * j];
    v[4*j] = u.x; v[4*j+1] = u.y; v[4*j+2] = u.z; v[4*j+3] = u.w;
  }
  #pragma unroll
  for (int j = 0; j < 16; ++j) v[j] += b1s[c0 + j];
  uint4 p0 = pack16(v), p1 = pack16(v + 8);
  bhalf* ob1 = T1o + (grow << 6) + c0;
  ((uint4*)ob1)[0] = p0; ((uint4*)ob1)[1] = p1;
  __syncthreads();                       // all Cs reads done before Ab overwrite
  *(uint4*)&Ab[rr * 72 + c0]     = p0;   // 144B row stride: 16B-aligned
  *(uint4*)&Ab[rr * 72 + c0 + 8] = p1;
  __syncthreads();

  // pass 2: m2 = m1(f16) @ W2
  const bhalf* ar2 = &Ab[((wv << 4) + lm) * 72 + (q << 3)];
  f16x8 c0v = *(const f16x8*)(ar2);
  f16x8 c1v = *(const f16x8*)(ar2 + 32);
  #pragma unroll
  for (int nt = 0; nt < 4; ++nt) {
    const bhalf* bp_ = &WT2[(nt * 16 + lm) * 72 + (q << 3)];
    f16x8 bv0 = *(const f16x8*)(bp_);
    f16x8 bv1 = *(const f16x8*)(bp_ + 32);
    f32x4 c = {0.f, 0.f, 0.f, 0.f};
    c = __builtin_amdgcn_mfma_f32_16x16x32_f16(c0v, bv0, c, 0, 0, 0);
    c = __builtin_amdgcn_mfma_f32_16x16x32_f16(c1v, bv1, c, 0, 0, 0);
    acc[nt] = c;
  }
  __syncthreads();                       // Ab reads done before Cs overwrite
  #pragma unroll
  for (int nt = 0; nt < 4; ++nt)
    #pragma unroll
    for (int r = 0; r < 4; ++r)
      Cs[((wv << 4) + (q << 2) + r) * 68 + (nt << 4) + lm] = acc[nt][r];
  __syncthreads();
  #pragma unroll
  for (int j = 0; j < 4; ++j) {
    float4 u = *(const float4*)&Cs[rr * 68 + c0 + 4 * j];
    v[4*j] = u.x; v[4*j+1] = u.y; v[4*j+2] = u.z; v[4*j+3] = u.w;
  }
  #pragma unroll
  for (int j = 0; j < 16; ++j) v[j] += b2s[c0 + j];
  bhalf* ob2 = T2o + (grow << 6) + c0;
  ((uint4*)ob2)[0] = pack16(v);
  ((uint4*)ob2)[1] = pack16(v + 8);
}

// ---------------- MFMA GEMM 64x64, residual epilogue ----------------
// BW=1: weight blob is per-batch (4096 f16 each), selected by blockIdx>>10.
#define EP_BIAS 1
#define EP_RESID 5  // fp32 out_(X) += result + bias + aux(P f16); writes xbout

template<int EP, int BW>
__global__ __launch_bounds__(256) void gemm64m(
    const bhalf* __restrict__ in_, const bhalf* __restrict__ wt,
    const float* __restrict__ bias, void* __restrict__ out_,
    const bhalf* __restrict__ aux, bhalf* __restrict__ xbout)
{
  __shared__ __align__(16) char smem[64 * 68 * 4];  // WT (9.2KB) then Cs (17.4KB)
  bhalf* WT = (bhalf*)smem;         // W^T, [n][k] stride 72
  float* Cs = (float*)smem;         // epilogue transpose buffer, stride 68
  __shared__ float bias_s[64];
  int t = threadIdx.x;
  if (BW) wt += (size_t)(blockIdx.x >> 10) << 12;
  {
    const uint4* ws = (const uint4*)wt;
    uint4* wd = (uint4*)WT;
    #pragma unroll
    for (int i = 0; i < 2; ++i) {
      int idx4 = i * 256 + t;               // 512 uint4 total; row = 8 uint4
      int n = idx4 >> 3, q4 = idx4 & 7;
      wd[n * 9 + q4] = ws[idx4];            // LDS row stride 72 f16 = 9 uint4
    }
    if (t < 64) bias_s[t] = bias[t];
  }
  __syncthreads();

  int wv = t >> 6, lane = t & 63;
  int lm = lane & 15, q = lane >> 4;
  size_t row0 = ((size_t)blockIdx.x << 6) + (wv << 4);

  const bhalf* arow = in_ + ((row0 + lm) << 6) + (q << 3);
  f16x8 a0 = *(const f16x8*)(arow);
  f16x8 a1 = *(const f16x8*)(arow + 32);

  f32x4 acc[4];
  #pragma unroll
  for (int nt = 0; nt < 4; ++nt) {
    const bhalf* bp_ = &WT[(nt * 16 + lm) * 72 + (q << 3)];
    f16x8 b0 = *(const f16x8*)(bp_);
    f16x8 b1 = *(const f16x8*)(bp_ + 32);
    f32x4 c = {0.f, 0.f, 0.f, 0.f};
    c = __builtin_amdgcn_mfma_f32_16x16x32_f16(a0, b0, c, 0, 0, 0);
    c = __builtin_amdgcn_mfma_f32_16x16x32_f16(a1, b1, c, 0, 0, 0);
    acc[nt] = c;
  }
  __syncthreads();   // all waves done with WT before Cs overwrites it
  #pragma unroll
  for (int nt = 0; nt < 4; ++nt)
    #pragma unroll
    for (int r = 0; r < 4; ++r)
      Cs[((wv << 4) + (q << 2) + r) * 68 + (nt << 4) + lm] = acc[nt][r];
  __syncthreads();

  int rr = t >> 2, c0 = (t & 3) << 4;
  size_t grow = ((size_t)blockIdx.x << 6) + rr;
  float v[16];
  #pragma unroll
  for (int j = 0; j < 4; ++j) {
    float4 u = *(const float4*)&Cs[rr * 68 + c0 + 4 * j];
    v[4*j] = u.x; v[4*j+1] = u.y; v[4*j+2] = u.z; v[4*j+3] = u.w;
  }

  if (EP == EP_RESID) {
    float* xr = (float*)out_ + (grow << 6) + c0;
    const bhalf* pr = aux + (grow << 6) + c0;
    uint4 p0 = ((const uint4*)pr)[0], p1 = ((const uint4*)pr)[1];
    float pf[16];
    unpack8h(p0, pf); unpack8h(p1, pf + 8);
    #pragma unroll
    for (int j = 0; j < 4; ++j) {
      float4* x4 = (float4*)(xr + 4 * j);
      float4 u = *x4;
      u.x += v[4*j]   + bias_s[c0 + 4*j]     + pf[4*j];
      u.y += v[4*j+1] + bias_s[c0 + 4*j + 1] + pf[4*j+1];
      u.z += v[4*j+2] + bias_s[c0 + 4*j + 2] + pf[4*j+2];
      u.w += v[4*j+3] + bias_s[c0 + 4*j + 3] + pf[4*j+3];
      *x4 = u;
      v[4*j] = u.x; v[4*j+1] = u.y; v[4*j+2] = u.z; v[4*j+3] = u.w;
    }
    bhalf* xb = xbout + (grow << 6) + c0;
    ((uint4*)xb)[0] = pack16(v);
    ((uint4*)xb)[1] = pack16(v + 8);
  } else {  // EP_BIAS
    #pragma unroll
    for (int j = 0; j < 16; ++j) v[j] += bias_s[c0 + j];
    bhalf* ob = (bhalf*)out_ + (grow << 6) + c0;
    ((uint4*)ob)[0] = pack16(v);
    ((uint4*)ob)[1] = pack16(v + 8);
  }
}

// ---------------- fused QKV + in-register channel-attention partials ----------------
// 1024 blocks x 128 rows (2 groups of 64). wt rows 0-63=Q, 64-127=K, 128-191=V.
// Q/K live only in accumulators: S16[h] += mfma_16x16x16(f16(accK[h]),
// f16(accQ[h])) — the gemm C-layout (lane=col, rows q*4+r) IS the A/B frag
// layout with k=rows. Norms from f32 accs (shfl_xor over q). V epilogues
// deferred until WT dead (Cs aliases WT). Cross-wave reduce in LDS, then
// 1152 atomics/block (half of R12's total).
__global__ __launch_bounds__(256) void qkv_gemm(
    const bhalf* __restrict__ xb, const bhalf* __restrict__ wt,
    const bhalf* __restrict__ ma, bhalf* __restrict__ Vb,
    bhalf* __restrict__ VG, float* __restrict__ S)
{
  __shared__ __align__(16) char smem[27648];   // WT 192x72 f16
  bhalf* WT = (bhalf*)smem;
  float* Cs = (float*)smem;                    // [64][68] f32 (17408B), post-mfma
  float* Sred = (float*)smem;                  // [4][1024] f32 (16384B), post-Cs
  float* qred = (float*)(smem + 16384);        // [4][64]
  float* kred = (float*)(smem + 17408);        // [4][64] (ends 18432 < 27648)
  int t = threadIdx.x;
  {
    const uint4* ws = (const uint4*)wt;
    uint4* wd = (uint4*)WT;
    #pragma unroll
    for (int i = 0; i < 6; ++i) {
      int idx4 = i * 256 + t;               // 1536 uint4
      int n = idx4 >> 3, q4 = idx4 & 7;
      wd[n * 9 + q4] = ws[idx4];
    }
  }
  __syncthreads();

  int wv_ = t >> 6, lane = t & 63;
  int lm = lane & 15, q = lane >> 4;
  int rr = t >> 2, c0 = (t & 3) << 4;

  f32x4 accS[4];
  f32x4 accV[2][4];
  float qss[4] = {0.f, 0.f, 0.f, 0.f};
  float kss[4] = {0.f, 0.f, 0.f, 0.f};
  #pragma unroll
  for (int h = 0; h < 4; ++h) accS[h] = (f32x4){0.f, 0.f, 0.f, 0.f};

  #pragma unroll
  for (int grp = 0; grp < 2; ++grp) {
    size_t row0 = ((size_t)blockIdx.x << 7) + (grp << 6) + (wv_ << 4);
    const bhalf* arow = xb + ((row0 + lm) << 6) + (q << 3);
    f16x8 a0 = *(const f16x8*)(arow);
    f16x8 a1 = *(const f16x8*)(arow + 32);
    f32x4 accQ[4], accK[4];
    #pragma unroll
    for (int nt = 0; nt < 4; ++nt) {
      const bhalf* bp_ = &WT[(nt * 16 + lm) * 72 + (q << 3)];
      f32x4 c = {0.f, 0.f, 0.f, 0.f};
      c = __builtin_amdgcn_mfma_f32_16x16x32_f16(a0, *(const f16x8*)(bp_), c, 0, 0, 0);
      c = __builtin_amdgcn_mfma_f32_16x16x32_f16(a1, *(const f16x8*)(bp_ + 32), c, 0, 0, 0);
      accQ[nt] = c;
    }
    #pragma unroll
    for (int nt = 0; nt < 4; ++nt) {
      const bhalf* bp_ = &WT[((64 + nt * 16) + lm) * 72 + (q << 3)];
      f32x4 c = {0.f, 0.f, 0.f, 0.f};
      c = __builtin_amdgcn_mfma_f32_16x16x32_f16(a0, *(const f16x8*)(bp_), c, 0, 0, 0);
      c = __builtin_amdgcn_mfma_f32_16x16x32_f16(a1, *(const f16x8*)(bp_ + 32), c, 0, 0, 0);
      accK[nt] = c;
    }
    #pragma unroll
    for (int nt = 0; nt < 4; ++nt) {
      const bhalf* bp_ = &WT[((128 + nt * 16) + lm) * 72 + (q << 3)];
      f32x4 c = {0.f, 0.f, 0.f, 0.f};
      c = __builtin_amdgcn_mfma_f32_16x16x32_f16(a0, *(const f16x8*)(bp_), c, 0, 0, 0);
      c = __builtin_amdgcn_mfma_f32_16x16x32_f16(a1, *(const f16x8*)(bp_ + 32), c, 0, 0, 0);
      accV[grp][nt] = c;
    }
    // S16[h] += K^T Q over this group's rows (in-register MFMA, k=16 rows)
    #pragma unroll
    for (int h = 0; h < 4; ++h) {
      f16x4 kf = cvt4h(accK[h]);
      f16x4 qf = cvt4h(accQ[h]);
      accS[h] = __builtin_amdgcn_mfma_f32_16x16x16f16(kf, qf, accS[h], 0, 0, 0);
      #pragma unroll
      for (int r = 0; r < 4; ++r) {
        qss[h] += accQ[h][r] * accQ[h][r];
        kss[h] += accK[h][r] * accK[h][r];
      }
    }
  }

  // ---- V epilogues (WT dead; Cs aliases it) ----
  #pragma unroll
  for (int grp = 0; grp < 2; ++grp) {
    __syncthreads();
    #pragma unroll
    for (int nt = 0; nt < 4; ++nt)
      #pragma unroll
      for (int r = 0; r < 4; ++r)
        Cs[((wv_ << 4) + (q << 2) + r) * 68 + (nt << 4) + lm] = accV[grp][nt][r];
    __syncthreads();
    float v[16];
    #pragma unroll
    for (int j = 0; j < 4; ++j) {
      float4 u = *(const float4*)&Cs[rr * 68 + c0 + 4 * j];
      v[4*j] = u.x; v[4*j+1] = u.y; v[4*j+2] = u.z; v[4*j+3] = u.w;
    }
    size_t grow = ((size_t)blockIdx.x << 7) + (grp << 6) + rr;
    bhalf* ob = Vb + (grow << 6) + c0;
    ((uint4*)ob)[0] = pack16(v);
    ((uint4*)ob)[1] = pack16(v + 8);
    const bhalf* mr = ma + (grow << 6) + c0;
    uint4 m0 = ((const uint4*)mr)[0], m1q = ((const uint4*)mr)[1];
    float mf[16];
    unpack8h(m0, mf); unpack8h(m1q, mf + 8);
    float gv[16];
    #pragma unroll
    for (int j = 0; j < 16; ++j) gv[j] = v[j] * mf[j];
    bhalf* gb = VG + (grow << 6) + c0;
    ((uint4*)gb)[0] = pack16(gv);
    ((uint4*)gb)[1] = pack16(gv + 8);
  }
  __syncthreads();   // last Cs reads done; Sred/qred/kred may write

  // ---- cross-wave reduce + atomics ----
  // accS[h] lane (lm,q) reg r = S[h][d = q*4+r][e = lm]
  #pragma unroll
  for (int h = 0; h < 4; ++h)
    #pragma unroll
    for (int r = 0; r < 4; ++r)
      Sred[(wv_ << 10) + (h << 8) + ((q << 2) + r) * 16 + lm] = accS[h][r];
  #pragma unroll
  for (int nt = 0; nt < 4; ++nt) {
    qss[nt] += __shfl_xor(qss[nt], 16); qss[nt] += __shfl_xor(qss[nt], 32);
    kss[nt] += __shfl_xor(kss[nt], 16); kss[nt] += __shfl_xor(kss[nt], 32);
  }
  if (q == 0) {
    #pragma unroll
    for (int nt = 0; nt < 4; ++nt) {
      qred[(wv_ << 6) + (nt << 4) + lm] = qss[nt];
      kred[(wv_ << 6) + (nt << 4) + lm] = kss[nt];
    }
  }
  __syncthreads();

  int b = (int)(blockIdx.x >> 9);
  float* Sc = S + (size_t)(blockIdx.x & (NSPLIT - 1)) * SCOPY;
  {
    int ci = t << 2;
    float4 s = {0.f, 0.f, 0.f, 0.f};
    #pragma unroll
    for (int wv2 = 0; wv2 < 4; ++wv2) {
      float4 u = *(const float4*)&Sred[(wv2 << 10) + ci];
      s.x += u.x; s.y += u.y; s.z += u.z; s.w += u.w;
    }
    float* sp = Sc + b * 1024 + ci;
    atomicAdd(sp + 0, s.x); atomicAdd(sp + 1, s.y);
    atomicAdd(sp + 2, s.z); atomicAdd(sp + 3, s.w);
  }
  if (t < 64) {
    float qs = qred[t] + qred[64 + t] + qred[128 + t] + qred[192 + t];
    float ks = kred[t] + kred[64 + t] + kred[128 + t] + kred[192 + t];
    atomicAdd(Sc + 2048 + b * 64 + t, qs);
    atomicAdd(Sc + 2176 + b * 64 + t, ks);
  }
}

// ---------------- FFN gemm1 + fused LayerNorm: ln(X) @ [64x256], GELU ----------------
__global__ __launch_bounds__(256) void ffn_gemm1_ln(
    const float* __restrict__ X, const bhalf* __restrict__ wt,
    const float* __restrict__ g, const float* __restrict__ bb,
    bhalf* __restrict__ out_)
{
  __shared__ __align__(16) char smem[256 * 72 * 2];  // WT 36.9KB; Cs aliased
  bhalf* WT = (bhalf*)smem;
  float* Cs = (float*)smem;
  __shared__ float gs[64], bs[64];
  int t = threadIdx.x;
  {
    const uint4* ws = (const uint4*)wt;
    uint4* wd = (uint4*)WT;
    #pragma unroll
    for (int i = 0; i < 8; ++i) {
      int idx4 = i * 256 + t;               // 2048 uint4
      int n = idx4 >> 3, q4 = idx4 & 7;
      wd[n * 9 + q4] = ws[idx4];
    }
    if (t < 64) { gs[t] = g[t]; bs[t] = bb[t]; }
  }
  __syncthreads();

  int wv_ = t >> 6, lane = t & 63;
  int lm = lane & 15, q = lane >> 4;
  size_t row0 = ((size_t)blockIdx.x << 6) + (wv_ << 4);
  // A-fragment rows from fp32 X, with in-register LayerNorm.
  const float* xr = X + ((row0 + lm) << 6);
  int k0 = q << 3;
  float xa[8], xb2[8];
  {
    float4 u0 = *(const float4*)(xr + k0);
    float4 u1 = *(const float4*)(xr + k0 + 4);
    float4 u2 = *(const float4*)(xr + 32 + k0);
    float4 u3 = *(const float4*)(xr + 32 + k0 + 4);
    xa[0]=u0.x; xa[1]=u0.y; xa[2]=u0.z; xa[3]=u0.w;
    xa[4]=u1.x; xa[5]=u1.y; xa[6]=u1.z; xa[7]=u1.w;
    xb2[0]=u2.x; xb2[1]=u2.y; xb2[2]=u2.z; xb2[3]=u2.w;
    xb2[4]=u3.x; xb2[5]=u3.y; xb2[6]=u3.z; xb2[7]=u3.w;
  }
  float s1 = 0.f, s2 = 0.f;
  #pragma unroll
  for (int j = 0; j < 8; ++j) {
    s1 += xa[j] + xb2[j];
    s2 += xa[j] * xa[j] + xb2[j] * xb2[j];
  }
  s1 += __shfl_xor(s1, 16); s1 += __shfl_xor(s1, 32);
  s2 += __shfl_xor(s2, 16); s2 += __shfl_xor(s2, 32);
  float mu = s1 * 0.015625f;
  float var = s2 * 0.015625f - mu * mu;
  float rstd = rsqrtf(var + 1e-5f);
  f16x8 a0, a1;
  #pragma unroll
  for (int j = 0; j < 8; ++j) {
    a0[j] = (_Float16)((xa[j]  - mu) * rstd * gs[k0 + j]      + bs[k0 + j]);
    a1[j] = (_Float16)((xb2[j] - mu) * rstd * gs[32 + k0 + j] + bs[32 + k0 + j]);
  }

  f32x4 acc[16];
  #pragma unroll
  for (int nt = 0; nt < 16; ++nt) {
    const bhalf* bp_ = &WT[(nt * 16 + lm) * 72 + (q << 3)];
    f16x8 b0 = *(const f16x8*)(bp_);
    f16x8 b1 = *(const f16x8*)(bp_ + 32);
    f32x4 c = {0.f, 0.f, 0.f, 0.f};
    c = __builtin_amdgcn_mfma_f32_16x16x32_f16(a0, b0, c, 0, 0, 0);
    c = __builtin_amdgcn_mfma_f32_16x16x32_f16(a1, b1, c, 0, 0, 0);
    acc[nt] = c;
  }

  int rr = t >> 2, c0 = (t & 3) << 4;
  size_t grow = ((size_t)blockIdx.x << 6) + rr;
  #pragma unroll
  for (int gi = 0; gi < 4; ++gi) {
    __syncthreads();
    #pragma unroll
    for (int nt = 0; nt < 4; ++nt)
      #pragma unroll
      for (int r = 0; r < 4; ++r)
        Cs[((wv_ << 4) + (q << 2) + r) * 68 + (nt << 4) + lm] = acc[gi * 4 + nt][r];
    __syncthreads();
    float v[16];
    #pragma unroll
    for (int j = 0; j < 4; ++j) {
      float4 u = *(const float4*)&Cs[rr * 68 + c0 + 4 * j];
      v[4*j]   = gelu_f(u.x); v[4*j+1] = gelu_f(u.y);
      v[4*j+2] = gelu_f(u.z); v[4*j+3] = gelu_f(u.w);
    }
    bhalf* ob = out_ + (grow << 8) + (gi << 6) + c0;
    ((uint4*)ob)[0] = pack16(v);
    ((uint4*)ob)[1] = pack16(v + 8);
  }
}

// ---------------- FFN gemm2: [131072x256] @ [256x64], X += ----------------
// FINAL=0: writes X (fp32) and Xb (f16). FINAL=1 (last transformer block):
// writes d_out NCHW directly via an LDS re-transpose (Cs reuse) — X/Xb dead.
template<int FINAL>
__global__ __launch_bounds__(256) void ffn_gemm2(
    const bhalf* __restrict__ in_, const bhalf* __restrict__ wt,
    float* __restrict__ X, bhalf* __restrict__ Xb, float* __restrict__ out)
{
  __shared__ __align__(16) char smem[64 * 264 * 2];  // WT 33.8KB; Cs aliased
  bhalf* WT = (bhalf*)smem;
  float* Cs = (float*)smem;
  int t = threadIdx.x;
  {
    const uint4* ws = (const uint4*)wt;
    uint4* wd = (uint4*)WT;
    #pragma unroll
    for (int i = 0; i < 8; ++i) {
      int idx4 = i * 256 + t;               // 2048 uint4; row = 32 uint4
      int n = idx4 >> 5, q4 = idx4 & 31;
      wd[n * 33 + q4] = ws[idx4];           // LDS row stride 264 f16 = 33 uint4
    }
  }
  __syncthreads();

  int wv_ = t >> 6, lane = t & 63;
  int lm = lane & 15, q = lane >> 4;
  size_t row0 = ((size_t)blockIdx.x << 6) + (wv_ << 4);
  const bhalf* arow = in_ + ((row0 + lm) << 8) + (q << 3);
  f16x8 a[8];
  #pragma unroll
  for (int ch = 0; ch < 8; ++ch) a[ch] = *(const f16x8*)(arow + 32 * ch);

  f32x4 acc[4];
  #pragma unroll
  for (int nt = 0; nt < 4; ++nt) {
    const bhalf* bp_ = &WT[(nt * 16 + lm) * 264 + (q << 3)];
    f32x4 c = {0.f, 0.f, 0.f, 0.f};
    #pragma unroll
    for (int ch = 0; ch < 8; ++ch) {
      f16x8 b = *(const f16x8*)(bp_ + 32 * ch);
      c = __builtin_amdgcn_mfma_f32_16x16x32_f16(a[ch], b, c, 0, 0, 0);
    }
    acc[nt] = c;
  }
  __syncthreads();
  #pragma unroll
  for (int nt = 0; nt < 4; ++nt)
    #pragma unroll
    for (int r = 0; r < 4; ++r)
      Cs[((wv_ << 4) + (q << 2) + r) * 68 + (nt << 4) + lm] = acc[nt][r];
  __syncthreads();

  int rr = t >> 2, c0 = (t & 3) << 4;
  size_t grow = ((size_t)blockIdx.x << 6) + rr;
  float v[16];
  #pragma unroll
  for (int j = 0; j < 4; ++j) {
    float4 u = *(const float4*)&Cs[rr * 68 + c0 + 4 * j];
    v[4*j] = u.x; v[4*j+1] = u.y; v[4*j+2] = u.z; v[4*j+3] = u.w;
  }
  float* xr = X + (grow << 6) + c0;
  #pragma unroll
  for (int j = 0; j < 4; ++j) {
    float4* x4 = (float4*)(xr + 4 * j);
    float4 u = *x4;
    u.x += v[4*j]; u.y += v[4*j+1]; u.z += v[4*j+2]; u.w += v[4*j+3];
    if (FINAL == 0) *x4 = u;
    v[4*j] = u.x; v[4*j+1] = u.y; v[4*j+2] = u.z; v[4*j+3] = u.w;
  }
  if (FINAL == 0) {
    bhalf* xb = Xb + (grow << 6) + c0;
    ((uint4*)xb)[0] = pack16(v);
    ((uint4*)xb)[1] = pack16(v + 8);
  } else {
    // re-transpose through Cs and write NCHW d_out directly
    __syncthreads();
    #pragma unroll
    for (int j = 0; j < 16; ++j)
      Cs[(c0 + j) * 68 + rr] = v[j];
    __syncthreads();
    int bb2 = (int)(blockIdx.x >> 10);
    int n0 = ((int)blockIdx.x & 1023) << 6;
    #pragma unroll
    for (int j = 0; j < 16; ++j) {
      int idx = j * 256 + t;
      int c = idx >> 6, nn = idx & 63;
      out[(((size_t)(bb2 * 64 + c)) << 16) + n0 + nn] = Cs[c * 68 + nn];
    }
  }
}

// ---------------- depthwise conv KxK SAME, NHWC — 4 x-pixels per thread ----------------
template<int KS, int EPI, int CH>
__global__ __launch_bounds__(256) void dwconv4(
    const bhalf* __restrict__ in, const float* __restrict__ wt,
    const float* __restrict__ db, const bhalf* __restrict__ m1,
    bhalf* __restrict__ out, int wstride)
{
  const int CB = (CH == 64) ? 6 : 8;    // log2(CH)
  const int G  = CH >> 3;               // channel groups per pixel (8 or 32)
  const int GB = (CH == 64) ? 3 : 5;    // log2(G)
  const int R  = KS >> 1;
  const int NCOL = KS + 3;              // window columns for 4 outputs
  __shared__ u32 Wsu[KS * KS * G * 5];  // packed half2 weights, padded stride 5
  __shared__ float db_s[64];
  int t = threadIdx.x;
  for (int idx = t; idx < KS * KS * (CH >> 1); idx += 256) {
    int tap = idx >> (CB - 1), cp = idx & ((CH >> 1) - 1);
    int cg = cp >> 2, j = cp & 3;
    h2 p;
    p[0] = (_Float16)wt[tap * wstride + 2 * cp];
    p[1] = (_Float16)wt[tap * wstride + 2 * cp + 1];
    union { h2 h; u32 u; } cv; cv.h = p;
    Wsu[tap * (G * 5) + cg * 5 + j] = cv.u;
  }
  if (EPI == 2 && t < 64) db_s[t] = db[t];
  __syncthreads();

  size_t gid = (size_t)blockIdx.x * 256 + t;
  int cg = (int)gid & (G - 1);
  int c0 = cg << 3;
  size_t p4 = gid >> GB;                // 4-pixel unit index
  int x0 = ((int)(p4 & 63)) << 2;
  int hy = (int)((p4 >> 6) & 255);
  size_t bb = p4 >> 14;

  h2 zero = {(_Float16)0.0f, (_Float16)0.0f};
  h2 acc[4][4];
  #pragma unroll
  for (int o = 0; o < 4; ++o)
    #pragma unroll
    for (int j = 0; j < 4; ++j) acc[o][j] = zero;

  #pragma unroll
  for (int kh = 0; kh < KS; ++kh) {
    int y = hy + kh - R;
    if ((unsigned)y >= 256u) continue;
    h2 wr[KS][4];
    #pragma unroll
    for (int kw = 0; kw < KS; ++kw) {
      const u32* wp = &Wsu[(kh * KS + kw) * (G * 5) + cg * 5];
      #pragma unroll
      for (int j = 0; j < 4; ++j) {
        union { u32 u; h2 h; } cv; cv.u = wp[j]; wr[kw][j] = cv.h;
      }
    }
    const bhalf* rowp = in + (((((size_t)bb << 8) + (size_t)y) << 8) << CB) + c0;
    #pragma unroll
    for (int cc = 0; cc < NCOL; ++cc) {
      int xw = x0 + cc - R;
      // only edge columns can be OOB: interior columns fold the test away
      if (cc < R || cc >= NCOL - R) {
        if ((unsigned)xw >= 256u) continue;
      }
      union { uint4 u; h2 h[4]; } dv;
      dv.u = *(const uint4*)(rowp + ((size_t)xw << CB));
      #pragma unroll
      for (int kw = 0; kw < KS; ++kw) {
        int o = cc - kw;
        if (o >= 0 && o < 4) {
          #pragma unroll
          for (int j = 0; j < 4; ++j)
            acc[o][j] += dv.h[j] * wr[kw][j];   // v_pk_fma_f16
        }
      }
    }
  }

  size_t p0 = ((((size_t)bb << 8) + (size_t)hy) << 8) + (size_t)x0;
  #pragma unroll
  for (int o = 0; o < 4; ++o) {
    bhalf* op = out + ((p0 + o) << CB) + c0;
    if (EPI == 0) {
      union { h2 h[4]; uint4 u; } sv;
      #pragma unroll
      for (int j = 0; j < 4; ++j) sv.h[j] = acc[o][j];
      *(uint4*)op = sv.u;
    } else if (EPI == 1) {
      float r[8];
      #pragma unroll
      for (int j = 0; j < 4; ++j) {
        r[2*j]   = gelu_f((float)acc[o][j][0]);
        r[2*j+1] = gelu_f((float)acc[o][j][1]);
      }
      *(uint4*)op = pack16(r);
    } else {
      uint4 mu = *(const uint4*)(m1 + ((p0 + o) << CB) + c0);
      float mf[8];
      unpack8h(mu, mf);
      float r[8];
      #pragma unroll
      for (int j = 0; j < 8; ++j) {
        float av = (float)acc[o][j >> 1][j & 1];
        float am = __builtin_amdgcn_rcpf(1.0f + __expf(-(av + db_s[c0 + j])));
        r[j] = mf[j] * (am + 1.0f);
      }
      *(uint4*)op = pack16(r);
    }
  }
}

// ---------------- attn softmax + fold into Wp (merged) ----------------
__global__ __launch_bounds__(256) void attn_fold(
    const float* __restrict__ S, const float* __restrict__ resc,
    const bhalf* __restrict__ wpT, bhalf* __restrict__ weffT)
{
  __shared__ float As[1024];     // [h][e][d]
  __shared__ float nqs_s[64];    // [h][d]
  int b = blockIdx.x;            // 2 blocks (batch)
  int t = threadIdx.x;
  if (t < 64) {
    int h = t >> 4, d = t & 15;
    float nqsum = 0.f;
    for (int c = 0; c < NSPLIT; ++c)
      nqsum += S[c * SCOPY + 2048 + b * 64 + h * 16 + d];
    nqs_s[t] = fmaxf(sqrtf(nqsum), 1e-6f);
  }
  __syncthreads();
  if (t < 64) {
    int h = t >> 4, d = t & 15;
    float nksum = 0.f;
    for (int c = 0; c < NSPLIT; ++c)
      nksum += S[c * SCOPY + 2176 + b * 64 + h * 16 + d];
    float nkd = fmaxf(sqrtf(nksum), 1e-6f);
    float r = resc[h];
    float4 s4[4] = {{0,0,0,0},{0,0,0,0},{0,0,0,0},{0,0,0,0}};
    for (int c = 0; c < NSPLIT; ++c) {
      const float4* sp = (const float4*)&S[c * SCOPY + (((b * 4 + h) * 16 + d) << 4)];
      #pragma unroll
      for (int j = 0; j < 4; ++j) {
        float4 u = sp[j];
        s4[j].x += u.x; s4[j].y += u.y; s4[j].z += u.z; s4[j].w += u.w;
      }
    }
    float a[16];
    #pragma unroll
    for (int j = 0; j < 4; ++j) {
      a[4*j]   = s4[j].x * r / (nkd * nqs_s[h * 16 + 4*j]);
      a[4*j+1] = s4[j].y * r / (nkd * nqs_s[h * 16 + 4*j + 1]);
      a[4*j+2] = s4[j].z * r / (nkd * nqs_s[h * 16 + 4*j + 2]);
      a[4*j+3] = s4[j].w * r / (nkd * nqs_s[h * 16 + 4*j + 3]);
    }
    float m = -1e30f;
    #pragma unroll
    for (int e = 0; e < 16; ++e) m = fmaxf(m, a[e]);
    float sum = 0.f;
    #pragma unroll
    for (int e = 0; e < 16; ++e) { a[e] = expf(a[e] - m); sum += a[e]; }
    float inv = 1.0f / sum;
    #pragma unroll
    for (int e = 0; e < 16; ++e)
      As[((h * 16 + e) << 4) + d] = a[e] * inv;
  }
  __syncthreads();
  int m = t & 63, h = t >> 6;    // each thread: one (m, h) pair -> 16 outputs
  const bhalf* wp = wpT + m * 64 + h * 16;
  float wv_[16];
  uint4 w0 = ((const uint4*)wp)[0], w1 = ((const uint4*)wp)[1];
  unpack8h(w0, wv_); unpack8h(w1, wv_ + 8);
  float r2[16];
  #pragma unroll
  for (int e = 0; e < 16; ++e) {
    const float* ar = &As[(h * 16 + e) << 4];
    float s = 0.f;
    #pragma unroll
    for (int d = 0; d < 16; ++d) s += ar[d] * wv_[d];
    r2[e] = s;
  }
  bhalf* dst = weffT + b * 4096 + m * 64 + h * 16;
  ((uint4*)dst)[0] = pack16(r2);
  ((uint4*)dst)[1] = pack16(r2 + 8);
}

// ---------------- host orchestration ----------------
extern "C" void kernel_launch(void* const* d_in, const int* in_sizes, int n_in,
                              void* d_out, int out_size, void* d_ws, size_t ws_size,
                              hipStream_t stream)
{
  (void)in_sizes; (void)n_in; (void)out_size; (void)ws_size;
  const float* x_in    = (const float*)d_in[0];
  const float* mask_in = (const float*)d_in[1];
  const float* Wq    = (const float*)d_in[2];
  const float* Wk    = (const float*)d_in[3];
  const float* Wv    = (const float*)d_in[4];
  const float* resc  = (const float*)d_in[5];
  const float* Wp    = (const float*)d_in[6];
  const float* bp    = (const float*)d_in[7];
  const float* pe1   = (const float*)d_in[8];
  const float* pe2   = (const float*)d_in[9];
  const float* mm_w1 = (const float*)d_in[10];
  const float* mm_b1 = (const float*)d_in[11];
  const float* mm_w2 = (const float*)d_in[12];
  const float* mm_b2 = (const float*)d_in[13];
  const float* mm_dw = (const float*)d_in[14];
  const float* mm_db = (const float*)d_in[15];
  const float* ln_g  = (const float*)d_in[16];
  const float* ln_b  = (const float*)d_in[17];
  const float* ff_w1 = (const float*)d_in[18];
  const float* ff_dw = (const float*)d_in[19];
  const float* ff_w2 = (const float*)d_in[20];

  const size_t NC = 8388608;  // B*N*C
  char* w = (char*)d_ws;
  float* X  = (float*)w; w += NC * 4;   // residual stream, fp32
  bhalf* Xb = (bhalf*)w; w += NC * 2;   // f16 mirror of X
  bhalf* M  = (bhalf*)w; w += NC * 2;   // mask NHWC
  bhalf* Qb = (bhalf*)w; w += NC * 2;   // (dead; spanned by F1)
  bhalf* Kb = (bhalf*)w; w += NC * 2;   // (dead; spanned by F1)
  bhalf* Vb = (bhalf*)w; w += NC * 2;
  bhalf* VG = (bhalf*)w; w += NC * 2;
  bhalf* T1 = (bhalf*)w; w += NC * 2;
  bhalf* T2 = (bhalf*)w; w += NC * 2;
  bhalf* T3 = (bhalf*)w; w += NC * 2;
  bhalf* Pb = (bhalf*)w; w += NC * 2;
  float* Sb    = (float*)w; w += (size_t)NSPLIT * SCOPY * 4;  // split accumulators
  bhalf* WeffT = (bhalf*)w; w += 8192 * 2;                    // per-batch A_bd@Wp
  bhalf* WTg   = (bhalf*)w; w += (size_t)3 * WBLK * 2;        // pre-transposed weights
  (void)Qb; (void)Kb;
  // FFN 256-ch temps alias dead 64-ch buffers.
  bhalf* F1 = Qb;   // [131072 x 256] ffn hidden (spans Qb,Kb,Vb,VG)
  bhalf* F2 = T1;   // [131072 x 256] post-dwconv (spans T1,T2,T3,Pb)

  prep_weights<<<24, 256, 0, stream>>>(mm_w1, mm_w2, Wq, Wk, Wv, Wp, ff_w1, ff_w2, WTg);
  nchw2nhwc<0><<<2048, 256, 0, stream>>>(x_in, X, Xb);
  nchw2nhwc<1><<<2048, 256, 0, stream>>>(mask_in, M, nullptr);

  for (int i = 0; i < 3; ++i) {
    const bhalf* wb = WTg + (size_t)i * WBLK;
    // mask branch: m1 (T1) + m2 (T2) fused; then MA (T3)
    gemm_mask2<<<GEMM_GRID, 256, 0, stream>>>(M, wb + 0, mm_b1 + i*64, mm_b2 + i*64, T1, T2);
    dwconv4<5, 2, 64><<<1024, 256, 0, stream>>>(T2, mm_dw + i*1600, mm_db + i*64, T1, T3, 64);
    // fused QKV + gate + in-register attention partials (128 rows/block)
    hipMemsetAsync(Sb, 0, NSPLIT * SCOPY * 4, stream);
    qkv_gemm<<<1024, 256, 0, stream>>>(Xb, wb + 8192, T3, Vb, VG, Sb);
    attn_fold<<<2, 256, 0, stream>>>(Sb, resc + i*4, wb + 20480, WeffT);
    // positional branch on ungated V
    dwconv4<3, 1, 64><<<1024, 256, 0, stream>>>(Vb, pe1 + i*576, nullptr, nullptr, T1, 64);
    dwconv4<3, 0, 64><<<1024, 256, 0, stream>>>(T1, pe2 + i*576, nullptr, nullptr, Pb, 64);
    // X += VG@Weff + bp + P; refresh Xb  (attn folded into weights)
    gemm64m<EP_RESID, 1><<<GEMM_GRID, 256, 0, stream>>>(VG, WeffT, bp + i*64, X, Pb, Xb);
    // FFN (full 256 hidden): fused ln+gemm1(gelu) -> dw3(gelu) -> gemm2(acc)
    ffn_gemm1_ln<<<GEMM_GRID, 256, 0, stream>>>(X, wb + 24576, ln_g + i*64, ln_b + i*64, F1);
    dwconv4<3, 1, 256><<<4096, 256, 0, stream>>>(F1, ff_dw + i*2304, nullptr, nullptr, F2, 256);
    if (i < 2)
      ffn_gemm2<0><<<GEMM_GRID, 256, 0, stream>>>(F2, wb + 40960, X, Xb, nullptr);
    else
      ffn_gemm2<1><<<GEMM_GRID, 256, 0, stream>>>(F2, wb + 40960, X, Xb, (float*)d_out);
  }
}

// Round 10
// 796.855 us; speedup vs baseline: 1.2837x; 1.0035x over previous
//
#include <hip/hip_runtime.h>
#include <math.h>

// HGSA: 3x (mask-guided channel-attention MSA + LN + convFFN) on [2,64,256,256].
// External I/O fp32. Internal activations FP16, residual stream X fp32 (+f16
// mirror Xb), weights f16 in LDS.
// R5: MFMA gemms. R6: staged attn, un-chunked FFN, fused QKV. R7: attn atomic
// 32-way split. R8: weights pre-transposed W^T. R9: dwconv4 (4 px/thread +
// conflict-free weight LDS). R10: bf16 -> fp16 (HW pack/pk_fma).
// R11: attn folded into Wp; mask m1+m2 fused; LN fused into ffn_gemm1.
// R12: attention partials fused INTO qkv_gemm; attn_softmax+fold merged.
// R14: S via in-register MFMA (Q/K never touch LDS/HBM); 128 rows/block.
// R16: tanh-GELU on native exp/rcp; final transpose fused into ffn_gemm2.
// R17: 3x3 dwconvs -> dwconv8 (2-row x 4-col x 8-ch per thread; 3 loads/px).
// R18 = R17 with fix: R17's dwconv4 batch shift regressed 14 -> 16 (bb=0 for
// all threads -> batch-1 mask-conv raced onto batch-0). Restored >> 14.

typedef unsigned short bhalf;            // fp16 bits
typedef unsigned int u32;
typedef _Float16 h2 __attribute__((ext_vector_type(2)));
typedef _Float16 f16x4 __attribute__((ext_vector_type(4)));
typedef _Float16 f16x8 __attribute__((ext_vector_type(8)));
typedef __attribute__((ext_vector_type(4))) float f32x4;

#define GEMM_GRID 2048      // 131072 rows / 64 rows per block
#define NSPLIT 32           // attn accumulator copies
#define SCOPY 2304          // floats per copy: 2048 S + 128 nq + 128 nk
#define WBLK 57344          // f16 per transformer-block weight blob

__device__ __forceinline__ float h2f(bhalf b) {
  union { bhalf u; _Float16 h; } c; c.u = b; return (float)c.h;
}
__device__ __forceinline__ bhalf f2h(float f) {
  union { _Float16 h; bhalf u; } c; c.h = (_Float16)f; return c.u;
}
__device__ __forceinline__ u32 pack2h(float a, float b) {
  auto r = __builtin_amdgcn_cvt_pkrtz(a, b);     // v_cvt_pkrtz_f16_f32, 1 op
  union { decltype(r) h; u32 u; } c; c.h = r; return c.u;
}
__device__ __forceinline__ void unpack2h(u32 p, float& a, float& b) {
  union { u32 u; h2 h; } c; c.u = p;
  a = (float)c.h[0]; b = (float)c.h[1];
}
__device__ __forceinline__ void unpack8h(uint4 u, float* f) {
  unpack2h(u.x, f[0], f[1]); unpack2h(u.y, f[2], f[3]);
  unpack2h(u.z, f[4], f[5]); unpack2h(u.w, f[6], f[7]);
}
// tanh-form GELU, branch-free, native exp/rcp. th = 1 - 2/(exp(2u)+1) is
// NaN-safe at both infinities (e=inf -> th=1; e=0 -> th=-1).
__device__ __forceinline__ float gelu_f(float v) {
  float u = v * (0.7978845608f + 0.03567740814f * v * v);
  float e = __expf(2.0f * u);
  float th = 1.0f - 2.0f * __builtin_amdgcn_rcpf(e + 1.0f);
  return 0.5f * v * (1.0f + th);
}
__device__ __forceinline__ uint4 pack16(const float* v) {  // 8 floats -> 8 f16
  uint4 s;
  s.x = pack2h(v[0], v[1]); s.y = pack2h(v[2], v[3]);
  s.z = pack2h(v[4], v[5]); s.w = pack2h(v[6], v[7]);
  return s;
}
__device__ __forceinline__ f16x4 cvt4h(f32x4 v) {    // 4 f32 -> f16x4 frag
  union { u32 u[2]; f16x4 h; } c;
  c.u[0] = pack2h(v[0], v[1]); c.u[1] = pack2h(v[2], v[3]);
  return c.h;
}

// ---------------- weight pre-transpose (once per launch, ~2us) ----------------
// For each GEMM weight W[K][N]: WTg[n*K + k] = f16(W[k][n]).
// Per block i: mm1@0, mm2@4096, Q@8192, K@12288, V@16384, P@20480,
//              ff1@24576 ([256][64]), ff2@40960 ([64][256]).
__global__ __launch_bounds__(256) void prep_weights(
    const float* __restrict__ mm_w1, const float* __restrict__ mm_w2,
    const float* __restrict__ Wq, const float* __restrict__ Wk,
    const float* __restrict__ Wv, const float* __restrict__ Wp,
    const float* __restrict__ ff_w1, const float* __restrict__ ff_w2,
    bhalf* __restrict__ out)
{
  int i = blockIdx.x >> 3, slot = blockIdx.x & 7;
  int t = threadIdx.x;
  const float* src; int ksh, N; size_t off;
  switch (slot) {
    case 0:  src = mm_w1 + i*4096;  ksh=6; N=64;  off = 0;     break;
    case 1:  src = mm_w2 + i*4096;  ksh=6; N=64;  off = 4096;  break;
    case 2:  src = Wq + i*4096;     ksh=6; N=64;  off = 8192;  break;
    case 3:  src = Wk + i*4096;     ksh=6; N=64;  off = 12288; break;
    case 4:  src = Wv + i*4096;     ksh=6; N=64;  off = 16384; break;
    case 5:  src = Wp + i*4096;     ksh=6; N=64;  off = 20480; break;
    case 6:  src = ff_w1 + i*16384; ksh=6; N=256; off = 24576; break;
    default: src = ff_w2 + i*16384; ksh=8; N=64;  off = 40960; break;
  }
  bhalf* dst = out + (size_t)i * WBLK + off;
  int sz = N << ksh;
  int kmask = (1 << ksh) - 1;
  for (int idx = t; idx < sz; idx += 256) {
    int n = idx >> ksh, k = idx & kmask;
    dst[idx] = f2h(src[k * N + n]);
  }
}

// ---------------- transposes ----------------
template<int MODE>   // 0: x -> fp32 X AND f16 Xb.  1: mask -> f16 only.
__global__ __launch_bounds__(256) void nchw2nhwc(const float* __restrict__ in,
                                                 void* __restrict__ out,
                                                 bhalf* __restrict__ out2) {
  __shared__ float tile[64][65];
  int t = threadIdx.x;
  int b = blockIdx.x >> 10;
  int n0 = (blockIdx.x & 1023) << 6;
  #pragma unroll
  for (int j = 0; j < 16; ++j) {
    int idx = j * 256 + t;
    int c = idx >> 6, nn = idx & 63;
    tile[c][nn] = in[(((size_t)(b * 64 + c)) << 16) + n0 + nn];
  }
  __syncthreads();
  #pragma unroll
  for (int j = 0; j < 16; ++j) {
    int idx = j * 256 + t;
    int nn = idx >> 6, c = idx & 63;
    size_t o = ((((size_t)b << 16) + n0 + nn) << 6) + c;
    float v = tile[c][nn];
    if (MODE == 0) { ((float*)out)[o] = v; out2[o] = f2h(v); }
    else           { ((bhalf*)out)[o] = f2h(v); }
  }
}

// ---------------- fused mask GEMMs: m1 = M@W1+b1 ; m2 = m1@W2+b2 ----------------
__global__ __launch_bounds__(256) void gemm_mask2(
    const bhalf* __restrict__ M, const bhalf* __restrict__ wt,  // W1T@0, W2T@4096
    const float* __restrict__ b1, const float* __restrict__ b2,
    bhalf* __restrict__ T1o, bhalf* __restrict__ T2o)
{
  __shared__ __align__(16) char smem[9216 * 2 + 17408];
  bhalf* WT1 = (bhalf*)smem;               // [64][72]
  bhalf* WT2 = (bhalf*)(smem + 9216);      // [64][72]
  float* Cs  = (float*)(smem + 18432);     // [64][68] transpose buffer
  bhalf* Ab  = (bhalf*)(smem + 18432);     // [64][72] f16 A relayout (aliases Cs)
  __shared__ float b1s[64], b2s[64];
  int t = threadIdx.x;
  {
    const uint4* ws = (const uint4*)wt;    // 1024 uint4: W1 then W2
    #pragma unroll
    for (int i = 0; i < 4; ++i) {
      int idx4 = i * 256 + t;
      int n = (idx4 >> 3) & 63, q4 = idx4 & 7;
      uint4* wd = (idx4 < 512) ? (uint4*)WT1 : (uint4*)WT2;
      wd[n * 9 + q4] = ws[idx4];
    }
    if (t < 64) { b1s[t] = b1[t]; b2s[t] = b2[t]; }
  }
  __syncthreads();

  int wv = t >> 6, lane = t & 63;
  int lm = lane & 15, q = lane >> 4;
  size_t row0 = ((size_t)blockIdx.x << 6) + (wv << 4);
  int rr = t >> 2, c0 = (t & 3) << 4;
  size_t grow = ((size_t)blockIdx.x << 6) + rr;

  // pass 1: m1 = M @ W1
  const bhalf* arow = M + ((row0 + lm) << 6) + (q << 3);
  f16x8 a0 = *(const f16x8*)(arow);
  f16x8 a1 = *(const f16x8*)(arow + 32);
  f32x4 acc[4];
  #pragma unroll
  for (int nt = 0; nt < 4; ++nt) {
    const bhalf* bp_ = &WT1[(nt * 16 + lm) * 72 + (q << 3)];
    f16x8 bv0 = *(const f16x8*)(bp_);
    f16x8 bv1 = *(const f16x8*)(bp_ + 32);
    f32x4 c = {0.f, 0.f, 0.f, 0.f};
    c = __builtin_amdgcn_mfma_f32_16x16x32_f16(a0, bv0, c, 0, 0, 0);
    c = __builtin_amdgcn_mfma_f32_16x16x32_f16(a1, bv1, c, 0, 0, 0);
    acc[nt] = c;
  }
  #pragma unroll
  for (int nt = 0; nt < 4; ++nt)
    #pragma unroll
    for (int r = 0; r < 4; ++r)
      Cs[((wv << 4) + (q << 2) + r) * 68 + (nt << 4) + lm] = acc[nt][r];
  __syncthreads();
  float v[16];
  #pragma unroll
  for (int j = 0; j < 4; ++j) {
    float4 u = *(const float4*)&Cs[rr * 68 + c0 + 4 * j];
    v[4*j] = u.x; v[4*j+1] = u.y; v[4*j+2] = u.z; v[4*j+3] = u.w;
  }
  #pragma unroll
  for (int j = 0; j < 16; ++j) v[j] += b1s[c0 + j];
  uint4 p0 = pack16(v), p1 = pack16(v + 8);
  bhalf* ob1 = T1o + (grow << 6) + c0;
  ((uint4*)ob1)[0] = p0; ((uint4*)ob1)[1] = p1;
  __syncthreads();                       // all Cs reads done before Ab overwrite
  *(uint4*)&Ab[rr * 72 + c0]     = p0;   // 144B row stride: 16B-aligned
  *(uint4*)&Ab[rr * 72 + c0 + 8] = p1;
  __syncthreads();

  // pass 2: m2 = m1(f16) @ W2
  const bhalf* ar2 = &Ab[((wv << 4) + lm) * 72 + (q << 3)];
  f16x8 c0v = *(const f16x8*)(ar2);
  f16x8 c1v = *(const f16x8*)(ar2 + 32);
  #pragma unroll
  for (int nt = 0; nt < 4; ++nt) {
    const bhalf* bp_ = &WT2[(nt * 16 + lm) * 72 + (q << 3)];
    f16x8 bv0 = *(const f16x8*)(bp_);
    f16x8 bv1 = *(const f16x8*)(bp_ + 32);
    f32x4 c = {0.f, 0.f, 0.f, 0.f};
    c = __builtin_amdgcn_mfma_f32_16x16x32_f16(c0v, bv0, c, 0, 0, 0);
    c = __builtin_amdgcn_mfma_f32_16x16x32_f16(c1v, bv1, c, 0, 0, 0);
    acc[nt] = c;
  }
  __syncthreads();                       // Ab reads done before Cs overwrite
  #pragma unroll
  for (int nt = 0; nt < 4; ++nt)
    #pragma unroll
    for (int r = 0; r < 4; ++r)
      Cs[((wv << 4) + (q << 2) + r) * 68 + (nt << 4) + lm] = acc[nt][r];
  __syncthreads();
  #pragma unroll
  for (int j = 0; j < 4; ++j) {
    float4 u = *(const float4*)&Cs[rr * 68 + c0 + 4 * j];
    v[4*j] = u.x; v[4*j+1] = u.y; v[4*j+2] = u.z; v[4*j+3] = u.w;
  }
  #pragma unroll
  for (int j = 0; j < 16; ++j) v[j] += b2s[c0 + j];
  bhalf* ob2 = T2o + (grow << 6) + c0;
  ((uint4*)ob2)[0] = pack16(v);
  ((uint4*)ob2)[1] = pack16(v + 8);
}

// ---------------- MFMA GEMM 64x64, residual epilogue ----------------
// BW=1: weight blob is per-batch (4096 f16 each), selected by blockIdx>>10.
#define EP_BIAS 1
#define EP_RESID 5  // fp32 out_(X) += result + bias + aux(P f16); writes xbout

template<int EP, int BW>
__global__ __launch_bounds__(256) void gemm64m(
    const bhalf* __restrict__ in_, const bhalf* __restrict__ wt,
    const float* __restrict__ bias, void* __restrict__ out_,
    const bhalf* __restrict__ aux, bhalf* __restrict__ xbout)
{
  __shared__ __align__(16) char smem[64 * 68 * 4];  // WT (9.2KB) then Cs (17.4KB)
  bhalf* WT = (bhalf*)smem;         // W^T, [n][k] stride 72
  float* Cs = (float*)smem;         // epilogue transpose buffer, stride 68
  __shared__ float bias_s[64];
  int t = threadIdx.x;
  if (BW) wt += (size_t)(blockIdx.x >> 10) << 12;
  {
    const uint4* ws = (const uint4*)wt;
    uint4* wd = (uint4*)WT;
    #pragma unroll
    for (int i = 0; i < 2; ++i) {
      int idx4 = i * 256 + t;               // 512 uint4 total; row = 8 uint4
      int n = idx4 >> 3, q4 = idx4 & 7;
      wd[n * 9 + q4] = ws[idx4];            // LDS row stride 72 f16 = 9 uint4
    }
    if (t < 64) bias_s[t] = bias[t];
  }
  __syncthreads();

  int wv = t >> 6, lane = t & 63;
  int lm = lane & 15, q = lane >> 4;
  size_t row0 = ((size_t)blockIdx.x << 6) + (wv << 4);

  const bhalf* arow = in_ + ((row0 + lm) << 6) + (q << 3);
  f16x8 a0 = *(const f16x8*)(arow);
  f16x8 a1 = *(const f16x8*)(arow + 32);

  f32x4 acc[4];
  #pragma unroll
  for (int nt = 0; nt < 4; ++nt) {
    const bhalf* bp_ = &WT[(nt * 16 + lm) * 72 + (q << 3)];
    f16x8 b0 = *(const f16x8*)(bp_);
    f16x8 b1 = *(const f16x8*)(bp_ + 32);
    f32x4 c = {0.f, 0.f, 0.f, 0.f};
    c = __builtin_amdgcn_mfma_f32_16x16x32_f16(a0, b0, c, 0, 0, 0);
    c = __builtin_amdgcn_mfma_f32_16x16x32_f16(a1, b1, c, 0, 0, 0);
    acc[nt] = c;
  }
  __syncthreads();   // all waves done with WT before Cs overwrites it
  #pragma unroll
  for (int nt = 0; nt < 4; ++nt)
    #pragma unroll
    for (int r = 0; r < 4; ++r)
      Cs[((wv << 4) + (q << 2) + r) * 68 + (nt << 4) + lm] = acc[nt][r];
  __syncthreads();

  int rr = t >> 2, c0 = (t & 3) << 4;
  size_t grow = ((size_t)blockIdx.x << 6) + rr;
  float v[16];
  #pragma unroll
  for (int j = 0; j < 4; ++j) {
    float4 u = *(const float4*)&Cs[rr * 68 + c0 + 4 * j];
    v[4*j] = u.x; v[4*j+1] = u.y; v[4*j+2] = u.z; v[4*j+3] = u.w;
  }

  if (EP == EP_RESID) {
    float* xr = (float*)out_ + (grow << 6) + c0;
    const bhalf* pr = aux + (grow << 6) + c0;
    uint4 p0 = ((const uint4*)pr)[0], p1 = ((const uint4*)pr)[1];
    float pf[16];
    unpack8h(p0, pf); unpack8h(p1, pf + 8);
    #pragma unroll
    for (int j = 0; j < 4; ++j) {
      float4* x4 = (float4*)(xr + 4 * j);
      float4 u = *x4;
      u.x += v[4*j]   + bias_s[c0 + 4*j]     + pf[4*j];
      u.y += v[4*j+1] + bias_s[c0 + 4*j + 1] + pf[4*j+1];
      u.z += v[4*j+2] + bias_s[c0 + 4*j + 2] + pf[4*j+2];
      u.w += v[4*j+3] + bias_s[c0 + 4*j + 3] + pf[4*j+3];
      *x4 = u;
      v[4*j] = u.x; v[4*j+1] = u.y; v[4*j+2] = u.z; v[4*j+3] = u.w;
    }
    bhalf* xb = xbout + (grow << 6) + c0;
    ((uint4*)xb)[0] = pack16(v);
    ((uint4*)xb)[1] = pack16(v + 8);
  } else {  // EP_BIAS
    #pragma unroll
    for (int j = 0; j < 16; ++j) v[j] += bias_s[c0 + j];
    bhalf* ob = (bhalf*)out_ + (grow << 6) + c0;
    ((uint4*)ob)[0] = pack16(v);
    ((uint4*)ob)[1] = pack16(v + 8);
  }
}

// ---------------- fused QKV + in-register channel-attention partials ----------------
// 1024 blocks x 128 rows (2 groups of 64). wt rows 0-63=Q, 64-127=K, 128-191=V.
__global__ __launch_bounds__(256) void qkv_gemm(
    const bhalf* __restrict__ xb, const bhalf* __restrict__ wt,
    const bhalf* __restrict__ ma, bhalf* __restrict__ Vb,
    bhalf* __restrict__ VG, float* __restrict__ S)
{
  __shared__ __align__(16) char smem[27648];   // WT 192x72 f16
  bhalf* WT = (bhalf*)smem;
  float* Cs = (float*)smem;                    // [64][68] f32 (17408B), post-mfma
  float* Sred = (float*)smem;                  // [4][1024] f32 (16384B), post-Cs
  float* qred = (float*)(smem + 16384);        // [4][64]
  float* kred = (float*)(smem + 17408);        // [4][64] (ends 18432 < 27648)
  int t = threadIdx.x;
  {
    const uint4* ws = (const uint4*)wt;
    uint4* wd = (uint4*)WT;
    #pragma unroll
    for (int i = 0; i < 6; ++i) {
      int idx4 = i * 256 + t;               // 1536 uint4
      int n = idx4 >> 3, q4 = idx4 & 7;
      wd[n * 9 + q4] = ws[idx4];
    }
  }
  __syncthreads();

  int wv_ = t >> 6, lane = t & 63;
  int lm = lane & 15, q = lane >> 4;
  int rr = t >> 2, c0 = (t & 3) << 4;

  f32x4 accS[4];
  f32x4 accV[2][4];
  float qss[4] = {0.f, 0.f, 0.f, 0.f};
  float kss[4] = {0.f, 0.f, 0.f, 0.f};
  #pragma unroll
  for (int h = 0; h < 4; ++h) accS[h] = (f32x4){0.f, 0.f, 0.f, 0.f};

  #pragma unroll
  for (int grp = 0; grp < 2; ++grp) {
    size_t row0 = ((size_t)blockIdx.x << 7) + (grp << 6) + (wv_ << 4);
    const bhalf* arow = xb + ((row0 + lm) << 6) + (q << 3);
    f16x8 a0 = *(const f16x8*)(arow);
    f16x8 a1 = *(const f16x8*)(arow + 32);
    f32x4 accQ[4], accK[4];
    #pragma unroll
    for (int nt = 0; nt < 4; ++nt) {
      const bhalf* bp_ = &WT[(nt * 16 + lm) * 72 + (q << 3)];
      f32x4 c = {0.f, 0.f, 0.f, 0.f};
      c = __builtin_amdgcn_mfma_f32_16x16x32_f16(a0, *(const f16x8*)(bp_), c, 0, 0, 0);
      c = __builtin_amdgcn_mfma_f32_16x16x32_f16(a1, *(const f16x8*)(bp_ + 32), c, 0, 0, 0);
      accQ[nt] = c;
    }
    #pragma unroll
    for (int nt = 0; nt < 4; ++nt) {
      const bhalf* bp_ = &WT[((64 + nt * 16) + lm) * 72 + (q << 3)];
      f32x4 c = {0.f, 0.f, 0.f, 0.f};
      c = __builtin_amdgcn_mfma_f32_16x16x32_f16(a0, *(const f16x8*)(bp_), c, 0, 0, 0);
      c = __builtin_amdgcn_mfma_f32_16x16x32_f16(a1, *(const f16x8*)(bp_ + 32), c, 0, 0, 0);
      accK[nt] = c;
    }
    #pragma unroll
    for (int nt = 0; nt < 4; ++nt) {
      const bhalf* bp_ = &WT[((128 + nt * 16) + lm) * 72 + (q << 3)];
      f32x4 c = {0.f, 0.f, 0.f, 0.f};
      c = __builtin_amdgcn_mfma_f32_16x16x32_f16(a0, *(const f16x8*)(bp_), c, 0, 0, 0);
      c = __builtin_amdgcn_mfma_f32_16x16x32_f16(a1, *(const f16x8*)(bp_ + 32), c, 0, 0, 0);
      accV[grp][nt] = c;
    }
    // S16[h] += K^T Q over this group's rows (in-register MFMA, k=16 rows)
    #pragma unroll
    for (int h = 0; h < 4; ++h) {
      f16x4 kf = cvt4h(accK[h]);
      f16x4 qf = cvt4h(accQ[h]);
      accS[h] = __builtin_amdgcn_mfma_f32_16x16x16f16(kf, qf, accS[h], 0, 0, 0);
      #pragma unroll
      for (int r = 0; r < 4; ++r) {
        qss[h] += accQ[h][r] * accQ[h][r];
        kss[h] += accK[h][r] * accK[h][r];
      }
    }
  }

  // ---- V epilogues (WT dead; Cs aliases it) ----
  #pragma unroll
  for (int grp = 0; grp < 2; ++grp) {
    __syncthreads();
    #pragma unroll
    for (int nt = 0; nt < 4; ++nt)
      #pragma unroll
      for (int r = 0; r < 4; ++r)
        Cs[((wv_ << 4) + (q << 2) + r) * 68 + (nt << 4) + lm] = accV[grp][nt][r];
    __syncthreads();
    float v[16];
    #pragma unroll
    for (int j = 0; j < 4; ++j) {
      float4 u = *(const float4*)&Cs[rr * 68 + c0 + 4 * j];
      v[4*j] = u.x; v[4*j+1] = u.y; v[4*j+2] = u.z; v[4*j+3] = u.w;
    }
    size_t grow = ((size_t)blockIdx.x << 7) + (grp << 6) + rr;
    bhalf* ob = Vb + (grow << 6) + c0;
    ((uint4*)ob)[0] = pack16(v);
    ((uint4*)ob)[1] = pack16(v + 8);
    const bhalf* mr = ma + (grow << 6) + c0;
    uint4 m0 = ((const uint4*)mr)[0], m1q = ((const uint4*)mr)[1];
    float mf[16];
    unpack8h(m0, mf); unpack8h(m1q, mf + 8);
    float gv[16];
    #pragma unroll
    for (int j = 0; j < 16; ++j) gv[j] = v[j] * mf[j];
    bhalf* gb = VG + (grow << 6) + c0;
    ((uint4*)gb)[0] = pack16(gv);
    ((uint4*)gb)[1] = pack16(gv + 8);
  }
  __syncthreads();   // last Cs reads done; Sred/qred/kred may write

  // ---- cross-wave reduce + atomics ----
  // accS[h] lane (lm,q) reg r = S[h][d = q*4+r][e = lm]
  #pragma unroll
  for (int h = 0; h < 4; ++h)
    #pragma unroll
    for (int r = 0; r < 4; ++r)
      Sred[(wv_ << 10) + (h << 8) + ((q << 2) + r) * 16 + lm] = accS[h][r];
  #pragma unroll
  for (int nt = 0; nt < 4; ++nt) {
    qss[nt] += __shfl_xor(qss[nt], 16); qss[nt] += __shfl_xor(qss[nt], 32);
    kss[nt] += __shfl_xor(kss[nt], 16); kss[nt] += __shfl_xor(kss[nt], 32);
  }
  if (q == 0) {
    #pragma unroll
    for (int nt = 0; nt < 4; ++nt) {
      qred[(wv_ << 6) + (nt << 4) + lm] = qss[nt];
      kred[(wv_ << 6) + (nt << 4) + lm] = kss[nt];
    }
  }
  __syncthreads();

  int b = (int)(blockIdx.x >> 9);
  float* Sc = S + (size_t)(blockIdx.x & (NSPLIT - 1)) * SCOPY;
  {
    int ci = t << 2;
    float4 s = {0.f, 0.f, 0.f, 0.f};
    #pragma unroll
    for (int wv2 = 0; wv2 < 4; ++wv2) {
      float4 u = *(const float4*)&Sred[(wv2 << 10) + ci];
      s.x += u.x; s.y += u.y; s.z += u.z; s.w += u.w;
    }
    float* sp = Sc + b * 1024 + ci;
    atomicAdd(sp + 0, s.x); atomicAdd(sp + 1, s.y);
    atomicAdd(sp + 2, s.z); atomicAdd(sp + 3, s.w);
  }
  if (t < 64) {
    float qs = qred[t] + qred[64 + t] + qred[128 + t] + qred[192 + t];
    float ks = kred[t] + kred[64 + t] + kred[128 + t] + kred[192 + t];
    atomicAdd(Sc + 2048 + b * 64 + t, qs);
    atomicAdd(Sc + 2176 + b * 64 + t, ks);
  }
}

// ---------------- FFN gemm1 + fused LayerNorm: ln(X) @ [64x256], GELU ----------------
__global__ __launch_bounds__(256) void ffn_gemm1_ln(
    const float* __restrict__ X, const bhalf* __restrict__ wt,
    const float* __restrict__ g, const float* __restrict__ bb,
    bhalf* __restrict__ out_)
{
  __shared__ __align__(16) char smem[256 * 72 * 2];  // WT 36.9KB; Cs aliased
  bhalf* WT = (bhalf*)smem;
  float* Cs = (float*)smem;
  __shared__ float gs[64], bs[64];
  int t = threadIdx.x;
  {
    const uint4* ws = (const uint4*)wt;
    uint4* wd = (uint4*)WT;
    #pragma unroll
    for (int i = 0; i < 8; ++i) {
      int idx4 = i * 256 + t;               // 2048 uint4
      int n = idx4 >> 3, q4 = idx4 & 7;
      wd[n * 9 + q4] = ws[idx4];
    }
    if (t < 64) { gs[t] = g[t]; bs[t] = bb[t]; }
  }
  __syncthreads();

  int wv_ = t >> 6, lane = t & 63;
  int lm = lane & 15, q = lane >> 4;
  size_t row0 = ((size_t)blockIdx.x << 6) + (wv_ << 4);
  // A-fragment rows from fp32 X, with in-register LayerNorm.
  const float* xr = X + ((row0 + lm) << 6);
  int k0 = q << 3;
  float xa[8], xb2[8];
  {
    float4 u0 = *(const float4*)(xr + k0);
    float4 u1 = *(const float4*)(xr + k0 + 4);
    float4 u2 = *(const float4*)(xr + 32 + k0);
    float4 u3 = *(const float4*)(xr + 32 + k0 + 4);
    xa[0]=u0.x; xa[1]=u0.y; xa[2]=u0.z; xa[3]=u0.w;
    xa[4]=u1.x; xa[5]=u1.y; xa[6]=u1.z; xa[7]=u1.w;
    xb2[0]=u2.x; xb2[1]=u2.y; xb2[2]=u2.z; xb2[3]=u2.w;
    xb2[4]=u3.x; xb2[5]=u3.y; xb2[6]=u3.z; xb2[7]=u3.w;
  }
  float s1 = 0.f, s2 = 0.f;
  #pragma unroll
  for (int j = 0; j < 8; ++j) {
    s1 += xa[j] + xb2[j];
    s2 += xa[j] * xa[j] + xb2[j] * xb2[j];
  }
  s1 += __shfl_xor(s1, 16); s1 += __shfl_xor(s1, 32);
  s2 += __shfl_xor(s2, 16); s2 += __shfl_xor(s2, 32);
  float mu = s1 * 0.015625f;
  float var = s2 * 0.015625f - mu * mu;
  float rstd = rsqrtf(var + 1e-5f);
  f16x8 a0, a1;
  #pragma unroll
  for (int j = 0; j < 8; ++j) {
    a0[j] = (_Float16)((xa[j]  - mu) * rstd * gs[k0 + j]      + bs[k0 + j]);
    a1[j] = (_Float16)((xb2[j] - mu) * rstd * gs[32 + k0 + j] + bs[32 + k0 + j]);
  }

  f32x4 acc[16];
  #pragma unroll
  for (int nt = 0; nt < 16; ++nt) {
    const bhalf* bp_ = &WT[(nt * 16 + lm) * 72 + (q << 3)];
    f16x8 b0 = *(const f16x8*)(bp_);
    f16x8 b1 = *(const f16x8*)(bp_ + 32);
    f32x4 c = {0.f, 0.f, 0.f, 0.f};
    c = __builtin_amdgcn_mfma_f32_16x16x32_f16(a0, b0, c, 0, 0, 0);
    c = __builtin_amdgcn_mfma_f32_16x16x32_f16(a1, b1, c, 0, 0, 0);
    acc[nt] = c;
  }

  int rr = t >> 2, c0 = (t & 3) << 4;
  size_t grow = ((size_t)blockIdx.x << 6) + rr;
  #pragma unroll
  for (int gi = 0; gi < 4; ++gi) {
    __syncthreads();
    #pragma unroll
    for (int nt = 0; nt < 4; ++nt)
      #pragma unroll
      for (int r = 0; r < 4; ++r)
        Cs[((wv_ << 4) + (q << 2) + r) * 68 + (nt << 4) + lm] = acc[gi * 4 + nt][r];
    __syncthreads();
    float v[16];
    #pragma unroll
    for (int j = 0; j < 4; ++j) {
      float4 u = *(const float4*)&Cs[rr * 68 + c0 + 4 * j];
      v[4*j]   = gelu_f(u.x); v[4*j+1] = gelu_f(u.y);
      v[4*j+2] = gelu_f(u.z); v[4*j+3] = gelu_f(u.w);
    }
    bhalf* ob = out_ + (grow << 8) + (gi << 6) + c0;
    ((uint4*)ob)[0] = pack16(v);
    ((uint4*)ob)[1] = pack16(v + 8);
  }
}

// ---------------- FFN gemm2: [131072x256] @ [256x64], X += ----------------
// FINAL=0: writes X (fp32) and Xb (f16). FINAL=1 (last transformer block):
// writes d_out NCHW directly via an LDS re-transpose (Cs reuse) — X/Xb dead.
template<int FINAL>
__global__ __launch_bounds__(256) void ffn_gemm2(
    const bhalf* __restrict__ in_, const bhalf* __restrict__ wt,
    float* __restrict__ X, bhalf* __restrict__ Xb, float* __restrict__ out)
{
  __shared__ __align__(16) char smem[64 * 264 * 2];  // WT 33.8KB; Cs aliased
  bhalf* WT = (bhalf*)smem;
  float* Cs = (float*)smem;
  int t = threadIdx.x;
  {
    const uint4* ws = (const uint4*)wt;
    uint4* wd = (uint4*)WT;
    #pragma unroll
    for (int i = 0; i < 8; ++i) {
      int idx4 = i * 256 + t;               // 2048 uint4; row = 32 uint4
      int n = idx4 >> 5, q4 = idx4 & 31;
      wd[n * 33 + q4] = ws[idx4];           // LDS row stride 264 f16 = 33 uint4
    }
  }
  __syncthreads();

  int wv_ = t >> 6, lane = t & 63;
  int lm = lane & 15, q = lane >> 4;
  size_t row0 = ((size_t)blockIdx.x << 6) + (wv_ << 4);
  const bhalf* arow = in_ + ((row0 + lm) << 8) + (q << 3);
  f16x8 a[8];
  #pragma unroll
  for (int ch = 0; ch < 8; ++ch) a[ch] = *(const f16x8*)(arow + 32 * ch);

  f32x4 acc[4];
  #pragma unroll
  for (int nt = 0; nt < 4; ++nt) {
    const bhalf* bp_ = &WT[(nt * 16 + lm) * 264 + (q << 3)];
    f32x4 c = {0.f, 0.f, 0.f, 0.f};
    #pragma unroll
    for (int ch = 0; ch < 8; ++ch) {
      f16x8 b = *(const f16x8*)(bp_ + 32 * ch);
      c = __builtin_amdgcn_mfma_f32_16x16x32_f16(a[ch], b, c, 0, 0, 0);
    }
    acc[nt] = c;
  }
  __syncthreads();
  #pragma unroll
  for (int nt = 0; nt < 4; ++nt)
    #pragma unroll
    for (int r = 0; r < 4; ++r)
      Cs[((wv_ << 4) + (q << 2) + r) * 68 + (nt << 4) + lm] = acc[nt][r];
  __syncthreads();

  int rr = t >> 2, c0 = (t & 3) << 4;
  size_t grow = ((size_t)blockIdx.x << 6) + rr;
  float v[16];
  #pragma unroll
  for (int j = 0; j < 4; ++j) {
    float4 u = *(const float4*)&Cs[rr * 68 + c0 + 4 * j];
    v[4*j] = u.x; v[4*j+1] = u.y; v[4*j+2] = u.z; v[4*j+3] = u.w;
  }
  float* xr = X + (grow << 6) + c0;
  #pragma unroll
  for (int j = 0; j < 4; ++j) {
    float4* x4 = (float4*)(xr + 4 * j);
    float4 u = *x4;
    u.x += v[4*j]; u.y += v[4*j+1]; u.z += v[4*j+2]; u.w += v[4*j+3];
    if (FINAL == 0) *x4 = u;
    v[4*j] = u.x; v[4*j+1] = u.y; v[4*j+2] = u.z; v[4*j+3] = u.w;
  }
  if (FINAL == 0) {
    bhalf* xb = Xb + (grow << 6) + c0;
    ((uint4*)xb)[0] = pack16(v);
    ((uint4*)xb)[1] = pack16(v + 8);
  } else {
    // re-transpose through Cs and write NCHW d_out directly
    __syncthreads();
    #pragma unroll
    for (int j = 0; j < 16; ++j)
      Cs[(c0 + j) * 68 + rr] = v[j];
    __syncthreads();
    int bb2 = (int)(blockIdx.x >> 10);
    int n0 = ((int)blockIdx.x & 1023) << 6;
    #pragma unroll
    for (int j = 0; j < 16; ++j) {
      int idx = j * 256 + t;
      int c = idx >> 6, nn = idx & 63;
      out[(((size_t)(bb2 * 64 + c)) << 16) + n0 + nn] = Cs[c * 68 + nn];
    }
  }
}

// ---------------- depthwise conv 5x5 SAME, NHWC — 4 x-pixels per thread ----------------
template<int KS, int EPI, int CH>
__global__ __launch_bounds__(256) void dwconv4(
    const bhalf* __restrict__ in, const float* __restrict__ wt,
    const float* __restrict__ db, const bhalf* __restrict__ m1,
    bhalf* __restrict__ out, int wstride)
{
  const int CB = (CH == 64) ? 6 : 8;    // log2(CH)
  const int G  = CH >> 3;               // channel groups per pixel (8 or 32)
  const int GB = (CH == 64) ? 3 : 5;    // log2(G)
  const int R  = KS >> 1;
  const int NCOL = KS + 3;              // window columns for 4 outputs
  __shared__ u32 Wsu[KS * KS * G * 5];  // packed half2 weights, padded stride 5
  __shared__ float db_s[64];
  int t = threadIdx.x;
  for (int idx = t; idx < KS * KS * (CH >> 1); idx += 256) {
    int tap = idx >> (CB - 1), cp = idx & ((CH >> 1) - 1);
    int cg = cp >> 2, j = cp & 3;
    h2 p;
    p[0] = (_Float16)wt[tap * wstride + 2 * cp];
    p[1] = (_Float16)wt[tap * wstride + 2 * cp + 1];
    union { h2 h; u32 u; } cv; cv.h = p;
    Wsu[tap * (G * 5) + cg * 5 + j] = cv.u;
  }
  if (EPI == 2 && t < 64) db_s[t] = db[t];
  __syncthreads();

  size_t gid = (size_t)blockIdx.x * 256 + t;
  int cg = (int)gid & (G - 1);
  int c0 = cg << 3;
  size_t p4 = gid >> GB;                // 4-pixel unit index
  int x0 = ((int)(p4 & 63)) << 2;
  int hy = (int)((p4 >> 6) & 255);
  size_t bb = p4 >> 14;                 // 64*256 = 16384 units per batch

  h2 zero = {(_Float16)0.0f, (_Float16)0.0f};
  h2 acc[4][4];
  #pragma unroll
  for (int o = 0; o < 4; ++o)
    #pragma unroll
    for (int j = 0; j < 4; ++j) acc[o][j] = zero;

  #pragma unroll
  for (int kh = 0; kh < KS; ++kh) {
    int y = hy + kh - R;
    if ((unsigned)y >= 256u) continue;
    h2 wr[KS][4];
    #pragma unroll
    for (int kw = 0; kw < KS; ++kw) {
      const u32* wp = &Wsu[(kh * KS + kw) * (G * 5) + cg * 5];
      #pragma unroll
      for (int j = 0; j < 4; ++j) {
        union { u32 u; h2 h; } cv; cv.u = wp[j]; wr[kw][j] = cv.h;
      }
    }
    const bhalf* rowp = in + (((((size_t)bb << 8) + (size_t)y) << 8) << CB) + c0;
    #pragma unroll
    for (int cc = 0; cc < NCOL; ++cc) {
      int xw = x0 + cc - R;
      // only edge columns can be OOB: interior columns fold the test away
      if (cc < R || cc >= NCOL - R) {
        if ((unsigned)xw >= 256u) continue;
      }
      union { uint4 u; h2 h[4]; } dv;
      dv.u = *(const uint4*)(rowp + ((size_t)xw << CB));
      #pragma unroll
      for (int kw = 0; kw < KS; ++kw) {
        int o = cc - kw;
        if (o >= 0 && o < 4) {
          #pragma unroll
          for (int j = 0; j < 4; ++j)
            acc[o][j] += dv.h[j] * wr[kw][j];   // v_pk_fma_f16
        }
      }
    }
  }

  size_t p0 = ((((size_t)bb << 8) + (size_t)hy) << 8) + (size_t)x0;
  #pragma unroll
  for (int o = 0; o < 4; ++o) {
    bhalf* op = out + ((p0 + o) << CB) + c0;
    if (EPI == 0) {
      union { h2 h[4]; uint4 u; } sv;
      #pragma unroll
      for (int j = 0; j < 4; ++j) sv.h[j] = acc[o][j];
      *(uint4*)op = sv.u;
    } else if (EPI == 1) {
      float r[8];
      #pragma unroll
      for (int j = 0; j < 4; ++j) {
        r[2*j]   = gelu_f((float)acc[o][j][0]);
        r[2*j+1] = gelu_f((float)acc[o][j][1]);
      }
      *(uint4*)op = pack16(r);
    } else {
      uint4 mu = *(const uint4*)(m1 + ((p0 + o) << CB) + c0);
      float mf[8];
      unpack8h(mu, mf);
      float r[8];
      #pragma unroll
      for (int j = 0; j < 8; ++j) {
        float av = (float)acc[o][j >> 1][j & 1];
        float am = __builtin_amdgcn_rcpf(1.0f + __expf(-(av + db_s[c0 + j])));
        r[j] = mf[j] * (am + 1.0f);
      }
      *(uint4*)op = pack16(r);
    }
  }
}

// ---------------- depthwise conv 3x3 SAME, NHWC — 2 rows x 4 cols per thread ----------------
// Vertical reuse: 4 input rows x 6 cols = 24 loads for 8 px (3/px vs 4.5/px).
// 9 weight taps preloaded to VGPRs. Tap accumulation order per output matches
// dwconv4 (kh asc, then col asc / kw desc) -> bit-identical results.
template<int EPI, int CH>   // EPI: 0 = none, 1 = gelu
__global__ __launch_bounds__(256) void dwconv8(
    const bhalf* __restrict__ in, const float* __restrict__ wt,
    bhalf* __restrict__ out, int wstride)
{
  const int CB = (CH == 64) ? 6 : 8;    // log2(CH)
  const int G  = CH >> 3;               // channel groups (8 or 32)
  const int GB = (CH == 64) ? 3 : 5;    // log2(G)
  __shared__ u32 Wsu[9 * G * 5];        // packed half2 weights, padded stride 5
  int t = threadIdx.x;
  for (int idx = t; idx < 9 * (CH >> 1); idx += 256) {
    int tap = idx >> (CB - 1), cp = idx & ((CH >> 1) - 1);
    int cg = cp >> 2, j = cp & 3;
    h2 p;
    p[0] = (_Float16)wt[tap * wstride + 2 * cp];
    p[1] = (_Float16)wt[tap * wstride + 2 * cp + 1];
    union { h2 h; u32 u; } cv; cv.h = p;
    Wsu[tap * (G * 5) + cg * 5 + j] = cv.u;
  }
  __syncthreads();

  size_t gid = (size_t)blockIdx.x * 256 + t;
  int cg = (int)gid & (G - 1);
  int c0 = cg << 3;
  size_t p8 = gid >> GB;                // 2x4-pixel unit index
  int x0 = ((int)(p8 & 63)) << 2;       // W/4 = 64 units
  int hy = (int)((p8 >> 6) & 127) << 1; // H/2 = 128 units
  size_t bb = p8 >> 13;                 // 64*128 = 8192 units per batch

  // preload all 9 taps (36 VGPRs)
  h2 wr[3][3][4];
  #pragma unroll
  for (int kh = 0; kh < 3; ++kh)
    #pragma unroll
    for (int kw = 0; kw < 3; ++kw) {
      const u32* wp = &Wsu[(kh * 3 + kw) * (G * 5) + cg * 5];
      #pragma unroll
      for (int j = 0; j < 4; ++j) {
        union { u32 u; h2 h; } cv; cv.u = wp[j]; wr[kh][kw][j] = cv.h;
      }
    }

  h2 zero = {(_Float16)0.0f, (_Float16)0.0f};
  h2 acc[2][4][4];
  #pragma unroll
  for (int o = 0; o < 2; ++o)
    #pragma unroll
    for (int px = 0; px < 4; ++px)
      #pragma unroll
      for (int j = 0; j < 4; ++j) acc[o][px][j] = zero;

  #pragma unroll
  for (int y = 0; y < 4; ++y) {         // input rows hy-1 .. hy+2
    int ay = hy + y - 1;
    if ((unsigned)ay >= 256u) continue;
    const bhalf* rowp = in + (((((size_t)bb << 8) + (size_t)ay) << 8) << CB) + c0;
    #pragma unroll
    for (int cc = 0; cc < 6; ++cc) {
      int xw = x0 + cc - 1;
      if (cc == 0 || cc == 5) {
        if ((unsigned)xw >= 256u) continue;
      }
      union { uint4 u; h2 h[4]; } dv;
      dv.u = *(const uint4*)(rowp + ((size_t)xw << CB));
      #pragma unroll
      for (int o = 0; o < 2; ++o) {
        int kh = y - o;
        if (kh >= 0 && kh < 3) {
          #pragma unroll
          for (int kw = 0; kw < 3; ++kw) {
            int px = cc - kw;
            if (px >= 0 && px < 4) {
              #pragma unroll
              for (int j = 0; j < 4; ++j)
                acc[o][px][j] += dv.h[j] * wr[kh][kw][j];   // v_pk_fma_f16
            }
          }
        }
      }
    }
  }

  #pragma unroll
  for (int o = 0; o < 2; ++o) {
    size_t prow = (((size_t)bb << 8) + (size_t)(hy + o)) << 8;
    #pragma unroll
    for (int px = 0; px < 4; ++px) {
      bhalf* op = out + ((prow + (size_t)(x0 + px)) << CB) + c0;
      if (EPI == 0) {
        union { h2 h[4]; uint4 u; } sv;
        #pragma unroll
        for (int j = 0; j < 4; ++j) sv.h[j] = acc[o][px][j];
        *(uint4*)op = sv.u;
      } else {
        float r[8];
        #pragma unroll
        for (int j = 0; j < 4; ++j) {
          r[2*j]   = gelu_f((float)acc[o][px][j][0]);
          r[2*j+1] = gelu_f((float)acc[o][px][j][1]);
        }
        *(uint4*)op = pack16(r);
      }
    }
  }
}

// ---------------- attn softmax + fold into Wp (merged) ----------------
__global__ __launch_bounds__(256) void attn_fold(
    const float* __restrict__ S, const float* __restrict__ resc,
    const bhalf* __restrict__ wpT, bhalf* __restrict__ weffT)
{
  __shared__ float As[1024];     // [h][e][d]
  __shared__ float nqs_s[64];    // [h][d]
  int b = blockIdx.x;            // 2 blocks (batch)
  int t = threadIdx.x;
  if (t < 64) {
    int h = t >> 4, d = t & 15;
    float nqsum = 0.f;
    for (int c = 0; c < NSPLIT; ++c)
      nqsum += S[c * SCOPY + 2048 + b * 64 + h * 16 + d];
    nqs_s[t] = fmaxf(sqrtf(nqsum), 1e-6f);
  }
  __syncthreads();
  if (t < 64) {
    int h = t >> 4, d = t & 15;
    float nksum = 0.f;
    for (int c = 0; c < NSPLIT; ++c)
      nksum += S[c * SCOPY + 2176 + b * 64 + h * 16 + d];
    float nkd = fmaxf(sqrtf(nksum), 1e-6f);
    float r = resc[h];
    float4 s4[4] = {{0,0,0,0},{0,0,0,0},{0,0,0,0},{0,0,0,0}};
    for (int c = 0; c < NSPLIT; ++c) {
      const float4* sp = (const float4*)&S[c * SCOPY + (((b * 4 + h) * 16 + d) << 4)];
      #pragma unroll
      for (int j = 0; j < 4; ++j) {
        float4 u = sp[j];
        s4[j].x += u.x; s4[j].y += u.y; s4[j].z += u.z; s4[j].w += u.w;
      }
    }
    float a[16];
    #pragma unroll
    for (int j = 0; j < 4; ++j) {
      a[4*j]   = s4[j].x * r / (nkd * nqs_s[h * 16 + 4*j]);
      a[4*j+1] = s4[j].y * r / (nkd * nqs_s[h * 16 + 4*j + 1]);
      a[4*j+2] = s4[j].z * r / (nkd * nqs_s[h * 16 + 4*j + 2]);
      a[4*j+3] = s4[j].w * r / (nkd * nqs_s[h * 16 + 4*j + 3]);
    }
    float m = -1e30f;
    #pragma unroll
    for (int e = 0; e < 16; ++e) m = fmaxf(m, a[e]);
    float sum = 0.f;
    #pragma unroll
    for (int e = 0; e < 16; ++e) { a[e] = expf(a[e] - m); sum += a[e]; }
    float inv = 1.0f / sum;
    #pragma unroll
    for (int e = 0; e < 16; ++e)
      As[((h * 16 + e) << 4) + d] = a[e] * inv;
  }
  __syncthreads();
  int m = t & 63, h = t >> 6;    // each thread: one (m, h) pair -> 16 outputs
  const bhalf* wp = wpT + m * 64 + h * 16;
  float wv_[16];
  uint4 w0 = ((const uint4*)wp)[0], w1 = ((const uint4*)wp)[1];
  unpack8h(w0, wv_); unpack8h(w1, wv_ + 8);
  float r2[16];
  #pragma unroll
  for (int e = 0; e < 16; ++e) {
    const float* ar = &As[(h * 16 + e) << 4];
    float s = 0.f;
    #pragma unroll
    for (int d = 0; d < 16; ++d) s += ar[d] * wv_[d];
    r2[e] = s;
  }
  bhalf* dst = weffT + b * 4096 + m * 64 + h * 16;
  ((uint4*)dst)[0] = pack16(r2);
  ((uint4*)dst)[1] = pack16(r2 + 8);
}

// ---------------- host orchestration ----------------
extern "C" void kernel_launch(void* const* d_in, const int* in_sizes, int n_in,
                              void* d_out, int out_size, void* d_ws, size_t ws_size,
                              hipStream_t stream)
{
  (void)in_sizes; (void)n_in; (void)out_size; (void)ws_size;
  const float* x_in    = (const float*)d_in[0];
  const float* mask_in = (const float*)d_in[1];
  const float* Wq    = (const float*)d_in[2];
  const float* Wk    = (const float*)d_in[3];
  const float* Wv    = (const float*)d_in[4];
  const float* resc  = (const float*)d_in[5];
  const float* Wp    = (const float*)d_in[6];
  const float* bp    = (const float*)d_in[7];
  const float* pe1   = (const float*)d_in[8];
  const float* pe2   = (const float*)d_in[9];
  const float* mm_w1 = (const float*)d_in[10];
  const float* mm_b1 = (const float*)d_in[11];
  const float* mm_w2 = (const float*)d_in[12];
  const float* mm_b2 = (const float*)d_in[13];
  const float* mm_dw = (const float*)d_in[14];
  const float* mm_db = (const float*)d_in[15];
  const float* ln_g  = (const float*)d_in[16];
  const float* ln_b  = (const float*)d_in[17];
  const float* ff_w1 = (const float*)d_in[18];
  const float* ff_dw = (const float*)d_in[19];
  const float* ff_w2 = (const float*)d_in[20];

  const size_t NC = 8388608;  // B*N*C
  char* w = (char*)d_ws;
  float* X  = (float*)w; w += NC * 4;   // residual stream, fp32
  bhalf* Xb = (bhalf*)w; w += NC * 2;   // f16 mirror of X
  bhalf* M  = (bhalf*)w; w += NC * 2;   // mask NHWC
  bhalf* Qb = (bhalf*)w; w += NC * 2;   // (dead; spanned by F1)
  bhalf* Kb = (bhalf*)w; w += NC * 2;   // (dead; spanned by F1)
  bhalf* Vb = (bhalf*)w; w += NC * 2;
  bhalf* VG = (bhalf*)w; w += NC * 2;
  bhalf* T1 = (bhalf*)w; w += NC * 2;
  bhalf* T2 = (bhalf*)w; w += NC * 2;
  bhalf* T3 = (bhalf*)w; w += NC * 2;
  bhalf* Pb = (bhalf*)w; w += NC * 2;
  float* Sb    = (float*)w; w += (size_t)NSPLIT * SCOPY * 4;  // split accumulators
  bhalf* WeffT = (bhalf*)w; w += 8192 * 2;                    // per-batch A_bd@Wp
  bhalf* WTg   = (bhalf*)w; w += (size_t)3 * WBLK * 2;        // pre-transposed weights
  (void)Qb; (void)Kb;
  // FFN 256-ch temps alias dead 64-ch buffers.
  bhalf* F1 = Qb;   // [131072 x 256] ffn hidden (spans Qb,Kb,Vb,VG)
  bhalf* F2 = T1;   // [131072 x 256] post-dwconv (spans T1,T2,T3,Pb)

  prep_weights<<<24, 256, 0, stream>>>(mm_w1, mm_w2, Wq, Wk, Wv, Wp, ff_w1, ff_w2, WTg);
  nchw2nhwc<0><<<2048, 256, 0, stream>>>(x_in, X, Xb);
  nchw2nhwc<1><<<2048, 256, 0, stream>>>(mask_in, M, nullptr);

  for (int i = 0; i < 3; ++i) {
    const bhalf* wb = WTg + (size_t)i * WBLK;
    // mask branch: m1 (T1) + m2 (T2) fused; then MA (T3)
    gemm_mask2<<<GEMM_GRID, 256, 0, stream>>>(M, wb + 0, mm_b1 + i*64, mm_b2 + i*64, T1, T2);
    dwconv4<5, 2, 64><<<1024, 256, 0, stream>>>(T2, mm_dw + i*1600, mm_db + i*64, T1, T3, 64);
    // fused QKV + gate + in-register attention partials (128 rows/block)
    hipMemsetAsync(Sb, 0, NSPLIT * SCOPY * 4, stream);
    qkv_gemm<<<1024, 256, 0, stream>>>(Xb, wb + 8192, T3, Vb, VG, Sb);
    attn_fold<<<2, 256, 0, stream>>>(Sb, resc + i*4, wb + 20480, WeffT);
    // positional branch on ungated V (2-row dwconv8)
    dwconv8<1, 64><<<512, 256, 0, stream>>>(Vb, pe1 + i*576, T1, 64);
    dwconv8<0, 64><<<512, 256, 0, stream>>>(T1, pe2 + i*576, Pb, 64);
    // X += VG@Weff + bp + P; refresh Xb  (attn folded into weights)
    gemm64m<EP_RESID, 1><<<GEMM_GRID, 256, 0, stream>>>(VG, WeffT, bp + i*64, X, Pb, Xb);
    // FFN (full 256 hidden): fused ln+gemm1(gelu) -> dw3(gelu) -> gemm2(acc)
    ffn_gemm1_ln<<<GEMM_GRID, 256, 0, stream>>>(X, wb + 24576, ln_g + i*64, ln_b + i*64, F1);
    dwconv8<1, 256><<<2048, 256, 0, stream>>>(F1, ff_dw + i*2304, F2, 256);
    if (i < 2)
      ffn_gemm2<0><<<GEMM_GRID, 256, 0, stream>>>(F2, wb + 40960, X, Xb, nullptr);
    else
      ffn_gemm2<1><<<GEMM_GRID, 256, 0, stream>>>(F2, wb + 40960, X, Xb, (float*)d_out);
  }
}

// Round 11
// 791.122 us; speedup vs baseline: 1.2930x; 1.0072x over previous
//
#include <hip/hip_runtime.h>
#include <math.h>

// HGSA: 3x (mask-guided channel-attention MSA + LN + convFFN) on [2,64,256,256].
// External I/O fp32. Internal activations FP16, residual stream X fp32 (+f16
// mirror Xb), weights f16 in LDS.
// R5: MFMA gemms. R6: staged attn, un-chunked FFN, fused QKV. R7: attn atomic
// 32-way split. R8: weights pre-transposed W^T. R9: dwconv4. R10: fp16.
// R11: attn folded into Wp; mask m1+m2 fused; LN fused into ffn_gemm1.
// R12: attention partials fused INTO qkv_gemm; attn_softmax+fold merged.
// R14: S via in-register MFMA; 128 rows/block. R16: tanh-GELU (native
// exp/rcp); final transpose fused into ffn_gemm2. R18: dwconv8 for FFN 3x3.
// R19: (a) gemm64m EP_RESID's Xb store deleted — DEAD (ffn_gemm2 rewrites Xb
// before qkv reads it); (b) PE branch dw3->gelu->dw3 fused into pe_fused:
// conv1+gelu on the 10x18 halo tile -> LDS (OOB px = 0 == SAME zero-pad),
// conv2 from LDS; T1 intermediate round-trip eliminated (-33.6 MB/iter).

typedef unsigned short bhalf;            // fp16 bits
typedef unsigned int u32;
typedef _Float16 h2 __attribute__((ext_vector_type(2)));
typedef _Float16 f16x4 __attribute__((ext_vector_type(4)));
typedef _Float16 f16x8 __attribute__((ext_vector_type(8)));
typedef __attribute__((ext_vector_type(4))) float f32x4;

#define GEMM_GRID 2048      // 131072 rows / 64 rows per block
#define NSPLIT 32           // attn accumulator copies
#define SCOPY 2304          // floats per copy: 2048 S + 128 nq + 128 nk
#define WBLK 57344          // f16 per transformer-block weight blob

__device__ __forceinline__ float h2f(bhalf b) {
  union { bhalf u; _Float16 h; } c; c.u = b; return (float)c.h;
}
__device__ __forceinline__ bhalf f2h(float f) {
  union { _Float16 h; bhalf u; } c; c.h = (_Float16)f; return c.u;
}
__device__ __forceinline__ u32 pack2h(float a, float b) {
  auto r = __builtin_amdgcn_cvt_pkrtz(a, b);     // v_cvt_pkrtz_f16_f32, 1 op
  union { decltype(r) h; u32 u; } c; c.h = r; return c.u;
}
__device__ __forceinline__ void unpack2h(u32 p, float& a, float& b) {
  union { u32 u; h2 h; } c; c.u = p;
  a = (float)c.h[0]; b = (float)c.h[1];
}
__device__ __forceinline__ void unpack8h(uint4 u, float* f) {
  unpack2h(u.x, f[0], f[1]); unpack2h(u.y, f[2], f[3]);
  unpack2h(u.z, f[4], f[5]); unpack2h(u.w, f[6], f[7]);
}
// tanh-form GELU, branch-free, native exp/rcp. th = 1 - 2/(exp(2u)+1) is
// NaN-safe at both infinities (e=inf -> th=1; e=0 -> th=-1).
__device__ __forceinline__ float gelu_f(float v) {
  float u = v * (0.7978845608f + 0.03567740814f * v * v);
  float e = __expf(2.0f * u);
  float th = 1.0f - 2.0f * __builtin_amdgcn_rcpf(e + 1.0f);
  return 0.5f * v * (1.0f + th);
}
__device__ __forceinline__ uint4 pack16(const float* v) {  // 8 floats -> 8 f16
  uint4 s;
  s.x = pack2h(v[0], v[1]); s.y = pack2h(v[2], v[3]);
  s.z = pack2h(v[4], v[5]); s.w = pack2h(v[6], v[7]);
  return s;
}
__device__ __forceinline__ f16x4 cvt4h(f32x4 v) {    // 4 f32 -> f16x4 frag
  union { u32 u[2]; f16x4 h; } c;
  c.u[0] = pack2h(v[0], v[1]); c.u[1] = pack2h(v[2], v[3]);
  return c.h;
}

// ---------------- weight pre-transpose (once per launch, ~2us) ----------------
// For each GEMM weight W[K][N]: WTg[n*K + k] = f16(W[k][n]).
// Per block i: mm1@0, mm2@4096, Q@8192, K@12288, V@16384, P@20480,
//              ff1@24576 ([256][64]), ff2@40960 ([64][256]).
__global__ __launch_bounds__(256) void prep_weights(
    const float* __restrict__ mm_w1, const float* __restrict__ mm_w2,
    const float* __restrict__ Wq, const float* __restrict__ Wk,
    const float* __restrict__ Wv, const float* __restrict__ Wp,
    const float* __restrict__ ff_w1, const float* __restrict__ ff_w2,
    bhalf* __restrict__ out)
{
  int i = blockIdx.x >> 3, slot = blockIdx.x & 7;
  int t = threadIdx.x;
  const float* src; int ksh, N; size_t off;
  switch (slot) {
    case 0:  src = mm_w1 + i*4096;  ksh=6; N=64;  off = 0;     break;
    case 1:  src = mm_w2 + i*4096;  ksh=6; N=64;  off = 4096;  break;
    case 2:  src = Wq + i*4096;     ksh=6; N=64;  off = 8192;  break;
    case 3:  src = Wk + i*4096;     ksh=6; N=64;  off = 12288; break;
    case 4:  src = Wv + i*4096;     ksh=6; N=64;  off = 16384; break;
    case 5:  src = Wp + i*4096;     ksh=6; N=64;  off = 20480; break;
    case 6:  src = ff_w1 + i*16384; ksh=6; N=256; off = 24576; break;
    default: src = ff_w2 + i*16384; ksh=8; N=64;  off = 40960; break;
  }
  bhalf* dst = out + (size_t)i * WBLK + off;
  int sz = N << ksh;
  int kmask = (1 << ksh) - 1;
  for (int idx = t; idx < sz; idx += 256) {
    int n = idx >> ksh, k = idx & kmask;
    dst[idx] = f2h(src[k * N + n]);
  }
}

// ---------------- transposes ----------------
template<int MODE>   // 0: x -> fp32 X AND f16 Xb.  1: mask -> f16 only.
__global__ __launch_bounds__(256) void nchw2nhwc(const float* __restrict__ in,
                                                 void* __restrict__ out,
                                                 bhalf* __restrict__ out2) {
  __shared__ float tile[64][65];
  int t = threadIdx.x;
  int b = blockIdx.x >> 10;
  int n0 = (blockIdx.x & 1023) << 6;
  #pragma unroll
  for (int j = 0; j < 16; ++j) {
    int idx = j * 256 + t;
    int c = idx >> 6, nn = idx & 63;
    tile[c][nn] = in[(((size_t)(b * 64 + c)) << 16) + n0 + nn];
  }
  __syncthreads();
  #pragma unroll
  for (int j = 0; j < 16; ++j) {
    int idx = j * 256 + t;
    int nn = idx >> 6, c = idx & 63;
    size_t o = ((((size_t)b << 16) + n0 + nn) << 6) + c;
    float v = tile[c][nn];
    if (MODE == 0) { ((float*)out)[o] = v; out2[o] = f2h(v); }
    else           { ((bhalf*)out)[o] = f2h(v); }
  }
}

// ---------------- fused mask GEMMs: m1 = M@W1+b1 ; m2 = m1@W2+b2 ----------------
__global__ __launch_bounds__(256) void gemm_mask2(
    const bhalf* __restrict__ M, const bhalf* __restrict__ wt,  // W1T@0, W2T@4096
    const float* __restrict__ b1, const float* __restrict__ b2,
    bhalf* __restrict__ T1o, bhalf* __restrict__ T2o)
{
  __shared__ __align__(16) char smem[9216 * 2 + 17408];
  bhalf* WT1 = (bhalf*)smem;               // [64][72]
  bhalf* WT2 = (bhalf*)(smem + 9216);      // [64][72]
  float* Cs  = (float*)(smem + 18432);     // [64][68] transpose buffer
  bhalf* Ab  = (bhalf*)(smem + 18432);     // [64][72] f16 A relayout (aliases Cs)
  __shared__ float b1s[64], b2s[64];
  int t = threadIdx.x;
  {
    const uint4* ws = (const uint4*)wt;    // 1024 uint4: W1 then W2
    #pragma unroll
    for (int i = 0; i < 4; ++i) {
      int idx4 = i * 256 + t;
      int n = (idx4 >> 3) & 63, q4 = idx4 & 7;
      uint4* wd = (idx4 < 512) ? (uint4*)WT1 : (uint4*)WT2;
      wd[n * 9 + q4] = ws[idx4];
    }
    if (t < 64) { b1s[t] = b1[t]; b2s[t] = b2[t]; }
  }
  __syncthreads();

  int wv = t >> 6, lane = t & 63;
  int lm = lane & 15, q = lane >> 4;
  size_t row0 = ((size_t)blockIdx.x << 6) + (wv << 4);
  int rr = t >> 2, c0 = (t & 3) << 4;
  size_t grow = ((size_t)blockIdx.x << 6) + rr;

  // pass 1: m1 = M @ W1
  const bhalf* arow = M + ((row0 + lm) << 6) + (q << 3);
  f16x8 a0 = *(const f16x8*)(arow);
  f16x8 a1 = *(const f16x8*)(arow + 32);
  f32x4 acc[4];
  #pragma unroll
  for (int nt = 0; nt < 4; ++nt) {
    const bhalf* bp_ = &WT1[(nt * 16 + lm) * 72 + (q << 3)];
    f16x8 bv0 = *(const f16x8*)(bp_);
    f16x8 bv1 = *(const f16x8*)(bp_ + 32);
    f32x4 c = {0.f, 0.f, 0.f, 0.f};
    c = __builtin_amdgcn_mfma_f32_16x16x32_f16(a0, bv0, c, 0, 0, 0);
    c = __builtin_amdgcn_mfma_f32_16x16x32_f16(a1, bv1, c, 0, 0, 0);
    acc[nt] = c;
  }
  #pragma unroll
  for (int nt = 0; nt < 4; ++nt)
    #pragma unroll
    for (int r = 0; r < 4; ++r)
      Cs[((wv << 4) + (q << 2) + r) * 68 + (nt << 4) + lm] = acc[nt][r];
  __syncthreads();
  float v[16];
  #pragma unroll
  for (int j = 0; j < 4; ++j) {
    float4 u = *(const float4*)&Cs[rr * 68 + c0 + 4 * j];
    v[4*j] = u.x; v[4*j+1] = u.y; v[4*j+2] = u.z; v[4*j+3] = u.w;
  }
  #pragma unroll
  for (int j = 0; j < 16; ++j) v[j] += b1s[c0 + j];
  uint4 p0 = pack16(v), p1 = pack16(v + 8);
  bhalf* ob1 = T1o + (grow << 6) + c0;
  ((uint4*)ob1)[0] = p0; ((uint4*)ob1)[1] = p1;
  __syncthreads();                       // all Cs reads done before Ab overwrite
  *(uint4*)&Ab[rr * 72 + c0]     = p0;   // 144B row stride: 16B-aligned
  *(uint4*)&Ab[rr * 72 + c0 + 8] = p1;
  __syncthreads();

  // pass 2: m2 = m1(f16) @ W2
  const bhalf* ar2 = &Ab[((wv << 4) + lm) * 72 + (q << 3)];
  f16x8 c0v = *(const f16x8*)(ar2);
  f16x8 c1v = *(const f16x8*)(ar2 + 32);
  #pragma unroll
  for (int nt = 0; nt < 4; ++nt) {
    const bhalf* bp_ = &WT2[(nt * 16 + lm) * 72 + (q << 3)];
    f16x8 bv0 = *(const f16x8*)(bp_);
    f16x8 bv1 = *(const f16x8*)(bp_ + 32);
    f32x4 c = {0.f, 0.f, 0.f, 0.f};
    c = __builtin_amdgcn_mfma_f32_16x16x32_f16(c0v, bv0, c, 0, 0, 0);
    c = __builtin_amdgcn_mfma_f32_16x16x32_f16(c1v, bv1, c, 0, 0, 0);
    acc[nt] = c;
  }
  __syncthreads();                       // Ab reads done before Cs overwrite
  #pragma unroll
  for (int nt = 0; nt < 4; ++nt)
    #pragma unroll
    for (int r = 0; r < 4; ++r)
      Cs[((wv << 4) + (q << 2) + r) * 68 + (nt << 4) + lm] = acc[nt][r];
  __syncthreads();
  #pragma unroll
  for (int j = 0; j < 4; ++j) {
    float4 u = *(const float4*)&Cs[rr * 68 + c0 + 4 * j];
    v[4*j] = u.x; v[4*j+1] = u.y; v[4*j+2] = u.z; v[4*j+3] = u.w;
  }
  #pragma unroll
  for (int j = 0; j < 16; ++j) v[j] += b2s[c0 + j];
  bhalf* ob2 = T2o + (grow << 6) + c0;
  ((uint4*)ob2)[0] = pack16(v);
  ((uint4*)ob2)[1] = pack16(v + 8);
}

// ---------------- MFMA GEMM 64x64, residual epilogue ----------------
// BW=1: weight blob is per-batch (4096 f16 each), selected by blockIdx>>10.
#define EP_BIAS 1
#define EP_RESID 5  // fp32 out_(X) += result + bias + aux(P f16)

template<int EP, int BW>
__global__ __launch_bounds__(256) void gemm64m(
    const bhalf* __restrict__ in_, const bhalf* __restrict__ wt,
    const float* __restrict__ bias, void* __restrict__ out_,
    const bhalf* __restrict__ aux)
{
  __shared__ __align__(16) char smem[64 * 68 * 4];  // WT (9.2KB) then Cs (17.4KB)
  bhalf* WT = (bhalf*)smem;         // W^T, [n][k] stride 72
  float* Cs = (float*)smem;         // epilogue transpose buffer, stride 68
  __shared__ float bias_s[64];
  int t = threadIdx.x;
  if (BW) wt += (size_t)(blockIdx.x >> 10) << 12;
  {
    const uint4* ws = (const uint4*)wt;
    uint4* wd = (uint4*)WT;
    #pragma unroll
    for (int i = 0; i < 2; ++i) {
      int idx4 = i * 256 + t;               // 512 uint4 total; row = 8 uint4
      int n = idx4 >> 3, q4 = idx4 & 7;
      wd[n * 9 + q4] = ws[idx4];            // LDS row stride 72 f16 = 9 uint4
    }
    if (t < 64) bias_s[t] = bias[t];
  }
  __syncthreads();

  int wv = t >> 6, lane = t & 63;
  int lm = lane & 15, q = lane >> 4;
  size_t row0 = ((size_t)blockIdx.x << 6) + (wv << 4);

  const bhalf* arow = in_ + ((row0 + lm) << 6) + (q << 3);
  f16x8 a0 = *(const f16x8*)(arow);
  f16x8 a1 = *(const f16x8*)(arow + 32);

  f32x4 acc[4];
  #pragma unroll
  for (int nt = 0; nt < 4; ++nt) {
    const bhalf* bp_ = &WT[(nt * 16 + lm) * 72 + (q << 3)];
    f16x8 b0 = *(const f16x8*)(bp_);
    f16x8 b1 = *(const f16x8*)(bp_ + 32);
    f32x4 c = {0.f, 0.f, 0.f, 0.f};
    c = __builtin_amdgcn_mfma_f32_16x16x32_f16(a0, b0, c, 0, 0, 0);
    c = __builtin_amdgcn_mfma_f32_16x16x32_f16(a1, b1, c, 0, 0, 0);
    acc[nt] = c;
  }
  __syncthreads();   // all waves done with WT before Cs overwrites it
  #pragma unroll
  for (int nt = 0; nt < 4; ++nt)
    #pragma unroll
    for (int r = 0; r < 4; ++r)
      Cs[((wv << 4) + (q << 2) + r) * 68 + (nt << 4) + lm] = acc[nt][r];
  __syncthreads();

  int rr = t >> 2, c0 = (t & 3) << 4;
  size_t grow = ((size_t)blockIdx.x << 6) + rr;
  float v[16];
  #pragma unroll
  for (int j = 0; j < 4; ++j) {
    float4 u = *(const float4*)&Cs[rr * 68 + c0 + 4 * j];
    v[4*j] = u.x; v[4*j+1] = u.y; v[4*j+2] = u.z; v[4*j+3] = u.w;
  }

  if (EP == EP_RESID) {
    float* xr = (float*)out_ + (grow << 6) + c0;
    const bhalf* pr = aux + (grow << 6) + c0;
    uint4 p0 = ((const uint4*)pr)[0], p1 = ((const uint4*)pr)[1];
    float pf[16];
    unpack8h(p0, pf); unpack8h(p1, pf + 8);
    // NOTE: Xb refresh here was DEAD (ffn_gemm2 rewrites Xb before next read).
    #pragma unroll
    for (int j = 0; j < 4; ++j) {
      float4* x4 = (float4*)(xr + 4 * j);
      float4 u = *x4;
      u.x += v[4*j]   + bias_s[c0 + 4*j]     + pf[4*j];
      u.y += v[4*j+1] + bias_s[c0 + 4*j + 1] + pf[4*j+1];
      u.z += v[4*j+2] + bias_s[c0 + 4*j + 2] + pf[4*j+2];
      u.w += v[4*j+3] + bias_s[c0 + 4*j + 3] + pf[4*j+3];
      *x4 = u;
    }
  } else {  // EP_BIAS
    #pragma unroll
    for (int j = 0; j < 16; ++j) v[j] += bias_s[c0 + j];
    bhalf* ob = (bhalf*)out_ + (grow << 6) + c0;
    ((uint4*)ob)[0] = pack16(v);
    ((uint4*)ob)[1] = pack16(v + 8);
  }
}

// ---------------- fused QKV + in-register channel-attention partials ----------------
// 1024 blocks x 128 rows (2 groups of 64). wt rows 0-63=Q, 64-127=K, 128-191=V.
__global__ __launch_bounds__(256) void qkv_gemm(
    const bhalf* __restrict__ xb, const bhalf* __restrict__ wt,
    const bhalf* __restrict__ ma, bhalf* __restrict__ Vb,
    bhalf* __restrict__ VG, float* __restrict__ S)
{
  __shared__ __align__(16) char smem[27648];   // WT 192x72 f16
  bhalf* WT = (bhalf*)smem;
  float* Cs = (float*)smem;                    // [64][68] f32 (17408B), post-mfma
  float* Sred = (float*)smem;                  // [4][1024] f32 (16384B), post-Cs
  float* qred = (float*)(smem + 16384);        // [4][64]
  float* kred = (float*)(smem + 17408);        // [4][64] (ends 18432 < 27648)
  int t = threadIdx.x;
  {
    const uint4* ws = (const uint4*)wt;
    uint4* wd = (uint4*)WT;
    #pragma unroll
    for (int i = 0; i < 6; ++i) {
      int idx4 = i * 256 + t;               // 1536 uint4
      int n = idx4 >> 3, q4 = idx4 & 7;
      wd[n * 9 + q4] = ws[idx4];
    }
  }
  __syncthreads();

  int wv_ = t >> 6, lane = t & 63;
  int lm = lane & 15, q = lane >> 4;
  int rr = t >> 2, c0 = (t & 3) << 4;

  f32x4 accS[4];
  f32x4 accV[2][4];
  float qss[4] = {0.f, 0.f, 0.f, 0.f};
  float kss[4] = {0.f, 0.f, 0.f, 0.f};
  #pragma unroll
  for (int h = 0; h < 4; ++h) accS[h] = (f32x4){0.f, 0.f, 0.f, 0.f};

  #pragma unroll
  for (int grp = 0; grp < 2; ++grp) {
    size_t row0 = ((size_t)blockIdx.x << 7) + (grp << 6) + (wv_ << 4);
    const bhalf* arow = xb + ((row0 + lm) << 6) + (q << 3);
    f16x8 a0 = *(const f16x8*)(arow);
    f16x8 a1 = *(const f16x8*)(arow + 32);
    f32x4 accQ[4], accK[4];
    #pragma unroll
    for (int nt = 0; nt < 4; ++nt) {
      const bhalf* bp_ = &WT[(nt * 16 + lm) * 72 + (q << 3)];
      f32x4 c = {0.f, 0.f, 0.f, 0.f};
      c = __builtin_amdgcn_mfma_f32_16x16x32_f16(a0, *(const f16x8*)(bp_), c, 0, 0, 0);
      c = __builtin_amdgcn_mfma_f32_16x16x32_f16(a1, *(const f16x8*)(bp_ + 32), c, 0, 0, 0);
      accQ[nt] = c;
    }
    #pragma unroll
    for (int nt = 0; nt < 4; ++nt) {
      const bhalf* bp_ = &WT[((64 + nt * 16) + lm) * 72 + (q << 3)];
      f32x4 c = {0.f, 0.f, 0.f, 0.f};
      c = __builtin_amdgcn_mfma_f32_16x16x32_f16(a0, *(const f16x8*)(bp_), c, 0, 0, 0);
      c = __builtin_amdgcn_mfma_f32_16x16x32_f16(a1, *(const f16x8*)(bp_ + 32), c, 0, 0, 0);
      accK[nt] = c;
    }
    #pragma unroll
    for (int nt = 0; nt < 4; ++nt) {
      const bhalf* bp_ = &WT[((128 + nt * 16) + lm) * 72 + (q << 3)];
      f32x4 c = {0.f, 0.f, 0.f, 0.f};
      c = __builtin_amdgcn_mfma_f32_16x16x32_f16(a0, *(const f16x8*)(bp_), c, 0, 0, 0);
      c = __builtin_amdgcn_mfma_f32_16x16x32_f16(a1, *(const f16x8*)(bp_ + 32), c, 0, 0, 0);
      accV[grp][nt] = c;
    }
    // S16[h] += K^T Q over this group's rows (in-register MFMA, k=16 rows)
    #pragma unroll
    for (int h = 0; h < 4; ++h) {
      f16x4 kf = cvt4h(accK[h]);
      f16x4 qf = cvt4h(accQ[h]);
      accS[h] = __builtin_amdgcn_mfma_f32_16x16x16f16(kf, qf, accS[h], 0, 0, 0);
      #pragma unroll
      for (int r = 0; r < 4; ++r) {
        qss[h] += accQ[h][r] * accQ[h][r];
        kss[h] += accK[h][r] * accK[h][r];
      }
    }
  }

  // ---- V epilogues (WT dead; Cs aliases it) ----
  #pragma unroll
  for (int grp = 0; grp < 2; ++grp) {
    __syncthreads();
    #pragma unroll
    for (int nt = 0; nt < 4; ++nt)
      #pragma unroll
      for (int r = 0; r < 4; ++r)
        Cs[((wv_ << 4) + (q << 2) + r) * 68 + (nt << 4) + lm] = accV[grp][nt][r];
    __syncthreads();
    float v[16];
    #pragma unroll
    for (int j = 0; j < 4; ++j) {
      float4 u = *(const float4*)&Cs[rr * 68 + c0 + 4 * j];
      v[4*j] = u.x; v[4*j+1] = u.y; v[4*j+2] = u.z; v[4*j+3] = u.w;
    }
    size_t grow = ((size_t)blockIdx.x << 7) + (grp << 6) + rr;
    bhalf* ob = Vb + (grow << 6) + c0;
    ((uint4*)ob)[0] = pack16(v);
    ((uint4*)ob)[1] = pack16(v + 8);
    const bhalf* mr = ma + (grow << 6) + c0;
    uint4 m0 = ((const uint4*)mr)[0], m1q = ((const uint4*)mr)[1];
    float mf[16];
    unpack8h(m0, mf); unpack8h(m1q, mf + 8);
    float gv[16];
    #pragma unroll
    for (int j = 0; j < 16; ++j) gv[j] = v[j] * mf[j];
    bhalf* gb = VG + (grow << 6) + c0;
    ((uint4*)gb)[0] = pack16(gv);
    ((uint4*)gb)[1] = pack16(gv + 8);
  }
  __syncthreads();   // last Cs reads done; Sred/qred/kred may write

  // ---- cross-wave reduce + atomics ----
  // accS[h] lane (lm,q) reg r = S[h][d = q*4+r][e = lm]
  #pragma unroll
  for (int h = 0; h < 4; ++h)
    #pragma unroll
    for (int r = 0; r < 4; ++r)
      Sred[(wv_ << 10) + (h << 8) + ((q << 2) + r) * 16 + lm] = accS[h][r];
  #pragma unroll
  for (int nt = 0; nt < 4; ++nt) {
    qss[nt] += __shfl_xor(qss[nt], 16); qss[nt] += __shfl_xor(qss[nt], 32);
    kss[nt] += __shfl_xor(kss[nt], 16); kss[nt] += __shfl_xor(kss[nt], 32);
  }
  if (q == 0) {
    #pragma unroll
    for (int nt = 0; nt < 4; ++nt) {
      qred[(wv_ << 6) + (nt << 4) + lm] = qss[nt];
      kred[(wv_ << 6) + (nt << 4) + lm] = kss[nt];
    }
  }
  __syncthreads();

  int b = (int)(blockIdx.x >> 9);
  float* Sc = S + (size_t)(blockIdx.x & (NSPLIT - 1)) * SCOPY;
  {
    int ci = t << 2;
    float4 s = {0.f, 0.f, 0.f, 0.f};
    #pragma unroll
    for (int wv2 = 0; wv2 < 4; ++wv2) {
      float4 u = *(const float4*)&Sred[(wv2 << 10) + ci];
      s.x += u.x; s.y += u.y; s.z += u.z; s.w += u.w;
    }
    float* sp = Sc + b * 1024 + ci;
    atomicAdd(sp + 0, s.x); atomicAdd(sp + 1, s.y);
    atomicAdd(sp + 2, s.z); atomicAdd(sp + 3, s.w);
  }
  if (t < 64) {
    float qs = qred[t] + qred[64 + t] + qred[128 + t] + qred[192 + t];
    float ks = kred[t] + kred[64 + t] + kred[128 + t] + kred[192 + t];
    atomicAdd(Sc + 2048 + b * 64 + t, qs);
    atomicAdd(Sc + 2176 + b * 64 + t, ks);
  }
}

// ---------------- FFN gemm1 + fused LayerNorm: ln(X) @ [64x256], GELU ----------------
__global__ __launch_bounds__(256) void ffn_gemm1_ln(
    const float* __restrict__ X, const bhalf* __restrict__ wt,
    const float* __restrict__ g, const float* __restrict__ bb,
    bhalf* __restrict__ out_)
{
  __shared__ __align__(16) char smem[256 * 72 * 2];  // WT 36.9KB; Cs aliased
  bhalf* WT = (bhalf*)smem;
  float* Cs = (float*)smem;
  __shared__ float gs[64], bs[64];
  int t = threadIdx.x;
  {
    const uint4* ws = (const uint4*)wt;
    uint4* wd = (uint4*)WT;
    #pragma unroll
    for (int i = 0; i < 8; ++i) {
      int idx4 = i * 256 + t;               // 2048 uint4
      int n = idx4 >> 3, q4 = idx4 & 7;
      wd[n * 9 + q4] = ws[idx4];
    }
    if (t < 64) { gs[t] = g[t]; bs[t] = bb[t]; }
  }
  __syncthreads();

  int wv_ = t >> 6, lane = t & 63;
  int lm = lane & 15, q = lane >> 4;
  size_t row0 = ((size_t)blockIdx.x << 6) + (wv_ << 4);
  // A-fragment rows from fp32 X, with in-register LayerNorm.
  const float* xr = X + ((row0 + lm) << 6);
  int k0 = q << 3;
  float xa[8], xb2[8];
  {
    float4 u0 = *(const float4*)(xr + k0);
    float4 u1 = *(const float4*)(xr + k0 + 4);
    float4 u2 = *(const float4*)(xr + 32 + k0);
    float4 u3 = *(const float4*)(xr + 32 + k0 + 4);
    xa[0]=u0.x; xa[1]=u0.y; xa[2]=u0.z; xa[3]=u0.w;
    xa[4]=u1.x; xa[5]=u1.y; xa[6]=u1.z; xa[7]=u1.w;
    xb2[0]=u2.x; xb2[1]=u2.y; xb2[2]=u2.z; xb2[3]=u2.w;
    xb2[4]=u3.x; xb2[5]=u3.y; xb2[6]=u3.z; xb2[7]=u3.w;
  }
  float s1 = 0.f, s2 = 0.f;
  #pragma unroll
  for (int j = 0; j < 8; ++j) {
    s1 += xa[j] + xb2[j];
    s2 += xa[j] * xa[j] + xb2[j] * xb2[j];
  }
  s1 += __shfl_xor(s1, 16); s1 += __shfl_xor(s1, 32);
  s2 += __shfl_xor(s2, 16); s2 += __shfl_xor(s2, 32);
  float mu = s1 * 0.015625f;
  float var = s2 * 0.015625f - mu * mu;
  float rstd = rsqrtf(var + 1e-5f);
  f16x8 a0, a1;
  #pragma unroll
  for (int j = 0; j < 8; ++j) {
    a0[j] = (_Float16)((xa[j]  - mu) * rstd * gs[k0 + j]      + bs[k0 + j]);
    a1[j] = (_Float16)((xb2[j] - mu) * rstd * gs[32 + k0 + j] + bs[32 + k0 + j]);
  }

  f32x4 acc[16];
  #pragma unroll
  for (int nt = 0; nt < 16; ++nt) {
    const bhalf* bp_ = &WT[(nt * 16 + lm) * 72 + (q << 3)];
    f16x8 b0 = *(const f16x8*)(bp_);
    f16x8 b1 = *(const f16x8*)(bp_ + 32);
    f32x4 c = {0.f, 0.f, 0.f, 0.f};
    c = __builtin_amdgcn_mfma_f32_16x16x32_f16(a0, b0, c, 0, 0, 0);
    c = __builtin_amdgcn_mfma_f32_16x16x32_f16(a1, b1, c, 0, 0, 0);
    acc[nt] = c;
  }

  int rr = t >> 2, c0 = (t & 3) << 4;
  size_t grow = ((size_t)blockIdx.x << 6) + rr;
  #pragma unroll
  for (int gi = 0; gi < 4; ++gi) {
    __syncthreads();
    #pragma unroll
    for (int nt = 0; nt < 4; ++nt)
      #pragma unroll
      for (int r = 0; r < 4; ++r)
        Cs[((wv_ << 4) + (q << 2) + r) * 68 + (nt << 4) + lm] = acc[gi * 4 + nt][r];
    __syncthreads();
    float v[16];
    #pragma unroll
    for (int j = 0; j < 4; ++j) {
      float4 u = *(const float4*)&Cs[rr * 68 + c0 + 4 * j];
      v[4*j]   = gelu_f(u.x); v[4*j+1] = gelu_f(u.y);
      v[4*j+2] = gelu_f(u.z); v[4*j+3] = gelu_f(u.w);
    }
    bhalf* ob = out_ + (grow << 8) + (gi << 6) + c0;
    ((uint4*)ob)[0] = pack16(v);
    ((uint4*)ob)[1] = pack16(v + 8);
  }
}

// ---------------- FFN gemm2: [131072x256] @ [256x64], X += ----------------
// FINAL=0: writes X (fp32) and Xb (f16). FINAL=1 (last transformer block):
// writes d_out NCHW directly via an LDS re-transpose (Cs reuse) — X/Xb dead.
template<int FINAL>
__global__ __launch_bounds__(256) void ffn_gemm2(
    const bhalf* __restrict__ in_, const bhalf* __restrict__ wt,
    float* __restrict__ X, bhalf* __restrict__ Xb, float* __restrict__ out)
{
  __shared__ __align__(16) char smem[64 * 264 * 2];  // WT 33.8KB; Cs aliased
  bhalf* WT = (bhalf*)smem;
  float* Cs = (float*)smem;
  int t = threadIdx.x;
  {
    const uint4* ws = (const uint4*)wt;
    uint4* wd = (uint4*)WT;
    #pragma unroll
    for (int i = 0; i < 8; ++i) {
      int idx4 = i * 256 + t;               // 2048 uint4; row = 32 uint4
      int n = idx4 >> 5, q4 = idx4 & 31;
      wd[n * 33 + q4] = ws[idx4];           // LDS row stride 264 f16 = 33 uint4
    }
  }
  __syncthreads();

  int wv_ = t >> 6, lane = t & 63;
  int lm = lane & 15, q = lane >> 4;
  size_t row0 = ((size_t)blockIdx.x << 6) + (wv_ << 4);
  const bhalf* arow = in_ + ((row0 + lm) << 8) + (q << 3);
  f16x8 a[8];
  #pragma unroll
  for (int ch = 0; ch < 8; ++ch) a[ch] = *(const f16x8*)(arow + 32 * ch);

  f32x4 acc[4];
  #pragma unroll
  for (int nt = 0; nt < 4; ++nt) {
    const bhalf* bp_ = &WT[(nt * 16 + lm) * 264 + (q << 3)];
    f32x4 c = {0.f, 0.f, 0.f, 0.f};
    #pragma unroll
    for (int ch = 0; ch < 8; ++ch) {
      f16x8 b = *(const f16x8*)(bp_ + 32 * ch);
      c = __builtin_amdgcn_mfma_f32_16x16x32_f16(a[ch], b, c, 0, 0, 0);
    }
    acc[nt] = c;
  }
  __syncthreads();
  #pragma unroll
  for (int nt = 0; nt < 4; ++nt)
    #pragma unroll
    for (int r = 0; r < 4; ++r)
      Cs[((wv_ << 4) + (q << 2) + r) * 68 + (nt << 4) + lm] = acc[nt][r];
  __syncthreads();

  int rr = t >> 2, c0 = (t & 3) << 4;
  size_t grow = ((size_t)blockIdx.x << 6) + rr;
  float v[16];
  #pragma unroll
  for (int j = 0; j < 4; ++j) {
    float4 u = *(const float4*)&Cs[rr * 68 + c0 + 4 * j];
    v[4*j] = u.x; v[4*j+1] = u.y; v[4*j+2] = u.z; v[4*j+3] = u.w;
  }
  float* xr = X + (grow << 6) + c0;
  #pragma unroll
  for (int j = 0; j < 4; ++j) {
    float4* x4 = (float4*)(xr + 4 * j);
    float4 u = *x4;
    u.x += v[4*j]; u.y += v[4*j+1]; u.z += v[4*j+2]; u.w += v[4*j+3];
    if (FINAL == 0) *x4 = u;
    v[4*j] = u.x; v[4*j+1] = u.y; v[4*j+2] = u.z; v[4*j+3] = u.w;
  }
  if (FINAL == 0) {
    bhalf* xb = Xb + (grow << 6) + c0;
    ((uint4*)xb)[0] = pack16(v);
    ((uint4*)xb)[1] = pack16(v + 8);
  } else {
    // re-transpose through Cs and write NCHW d_out directly
    __syncthreads();
    #pragma unroll
    for (int j = 0; j < 16; ++j)
      Cs[(c0 + j) * 68 + rr] = v[j];
    __syncthreads();
    int bb2 = (int)(blockIdx.x >> 10);
    int n0 = ((int)blockIdx.x & 1023) << 6;
    #pragma unroll
    for (int j = 0; j < 16; ++j) {
      int idx = j * 256 + t;
      int c = idx >> 6, nn = idx & 63;
      out[(((size_t)(bb2 * 64 + c)) << 16) + n0 + nn] = Cs[c * 68 + nn];
    }
  }
}

// ---------------- depthwise conv 5x5 SAME, NHWC — 4 x-pixels per thread ----------------
template<int KS, int EPI, int CH>
__global__ __launch_bounds__(256) void dwconv4(
    const bhalf* __restrict__ in, const float* __restrict__ wt,
    const float* __restrict__ db, const bhalf* __restrict__ m1,
    bhalf* __restrict__ out, int wstride)
{
  const int CB = (CH == 64) ? 6 : 8;    // log2(CH)
  const int G  = CH >> 3;               // channel groups per pixel (8 or 32)
  const int GB = (CH == 64) ? 3 : 5;    // log2(G)
  const int R  = KS >> 1;
  const int NCOL = KS + 3;              // window columns for 4 outputs
  __shared__ u32 Wsu[KS * KS * G * 5];  // packed half2 weights, padded stride 5
  __shared__ float db_s[64];
  int t = threadIdx.x;
  for (int idx = t; idx < KS * KS * (CH >> 1); idx += 256) {
    int tap = idx >> (CB - 1), cp = idx & ((CH >> 1) - 1);
    int cg = cp >> 2, j = cp & 3;
    h2 p;
    p[0] = (_Float16)wt[tap * wstride + 2 * cp];
    p[1] = (_Float16)wt[tap * wstride + 2 * cp + 1];
    union { h2 h; u32 u; } cv; cv.h = p;
    Wsu[tap * (G * 5) + cg * 5 + j] = cv.u;
  }
  if (EPI == 2 && t < 64) db_s[t] = db[t];
  __syncthreads();

  size_t gid = (size_t)blockIdx.x * 256 + t;
  int cg = (int)gid & (G - 1);
  int c0 = cg << 3;
  size_t p4 = gid >> GB;                // 4-pixel unit index
  int x0 = ((int)(p4 & 63)) << 2;
  int hy = (int)((p4 >> 6) & 255);
  size_t bb = p4 >> 14;                 // 64*256 = 16384 units per batch

  h2 zero = {(_Float16)0.0f, (_Float16)0.0f};
  h2 acc[4][4];
  #pragma unroll
  for (int o = 0; o < 4; ++o)
    #pragma unroll
    for (int j = 0; j < 4; ++j) acc[o][j] = zero;

  #pragma unroll
  for (int kh = 0; kh < KS; ++kh) {
    int y = hy + kh - R;
    if ((unsigned)y >= 256u) continue;
    h2 wr[KS][4];
    #pragma unroll
    for (int kw = 0; kw < KS; ++kw) {
      const u32* wp = &Wsu[(kh * KS + kw) * (G * 5) + cg * 5];
      #pragma unroll
      for (int j = 0; j < 4; ++j) {
        union { u32 u; h2 h; } cv; cv.u = wp[j]; wr[kw][j] = cv.h;
      }
    }
    const bhalf* rowp = in + (((((size_t)bb << 8) + (size_t)y) << 8) << CB) + c0;
    #pragma unroll
    for (int cc = 0; cc < NCOL; ++cc) {
      int xw = x0 + cc - R;
      // only edge columns can be OOB: interior columns fold the test away
      if (cc < R || cc >= NCOL - R) {
        if ((unsigned)xw >= 256u) continue;
      }
      union { uint4 u; h2 h[4]; } dv;
      dv.u = *(const uint4*)(rowp + ((size_t)xw << CB));
      #pragma unroll
      for (int kw = 0; kw < KS; ++kw) {
        int o = cc - kw;
        if (o >= 0 && o < 4) {
          #pragma unroll
          for (int j = 0; j < 4; ++j)
            acc[o][j] += dv.h[j] * wr[kw][j];   // v_pk_fma_f16
        }
      }
    }
  }

  size_t p0 = ((((size_t)bb << 8) + (size_t)hy) << 8) + (size_t)x0;
  #pragma unroll
  for (int o = 0; o < 4; ++o) {
    bhalf* op = out + ((p0 + o) << CB) + c0;
    if (EPI == 0) {
      union { h2 h[4]; uint4 u; } sv;
      #pragma unroll
      for (int j = 0; j < 4; ++j) sv.h[j] = acc[o][j];
      *(uint4*)op = sv.u;
    } else if (EPI == 1) {
      float r[8];
      #pragma unroll
      for (int j = 0; j < 4; ++j) {
        r[2*j]   = gelu_f((float)acc[o][j][0]);
        r[2*j+1] = gelu_f((float)acc[o][j][1]);
      }
      *(uint4*)op = pack16(r);
    } else {
      uint4 mu = *(const uint4*)(m1 + ((p0 + o) << CB) + c0);
      float mf[8];
      unpack8h(mu, mf);
      float r[8];
      #pragma unroll
      for (int j = 0; j < 8; ++j) {
        float av = (float)acc[o][j >> 1][j & 1];
        float am = __builtin_amdgcn_rcpf(1.0f + __expf(-(av + db_s[c0 + j])));
        r[j] = mf[j] * (am + 1.0f);
      }
      *(uint4*)op = pack16(r);
    }
  }
}

// ---------------- depthwise conv 3x3 SAME, NHWC — 2 rows x 4 cols per thread ----------------
template<int EPI, int CH>   // EPI: 0 = none, 1 = gelu
__global__ __launch_bounds__(256) void dwconv8(
    const bhalf* __restrict__ in, const float* __restrict__ wt,
    bhalf* __restrict__ out, int wstride)
{
  const int CB = (CH == 64) ? 6 : 8;    // log2(CH)
  const int G  = CH >> 3;               // channel groups (8 or 32)
  const int GB = (CH == 64) ? 3 : 5;    // log2(G)
  __shared__ u32 Wsu[9 * G * 5];        // packed half2 weights, padded stride 5
  int t = threadIdx.x;
  for (int idx = t; idx < 9 * (CH >> 1); idx += 256) {
    int tap = idx >> (CB - 1), cp = idx & ((CH >> 1) - 1);
    int cg = cp >> 2, j = cp & 3;
    h2 p;
    p[0] = (_Float16)wt[tap * wstride + 2 * cp];
    p[1] = (_Float16)wt[tap * wstride + 2 * cp + 1];
    union { h2 h; u32 u; } cv; cv.h = p;
    Wsu[tap * (G * 5) + cg * 5 + j] = cv.u;
  }
  __syncthreads();

  size_t gid = (size_t)blockIdx.x * 256 + t;
  int cg = (int)gid & (G - 1);
  int c0 = cg << 3;
  size_t p8 = gid >> GB;                // 2x4-pixel unit index
  int x0 = ((int)(p8 & 63)) << 2;       // W/4 = 64 units
  int hy = (int)((p8 >> 6) & 127) << 1; // H/2 = 128 units
  size_t bb = p8 >> 13;                 // 64*128 = 8192 units per batch

  // preload all 9 taps (36 VGPRs)
  h2 wr[3][3][4];
  #pragma unroll
  for (int kh = 0; kh < 3; ++kh)
    #pragma unroll
    for (int kw = 0; kw < 3; ++kw) {
      const u32* wp = &Wsu[(kh * 3 + kw) * (G * 5) + cg * 5];
      #pragma unroll
      for (int j = 0; j < 4; ++j) {
        union { u32 u; h2 h; } cv; cv.u = wp[j]; wr[kh][kw][j] = cv.h;
      }
    }

  h2 zero = {(_Float16)0.0f, (_Float16)0.0f};
  h2 acc[2][4][4];
  #pragma unroll
  for (int o = 0; o < 2; ++o)
    #pragma unroll
    for (int px = 0; px < 4; ++px)
      #pragma unroll
      for (int j = 0; j < 4; ++j) acc[o][px][j] = zero;

  #pragma unroll
  for (int y = 0; y < 4; ++y) {         // input rows hy-1 .. hy+2
    int ay = hy + y - 1;
    if ((unsigned)ay >= 256u) continue;
    const bhalf* rowp = in + (((((size_t)bb << 8) + (size_t)ay) << 8) << CB) + c0;
    #pragma unroll
    for (int cc = 0; cc < 6; ++cc) {
      int xw = x0 + cc - 1;
      if (cc == 0 || cc == 5) {
        if ((unsigned)xw >= 256u) continue;
      }
      union { uint4 u; h2 h[4]; } dv;
      dv.u = *(const uint4*)(rowp + ((size_t)xw << CB));
      #pragma unroll
      for (int o = 0; o < 2; ++o) {
        int kh = y - o;
        if (kh >= 0 && kh < 3) {
          #pragma unroll
          for (int kw = 0; kw < 3; ++kw) {
            int px = cc - kw;
            if (px >= 0 && px < 4) {
              #pragma unroll
              for (int j = 0; j < 4; ++j)
                acc[o][px][j] += dv.h[j] * wr[kh][kw][j];   // v_pk_fma_f16
            }
          }
        }
      }
    }
  }

  #pragma unroll
  for (int o = 0; o < 2; ++o) {
    size_t prow = (((size_t)bb << 8) + (size_t)(hy + o)) << 8;
    #pragma unroll
    for (int px = 0; px < 4; ++px) {
      bhalf* op = out + ((prow + (size_t)(x0 + px)) << CB) + c0;
      if (EPI == 0) {
        union { h2 h[4]; uint4 u; } sv;
        #pragma unroll
        for (int j = 0; j < 4; ++j) sv.h[j] = acc[o][px][j];
        *(uint4*)op = sv.u;
      } else {
        float r[8];
        #pragma unroll
        for (int j = 0; j < 4; ++j) {
          r[2*j]   = gelu_f((float)acc[o][px][j][0]);
          r[2*j+1] = gelu_f((float)acc[o][px][j][1]);
        }
        *(uint4*)op = pack16(r);
      }
    }
  }
}

// ---------------- fused PE branch: Pb = dw3(gelu(dw3(V, pe1)), pe2), ch64 ----------------
// 1024 blocks: 16 x-tiles x 32 y-tiles x 2 batches; output tile 16x8 px x 64 ch.
// Phase 1: conv1+gelu on the 10x18 halo tile (V read from global/L2) -> G1 LDS
// (OOB px stored 0 == SAME zero-padding). Phase 2: conv2 from G1. Eliminates
// the T1 global intermediate.
__global__ __launch_bounds__(256) void pe_fused(
    const bhalf* __restrict__ V, const float* __restrict__ w1,
    const float* __restrict__ w2, bhalf* __restrict__ Pb)
{
  __shared__ __align__(16) bhalf G1[10 * 18 * 64];   // 23040 B
  __shared__ u32 W1s[9 * 8 * 5], W2s[9 * 8 * 5];
  int t = threadIdx.x;
  for (int idx = t; idx < 288; idx += 256) {         // 9 taps x 32 ch-pairs
    int tap = idx >> 5, cp = idx & 31;
    int cgw = cp >> 2, j = cp & 3;
    union { h2 h; u32 u; } cv;
    h2 p1; p1[0] = (_Float16)w1[tap * 64 + 2 * cp]; p1[1] = (_Float16)w1[tap * 64 + 2 * cp + 1];
    cv.h = p1; W1s[tap * 40 + cgw * 5 + j] = cv.u;
    h2 p2; p2[0] = (_Float16)w2[tap * 64 + 2 * cp]; p2[1] = (_Float16)w2[tap * 64 + 2 * cp + 1];
    cv.h = p2; W2s[tap * 40 + cgw * 5 + j] = cv.u;
  }
  __syncthreads();

  int bx = (int)(blockIdx.x & 15), by = (int)((blockIdx.x >> 4) & 31);
  int bb = (int)(blockIdx.x >> 9);
  int x0 = bx << 4, y0 = by << 3;
  int cg = t & 7, c0 = cg << 3;
  int slot = t >> 3;               // 0..31

  h2 wr[9][4];
  #pragma unroll
  for (int tap = 0; tap < 9; ++tap)
    #pragma unroll
    for (int j = 0; j < 4; ++j) {
      union { u32 u; h2 h; } cv; cv.u = W1s[tap * 40 + cg * 5 + j]; wr[tap][j] = cv.h;
    }

  h2 zero = {(_Float16)0.0f, (_Float16)0.0f};
  // phase 1: conv1 + gelu on 10x18 px (image coords y0-1..y0+8, x0-1..x0+16)
  for (int i = slot; i < 180; i += 32) {
    int y1 = i / 18, x1 = i - y1 * 18;
    int py = y0 + y1 - 1, px = x0 + x1 - 1;
    uint4 outv = {0, 0, 0, 0};
    if ((unsigned)py < 256u && (unsigned)px < 256u) {
      h2 acc[4] = {zero, zero, zero, zero};
      #pragma unroll
      for (int kh = 0; kh < 3; ++kh) {
        int gy = py + kh - 1;
        if ((unsigned)gy >= 256u) continue;
        #pragma unroll
        for (int kw = 0; kw < 3; ++kw) {
          int gx = px + kw - 1;
          if ((unsigned)gx >= 256u) continue;
          size_t base = ((((size_t)bb << 8) + (size_t)gy) << 8) + (size_t)gx;
          union { uint4 u; h2 h[4]; } dv;
          dv.u = *(const uint4*)(V + (base << 6) + c0);
          #pragma unroll
          for (int j = 0; j < 4; ++j)
            acc[j] += dv.h[j] * wr[kh * 3 + kw][j];
        }
      }
      float r[8];
      #pragma unroll
      for (int j = 0; j < 4; ++j) {
        r[2*j]   = gelu_f((float)acc[j][0]);
        r[2*j+1] = gelu_f((float)acc[j][1]);
      }
      outv = pack16(r);
    }
    *(uint4*)&G1[(y1 * 18 + x1) * 64 + c0] = outv;
  }
  __syncthreads();

  // reload w2 taps
  #pragma unroll
  for (int tap = 0; tap < 9; ++tap)
    #pragma unroll
    for (int j = 0; j < 4; ++j) {
      union { u32 u; h2 h; } cv; cv.u = W2s[tap * 40 + cg * 5 + j]; wr[tap][j] = cv.h;
    }

  // phase 2: conv2 on the 8x16 output tile from G1
  for (int i = slot; i < 128; i += 32) {
    int y2 = i >> 4, x2 = i & 15;
    h2 acc[4] = {zero, zero, zero, zero};
    #pragma unroll
    for (int kh = 0; kh < 3; ++kh)
      #pragma unroll
      for (int kw = 0; kw < 3; ++kw) {
        union { uint4 u; h2 h[4]; } dv;
        dv.u = *(const uint4*)&G1[((y2 + kh) * 18 + (x2 + kw)) * 64 + c0];
        #pragma unroll
        for (int j = 0; j < 4; ++j)
          acc[j] += dv.h[j] * wr[kh * 3 + kw][j];
      }
    union { h2 h[4]; uint4 u; } sv;
    #pragma unroll
    for (int j = 0; j < 4; ++j) sv.h[j] = acc[j];
    size_t base = ((((size_t)bb << 8) + (size_t)(y0 + y2)) << 8) + (size_t)(x0 + x2);
    *(uint4*)(Pb + (base << 6) + c0) = sv.u;
  }
}

// ---------------- attn softmax + fold into Wp (merged) ----------------
__global__ __launch_bounds__(256) void attn_fold(
    const float* __restrict__ S, const float* __restrict__ resc,
    const bhalf* __restrict__ wpT, bhalf* __restrict__ weffT)
{
  __shared__ float As[1024];     // [h][e][d]
  __shared__ float nqs_s[64];    // [h][d]
  int b = blockIdx.x;            // 2 blocks (batch)
  int t = threadIdx.x;
  if (t < 64) {
    int h = t >> 4, d = t & 15;
    float nqsum = 0.f;
    for (int c = 0; c < NSPLIT; ++c)
      nqsum += S[c * SCOPY + 2048 + b * 64 + h * 16 + d];
    nqs_s[t] = fmaxf(sqrtf(nqsum), 1e-6f);
  }
  __syncthreads();
  if (t < 64) {
    int h = t >> 4, d = t & 15;
    float nksum = 0.f;
    for (int c = 0; c < NSPLIT; ++c)
      nksum += S[c * SCOPY + 2176 + b * 64 + h * 16 + d];
    float nkd = fmaxf(sqrtf(nksum), 1e-6f);
    float r = resc[h];
    float4 s4[4] = {{0,0,0,0},{0,0,0,0},{0,0,0,0},{0,0,0,0}};
    for (int c = 0; c < NSPLIT; ++c) {
      const float4* sp = (const float4*)&S[c * SCOPY + (((b * 4 + h) * 16 + d) << 4)];
      #pragma unroll
      for (int j = 0; j < 4; ++j) {
        float4 u = sp[j];
        s4[j].x += u.x; s4[j].y += u.y; s4[j].z += u.z; s4[j].w += u.w;
      }
    }
    float a[16];
    #pragma unroll
    for (int j = 0; j < 4; ++j) {
      a[4*j]   = s4[j].x * r / (nkd * nqs_s[h * 16 + 4*j]);
      a[4*j+1] = s4[j].y * r / (nkd * nqs_s[h * 16 + 4*j + 1]);
      a[4*j+2] = s4[j].z * r / (nkd * nqs_s[h * 16 + 4*j + 2]);
      a[4*j+3] = s4[j].w * r / (nkd * nqs_s[h * 16 + 4*j + 3]);
    }
    float m = -1e30f;
    #pragma unroll
    for (int e = 0; e < 16; ++e) m = fmaxf(m, a[e]);
    float sum = 0.f;
    #pragma unroll
    for (int e = 0; e < 16; ++e) { a[e] = expf(a[e] - m); sum += a[e]; }
    float inv = 1.0f / sum;
    #pragma unroll
    for (int e = 0; e < 16; ++e)
      As[((h * 16 + e) << 4) + d] = a[e] * inv;
  }
  __syncthreads();
  int m = t & 63, h = t >> 6;    // each thread: one (m, h) pair -> 16 outputs
  const bhalf* wp = wpT + m * 64 + h * 16;
  float wv_[16];
  uint4 w0 = ((const uint4*)wp)[0], w1 = ((const uint4*)wp)[1];
  unpack8h(w0, wv_); unpack8h(w1, wv_ + 8);
  float r2[16];
  #pragma unroll
  for (int e = 0; e < 16; ++e) {
    const float* ar = &As[(h * 16 + e) << 4];
    float s = 0.f;
    #pragma unroll
    for (int d = 0; d < 16; ++d) s += ar[d] * wv_[d];
    r2[e] = s;
  }
  bhalf* dst = weffT + b * 4096 + m * 64 + h * 16;
  ((uint4*)dst)[0] = pack16(r2);
  ((uint4*)dst)[1] = pack16(r2 + 8);
}

// ---------------- host orchestration ----------------
extern "C" void kernel_launch(void* const* d_in, const int* in_sizes, int n_in,
                              void* d_out, int out_size, void* d_ws, size_t ws_size,
                              hipStream_t stream)
{
  (void)in_sizes; (void)n_in; (void)out_size; (void)ws_size;
  const float* x_in    = (const float*)d_in[0];
  const float* mask_in = (const float*)d_in[1];
  const float* Wq    = (const float*)d_in[2];
  const float* Wk    = (const float*)d_in[3];
  const float* Wv    = (const float*)d_in[4];
  const float* resc  = (const float*)d_in[5];
  const float* Wp    = (const float*)d_in[6];
  const float* bp    = (const float*)d_in[7];
  const float* pe1   = (const float*)d_in[8];
  const float* pe2   = (const float*)d_in[9];
  const float* mm_w1 = (const float*)d_in[10];
  const float* mm_b1 = (const float*)d_in[11];
  const float* mm_w2 = (const float*)d_in[12];
  const float* mm_b2 = (const float*)d_in[13];
  const float* mm_dw = (const float*)d_in[14];
  const float* mm_db = (const float*)d_in[15];
  const float* ln_g  = (const float*)d_in[16];
  const float* ln_b  = (const float*)d_in[17];
  const float* ff_w1 = (const float*)d_in[18];
  const float* ff_dw = (const float*)d_in[19];
  const float* ff_w2 = (const float*)d_in[20];

  const size_t NC = 8388608;  // B*N*C
  char* w = (char*)d_ws;
  float* X  = (float*)w; w += NC * 4;   // residual stream, fp32
  bhalf* Xb = (bhalf*)w; w += NC * 2;   // f16 mirror of X
  bhalf* M  = (bhalf*)w; w += NC * 2;   // mask NHWC
  bhalf* Qb = (bhalf*)w; w += NC * 2;   // (dead; spanned by F1)
  bhalf* Kb = (bhalf*)w; w += NC * 2;   // (dead; spanned by F1)
  bhalf* Vb = (bhalf*)w; w += NC * 2;
  bhalf* VG = (bhalf*)w; w += NC * 2;
  bhalf* T1 = (bhalf*)w; w += NC * 2;
  bhalf* T2 = (bhalf*)w; w += NC * 2;
  bhalf* T3 = (bhalf*)w; w += NC * 2;
  bhalf* Pb = (bhalf*)w; w += NC * 2;
  float* Sb    = (float*)w; w += (size_t)NSPLIT * SCOPY * 4;  // split accumulators
  bhalf* WeffT = (bhalf*)w; w += 8192 * 2;                    // per-batch A_bd@Wp
  bhalf* WTg   = (bhalf*)w; w += (size_t)3 * WBLK * 2;        // pre-transposed weights
  (void)Qb; (void)Kb;
  // FFN 256-ch temps alias dead 64-ch buffers.
  bhalf* F1 = Qb;   // [131072 x 256] ffn hidden (spans Qb,Kb,Vb,VG)
  bhalf* F2 = T1;   // [131072 x 256] post-dwconv (spans T1,T2,T3,Pb)

  prep_weights<<<24, 256, 0, stream>>>(mm_w1, mm_w2, Wq, Wk, Wv, Wp, ff_w1, ff_w2, WTg);
  nchw2nhwc<0><<<2048, 256, 0, stream>>>(x_in, X, Xb);
  nchw2nhwc<1><<<2048, 256, 0, stream>>>(mask_in, M, nullptr);

  for (int i = 0; i < 3; ++i) {
    const bhalf* wb = WTg + (size_t)i * WBLK;
    // mask branch: m1 (T1) + m2 (T2) fused; then MA (T3)
    gemm_mask2<<<GEMM_GRID, 256, 0, stream>>>(M, wb + 0, mm_b1 + i*64, mm_b2 + i*64, T1, T2);
    dwconv4<5, 2, 64><<<1024, 256, 0, stream>>>(T2, mm_dw + i*1600, mm_db + i*64, T1, T3, 64);
    // fused QKV + gate + in-register attention partials (128 rows/block)
    hipMemsetAsync(Sb, 0, NSPLIT * SCOPY * 4, stream);
    qkv_gemm<<<1024, 256, 0, stream>>>(Xb, wb + 8192, T3, Vb, VG, Sb);
    attn_fold<<<2, 256, 0, stream>>>(Sb, resc + i*4, wb + 20480, WeffT);
    // positional branch on ungated V (fused dw3 -> gelu -> dw3)
    pe_fused<<<1024, 256, 0, stream>>>(Vb, pe1 + i*576, pe2 + i*576, Pb);
    // X += VG@Weff + bp + P  (attn folded into weights; Xb refresh was dead)
    gemm64m<EP_RESID, 1><<<GEMM_GRID, 256, 0, stream>>>(VG, WeffT, bp + i*64, X, Pb);
    // FFN (full 256 hidden): fused ln+gemm1(gelu) -> dw3(gelu) -> gemm2(acc)
    ffn_gemm1_ln<<<GEMM_GRID, 256, 0, stream>>>(X, wb + 24576, ln_g + i*64, ln_b + i*64, F1);
    dwconv8<1, 256><<<2048, 256, 0, stream>>>(F1, ff_dw + i*2304, F2, 256);
    if (i < 2)
      ffn_gemm2<0><<<GEMM_GRID, 256, 0, stream>>>(F2, wb + 40960, X, Xb, nullptr);
    else
      ffn_gemm2<1><<<GEMM_GRID, 256, 0, stream>>>(F2, wb + 40960, X, Xb, (float*)d_out);
  }
}